// Round 8
// baseline (215.973 us; speedup 1.0000x reference)
//
#include <hip/hip_runtime.h>

#define GROUP 8
#define BS 4096
#define CH 512
#define PW 32
#define NPANEL 16

typedef __attribute__((ext_vector_type(4))) float f32x4;
typedef __attribute__((ext_vector_type(8))) short bf16x8;
typedef __attribute__((ext_vector_type(8))) unsigned short u16x8;
typedef unsigned short u16;

static __device__ __forceinline__ u16 f2bf(float f) {
    unsigned int u = __builtin_bit_cast(unsigned int, f);
    u += 0x7FFFu + ((u >> 16) & 1u);   // RNE
    return (u16)(u >> 16);
}
static __device__ __forceinline__ float bf2f(u16 h) {
    return __builtin_bit_cast(float, (unsigned int)h << 16);
}
static __device__ __forceinline__ void split8(const float* v, bf16x8& h, bf16x8& l) {
#pragma unroll
    for (int j = 0; j < 8; ++j) {
        u16 hu = f2bf(v[j]);
        h[j] = (short)hu;
        l[j] = (short)f2bf(v[j] - bf2f(hu));
    }
}
#define MFMA(a, b, c) __builtin_amdgcn_mfma_f32_16x16x32_bf16(a, b, c, 0, 0, 0)

typedef const __attribute__((address_space(1))) void* gas_t;
typedef __attribute__((address_space(3))) void* las_t;
static __device__ __forceinline__ void gload16(const void* g, void* l) {
    __builtin_amdgcn_global_load_lds((gas_t)g, (las_t)l, 16, 0, 0);
}

// ---------------------------------------------------------------------------
// Kernel 1: per-32-panel prep, 1024 thr (16 waves).
// Blocks 0..127: prep. Blocks 128..1151 (fat only): x fp32->bf16 cast.
// ---------------------------------------------------------------------------
__global__ __launch_bounds__(1024) void k_panelprep(const float* __restrict__ w,
                                                    const float* __restrict__ x,
                                                    u16* __restrict__ Yh,
                                                    u16* __restrict__ Yl,
                                                    u16* __restrict__ Mth,
                                                    u16* __restrict__ Mtl,
                                                    u16* __restrict__ xb) {
    __shared__ float Ylds[PW][516];      // 66048 B
    __shared__ float Sp[16][PW][36];     // 73728 B
    __shared__ float S_ls[PW][36];
    __shared__ float T_ls[PW][36];
    __shared__ float betaL[PW];

    int bid = blockIdx.x;
    int t   = threadIdx.x;

    if (bid >= 128) {
        // ---- xcast: 1024 blocks x 1024 thr, 2 iters each ----
        const int TOT8 = GROUP * BS * CH / 8;       // 2097152
        for (int i = (bid - 128) * 1024 + t; i < TOT8; i += 1024 * 1024) {
            const float4* s = (const float4*)(x + (size_t)i * 8);
            float4 a = s[0], b = s[1];
            u16x8 o;
            o[0] = f2bf(a.x); o[1] = f2bf(a.y); o[2] = f2bf(a.z); o[3] = f2bf(a.w);
            o[4] = f2bf(b.x); o[5] = f2bf(b.y); o[6] = f2bf(b.z); o[7] = f2bf(b.w);
            *(u16x8*)(xb + (size_t)i * 8) = o;
        }
        return;
    }

    int lane = t & 63;
    int wv   = t >> 6;           // 0..15
    int fr   = lane & 15;
    int kg   = lane >> 4;
    int g    = bid >> 4;
    int p    = bid & 15;
    int i0   = p * PW;

    // ---- stage Y[i][c] = w[g][c][i0+i] (transpose-read, 32x512) ----
    const float* wg = w + (size_t)g * CH * CH;
    for (int idx4 = t; idx4 < 4096; idx4 += 1024) {
        int c = idx4 >> 3, f4 = idx4 & 7;
        float4 v = *(const float4*)(wg + (size_t)c * CH + i0 + f4 * 4);
        Ylds[f4 * 4 + 0][c] = v.x;
        Ylds[f4 * 4 + 1][c] = v.y;
        Ylds[f4 * 4 + 2][c] = v.z;
        Ylds[f4 * 4 + 3][c] = v.w;
    }
    __syncthreads();

    // ---- S = Y Y^T via split MFMA; wave wv covers kk = wv ----
    {
        f32x4 sacc[2][2];
#pragma unroll
        for (int a = 0; a < 2; ++a)
#pragma unroll
            for (int b = 0; b < 2; ++b)
#pragma unroll
                for (int z = 0; z < 4; ++z) sacc[a][b][z] = 0.f;
        {
            int kk = wv;
            bf16x8 fh[2], fl[2];
#pragma unroll
            for (int h = 0; h < 2; ++h) {
                float a8[8];
                const float* src = &Ylds[h * 16 + fr][kk * 32 + kg * 8];
#pragma unroll
                for (int j = 0; j < 8; ++j) a8[j] = src[j];
                split8(a8, fh[h], fl[h]);
            }
#pragma unroll
            for (int a = 0; a < 2; ++a)
#pragma unroll
                for (int b = 0; b < 2; ++b) {
                    sacc[a][b] = MFMA(fh[a], fh[b], sacc[a][b]);
                    sacc[a][b] = MFMA(fh[a], fl[b], sacc[a][b]);
                    sacc[a][b] = MFMA(fl[a], fh[b], sacc[a][b]);
                }
        }
#pragma unroll
        for (int a = 0; a < 2; ++a)
#pragma unroll
            for (int b = 0; b < 2; ++b)
#pragma unroll
                for (int j = 0; j < 4; ++j)
                    Sp[wv][a * 16 + kg * 4 + j][b * 16 + fr] = sacc[a][b][j];
    }
    __syncthreads();
    for (int idx = t; idx < PW * PW; idx += 1024) {
        int r = idx >> 5, c = idx & 31;
        float s = 0.f;
#pragma unroll
        for (int q = 0; q < 16; ++q) s += Sp[q][r][c];
        S_ls[r][c] = s;
    }
    __syncthreads();
    if (t < PW) betaL[t] = 2.0f / S_ls[t][t];
    for (int idx = t; idx < PW * 36; idx += 1024) ((float*)T_ls)[idx] = 0.f;
    __syncthreads();
    if (t < PW) T_ls[t][t] = betaL[t];
    __syncthreads();
    for (int k = 1; k < PW; ++k) {
        if (t < k) {
            float acc = 0.f;
            for (int j = t; j < k; ++j) acc += T_ls[t][j] * S_ls[j][k];
            T_ls[t][k] = -betaL[k] * acc;
        }
        __syncthreads();
    }

    // ---- M^T = Y^T * T^T (512x32, K=32): wave wv covers rf = 2wv..2wv+1 ----
    bf16x8 tbh[2], tbl[2];
#pragma unroll
    for (int cf = 0; cf < 2; ++cf) {
        float t8[8];
        const float* src = &T_ls[cf * 16 + fr][kg * 8];
#pragma unroll
        for (int j = 0; j < 8; ++j) t8[j] = src[j];
        split8(t8, tbh[cf], tbl[cf]);
    }
#pragma unroll
    for (int rfi = 0; rfi < 2; ++rfi) {
        int rf = 2 * wv + rfi;
        float a8[8];
#pragma unroll
        for (int j = 0; j < 8; ++j) a8[j] = Ylds[kg * 8 + j][rf * 16 + fr];
        bf16x8 ah, al;
        split8(a8, ah, al);
#pragma unroll
        for (int cf = 0; cf < 2; ++cf) {
            f32x4 m;
#pragma unroll
            for (int z = 0; z < 4; ++z) m[z] = 0.f;
            m = MFMA(ah, tbh[cf], m);
            m = MFMA(ah, tbl[cf], m);
            m = MFMA(al, tbh[cf], m);
#pragma unroll
            for (int j = 0; j < 4; ++j) {
                int c = rf * 16 + kg * 4 + j;
                int i = cf * 16 + fr;
                size_t off = ((size_t)g * CH + c) * CH + (i0 + i);
                u16 hu = f2bf(m[j]);
                Mth[off] = hu;
                Mtl[off] = f2bf(m[j] - bf2f(hu));
            }
        }
    }

    // ---- export Y panel bf16 hi/lo ----
    for (int idx = t; idx < PW * CH; idx += 1024) {
        int r = idx >> 9, c = idx & 511;
        float v = Ylds[r][c];
        size_t off = ((size_t)g * CH + i0 + r) * CH + c;
        u16 hu = f2bf(v);
        Yh[off] = hu;
        Yl[off] = f2bf(v - bf2f(hu));
    }
}

// ---------------------------------------------------------------------------
// Kernel 2 (x4 levels): WY merge, ping-pong src->dst, c-split x4.
// Grid 1024 x 256 thr: bid<512 merge blocks (g, strip s, c-slice cq):
//   M_top' = M_top - (M_top Y_bot^T) M_bot for 16 rows x 128-col slice;
// bid>=512 copy blocks: copy bottom rows' slice src->dst.
// ---------------------------------------------------------------------------
template<int W>
__global__ __launch_bounds__(256) void k_combine(const u16* __restrict__ Yh,
                                                 const u16* __restrict__ Yl,
                                                 const u16* __restrict__ Sh,
                                                 const u16* __restrict__ Sl,
                                                 u16* __restrict__ Dh,
                                                 u16* __restrict__ Dl) {
    __shared__ u16 MAh[16][520];
    __shared__ u16 MAl[16][520];
    __shared__ float Cl[16][260];

    int bid = blockIdx.x;
    int t = threadIdx.x, lane = t & 63, wv = t >> 6;
    int fr = lane & 15, kg = lane >> 4;

    constexpr int SP = W / 16;           // 16-row strips per pair-top

    if (bid >= 512) {
        // ---- copy block: bottom strip slice src -> dst ----
        int cb = bid - 512;
        int g  = cb >> 6;
        int r  = cb & 63;
        int s  = r >> 2, cq = r & 3;
        int q  = s / SP, rs = s % SP;
        int i_c0 = 2 * q * W + W + rs * 16;
        size_t go = (size_t)g * CH * CH;
        int c  = cq * 128 + (t >> 1);
        int ch = t & 1;
        size_t off = go + (size_t)c * CH + i_c0 + ch * 8;
        *(bf16x8*)(Dh + off) = *(const bf16x8*)(Sh + off);
        *(bf16x8*)(Dl + off) = *(const bf16x8*)(Sl + off);
        return;
    }

    int g  = bid >> 6;
    int r  = bid & 63;
    int s  = r >> 2, cq = r & 3;
    int q  = s / SP, rs = s % SP;
    int i_top0 = 2 * q * W + rs * 16;
    int i_bot0 = 2 * q * W + W;

    const u16* Yh_g = Yh + (size_t)g * CH * CH;
    const u16* Yl_g = Yl + (size_t)g * CH * CH;
    const u16* Sh_g = Sh + (size_t)g * CH * CH;
    const u16* Sl_g = Sl + (size_t)g * CH * CH;
    u16* Dh_g = Dh + (size_t)g * CH * CH;
    u16* Dl_g = Dl + (size_t)g * CH * CH;

    // ---- stage M_A strip from SRC, transposed to MA[i][c] (16 x 512) ----
    for (int idx = t; idx < 1024; idx += 256) {
        int c = idx >> 1, ch = idx & 1;
        bf16x8 hv = *(const bf16x8*)(Sh_g + (size_t)c * CH + i_top0 + ch * 8);
        bf16x8 lv = *(const bf16x8*)(Sl_g + (size_t)c * CH + i_top0 + ch * 8);
#pragma unroll
        for (int j = 0; j < 8; ++j) {
            MAh[ch * 8 + j][c] = (u16)hv[j];
            MAl[ch * 8 + j][c] = (u16)lv[j];
        }
    }
    __syncthreads();

    // ---- C[i][jb] = sum_c MA[i][c] Ybot[jb][c]  (16 x W, K=512) ----
    constexpr int NF = W / 16;
    constexpr int CPW = (NF + 3) / 4;
    f32x4 accC[CPW];
#pragma unroll
    for (int nfi = 0; nfi < CPW; ++nfi)
#pragma unroll
        for (int z = 0; z < 4; ++z) accC[nfi][z] = 0.f;

    for (int ks = 0; ks < 16; ++ks) {
        bf16x8 ah = *(const bf16x8*)&MAh[fr][ks * 32 + kg * 8];
        bf16x8 al = *(const bf16x8*)&MAl[fr][ks * 32 + kg * 8];
#pragma unroll
        for (int nfi = 0; nfi < CPW; ++nfi) {
            int nf = wv + 4 * nfi;
            if (nf < NF) {
                size_t yo = (size_t)(i_bot0 + nf * 16 + fr) * CH + ks * 32 + kg * 8;
                bf16x8 bh = *(const bf16x8*)(Yh_g + yo);
                bf16x8 bl = *(const bf16x8*)(Yl_g + yo);
                accC[nfi] = MFMA(ah, bh, accC[nfi]);
                accC[nfi] = MFMA(ah, bl, accC[nfi]);
                accC[nfi] = MFMA(al, bh, accC[nfi]);
            }
        }
    }
#pragma unroll
    for (int nfi = 0; nfi < CPW; ++nfi) {
        int nf = wv + 4 * nfi;
        if (nf < NF)
#pragma unroll
            for (int jj = 0; jj < 4; ++jj)
                Cl[kg * 4 + jj][nf * 16 + fr] = accC[nfi][jj];
    }
    __syncthreads();

    // ---- U[i][c] = sum_j C[i][j] MB[j][c]  (16 x 128-slice, K=W) ----
    f32x4 accU[2];
#pragma unroll
    for (int ni = 0; ni < 2; ++ni)
#pragma unroll
        for (int z = 0; z < 4; ++z) accU[ni][z] = 0.f;

    for (int ks2 = 0; ks2 < W / 32; ++ks2) {
        float a8[8];
#pragma unroll
        for (int j = 0; j < 8; ++j) a8[j] = Cl[fr][ks2 * 32 + kg * 8 + j];
        bf16x8 ah2, al2;
        split8(a8, ah2, al2);
#pragma unroll
        for (int ni = 0; ni < 2; ++ni) {
            int c = cq * 128 + (wv * 2 + ni) * 16 + fr;
            size_t mo = (size_t)c * CH + i_bot0 + ks2 * 32 + kg * 8;
            bf16x8 bh = *(const bf16x8*)(Sh_g + mo);
            bf16x8 bl = *(const bf16x8*)(Sl_g + mo);
            accU[ni] = MFMA(ah2, bh, accU[ni]);
            accU[ni] = MFMA(ah2, bl, accU[ni]);
            accU[ni] = MFMA(al2, bh, accU[ni]);
        }
    }
    // ---- subtract into LDS (slice cols only) ----
#pragma unroll
    for (int ni = 0; ni < 2; ++ni) {
        int c = cq * 128 + (wv * 2 + ni) * 16 + fr;
#pragma unroll
        for (int jj = 0; jj < 4; ++jj) {
            int il = kg * 4 + jj;
            float ma = bf2f(MAh[il][c]) + bf2f(MAl[il][c]);
            float m2 = ma - accU[ni][jj];
            u16 hu = f2bf(m2);
            MAh[il][c] = hu;
            MAl[il][c] = f2bf(m2 - bf2f(hu));
        }
    }
    __syncthreads();

    // ---- store slice back to DST [c][i] layout (one iter: 128c x 2ch) ----
    {
        int c  = cq * 128 + (t >> 1);
        int ch = t & 1;
        bf16x8 hv, lv;
#pragma unroll
        for (int j = 0; j < 8; ++j) {
            hv[j] = (short)MAh[ch * 8 + j][c];
            lv[j] = (short)MAl[ch * 8 + j][c];
        }
        *(bf16x8*)(Dh_g + (size_t)c * CH + i_top0 + ch * 8) = hv;
        *(bf16x8*)(Dl_g + (size_t)c * CH + i_top0 + ch * 8) = lv;
    }
}

// ---------------------------------------------------------------------------
// Kernel 3: Qt[g][d][c] = [I - w*M]^T. 512 blocks x 256 thr.
// ---------------------------------------------------------------------------
__global__ __launch_bounds__(256) void k_qbuild2(const float* __restrict__ w,
                                                 const u16* __restrict__ Mth,
                                                 const u16* __restrict__ Mtl,
                                                 u16* __restrict__ Qt) {
    int t = threadIdx.x, lane = t & 63, wv = t >> 6;
    int fr = lane & 15, kg = lane >> 4;
    int g  = blockIdx.x >> 6;
    int tm = (blockIdx.x >> 2) & 15, tn = blockIdx.x & 3;
    int c0 = tm * 32;
    int d0 = tn * 128 + wv * 32;

    const float* wg = w + (size_t)g * CH * CH;
    const u16* Mth_g = Mth + (size_t)g * CH * CH;
    const u16* Mtl_g = Mtl + (size_t)g * CH * CH;
    u16* Qt_g = Qt + (size_t)g * CH * CH;

    f32x4 acc[2][2];
#pragma unroll
    for (int mi = 0; mi < 2; ++mi)
#pragma unroll
        for (int ni = 0; ni < 2; ++ni)
#pragma unroll
            for (int z = 0; z < 4; ++z) acc[mi][ni][z] = 0.f;

    for (int ks = 0; ks < 16; ++ks) {
        bf16x8 ah[2], al[2], bh[2], bl[2];
#pragma unroll
        for (int mi = 0; mi < 2; ++mi) {
            const float* src = wg + (size_t)(c0 + mi * 16 + fr) * CH + ks * 32 + kg * 8;
            float4 v0 = *(const float4*)src;
            float4 v1 = *(const float4*)(src + 4);
            float a8[8] = {v0.x, v0.y, v0.z, v0.w, v1.x, v1.y, v1.z, v1.w};
            split8(a8, ah[mi], al[mi]);
        }
#pragma unroll
        for (int ni = 0; ni < 2; ++ni) {
            size_t mo = (size_t)(d0 + ni * 16 + fr) * CH + ks * 32 + kg * 8;
            bh[ni] = *(const bf16x8*)(Mth_g + mo);
            bl[ni] = *(const bf16x8*)(Mtl_g + mo);
        }
#pragma unroll
        for (int mi = 0; mi < 2; ++mi)
#pragma unroll
            for (int ni = 0; ni < 2; ++ni) {
                acc[mi][ni] = MFMA(ah[mi], bh[ni], acc[mi][ni]);
                acc[mi][ni] = MFMA(ah[mi], bl[ni], acc[mi][ni]);
                acc[mi][ni] = MFMA(al[mi], bh[ni], acc[mi][ni]);
            }
    }
#pragma unroll
    for (int mi = 0; mi < 2; ++mi)
#pragma unroll
        for (int ni = 0; ni < 2; ++ni) {
            int cb = c0 + mi * 16 + kg * 4;
            int d  = d0 + ni * 16 + fr;
            ushort4 h4;
            h4.x = f2bf(((cb + 0 == d) ? 1.0f : 0.0f) - acc[mi][ni][0]);
            h4.y = f2bf(((cb + 1 == d) ? 1.0f : 0.0f) - acc[mi][ni][1]);
            h4.z = f2bf(((cb + 2 == d) ? 1.0f : 0.0f) - acc[mi][ni][2]);
            h4.w = f2bf(((cb + 3 == d) ? 1.0f : 0.0f) - acc[mi][ni][3]);
            *(ushort4*)(Qt_g + (size_t)d * CH + cb) = h4;
        }
}

// ---------------------------------------------------------------------------
// Kernel 4 (m97-style, BK=64): out = xb @ Qt; both bf16 via global_load_lds
// width-16 into linear LDS [128][64]. 128x128 tile, 8 K-steps.
// ---------------------------------------------------------------------------
__global__ __launch_bounds__(256) void k_gemm2(const u16* __restrict__ xb,
                                               const u16* __restrict__ Qt,
                                               float* __restrict__ out) {
    __shared__ u16 Ab[128 * 64];
    __shared__ u16 Bb[128 * 64];

    int bid = blockIdx.x;
    int g  = bid >> 7;
    int tn = (bid >> 5) & 3;
    int tm = bid & 31;

    int t    = threadIdx.x;
    int lane = t & 63;
    int wv   = t >> 6;
    int wr   = wv >> 1, wc = wv & 1;
    int fr   = lane & 15, kg = lane >> 4;

    const u16* xg  = xb + (size_t)g * BS * CH + (size_t)tm * 128 * CH;
    const u16* Qtg = Qt + (size_t)g * CH * CH + (size_t)tn * 128 * CH;
    float* og = out + (size_t)g * BS * CH + (size_t)tm * 128 * CH + (size_t)tn * 128;

    f32x4 acc[4][4];
#pragma unroll
    for (int mi = 0; mi < 4; ++mi)
#pragma unroll
        for (int ni = 0; ni < 4; ++ni)
#pragma unroll
            for (int z = 0; z < 4; ++z) acc[mi][ni][z] = 0.f;

    int srow8 = lane >> 3;       // 0..7 row within 8-row segment
    int scol  = (lane & 7) * 8;  // bf16 col offset within 64-wide K

    for (int ks = 0; ks < 8; ++ks) {
        int k0 = ks * 64;
        __syncthreads();
        // stage A,B: 16 segments each (1 KB = 8 rows x 128 B); wave wv: 4+4
#pragma unroll
        for (int si = 0; si < 4; ++si) {
            int s = wv * 4 + si;
            int row = s * 8 + srow8;
            gload16(xg  + (size_t)row * CH + k0 + scol, &Ab[s * 512]);
            gload16(Qtg + (size_t)row * CH + k0 + scol, &Bb[s * 512]);
        }
        __syncthreads();   // drains vmcnt(0): LDS valid

#pragma unroll
        for (int kk = 0; kk < 2; ++kk) {
            bf16x8 af[4], bfr[4];
#pragma unroll
            for (int mi = 0; mi < 4; ++mi)
                af[mi] = *(const bf16x8*)&Ab[(wr * 64 + mi * 16 + fr) * 64 + kk * 32 + kg * 8];
#pragma unroll
            for (int ni = 0; ni < 4; ++ni)
                bfr[ni] = *(const bf16x8*)&Bb[(wc * 64 + ni * 16 + fr) * 64 + kk * 32 + kg * 8];
#pragma unroll
            for (int mi = 0; mi < 4; ++mi)
#pragma unroll
                for (int ni = 0; ni < 4; ++ni)
                    acc[mi][ni] = MFMA(af[mi], bfr[ni], acc[mi][ni]);
        }
    }

    int rg = lane >> 4;
#pragma unroll
    for (int mi = 0; mi < 4; ++mi)
#pragma unroll
        for (int ni = 0; ni < 4; ++ni)
#pragma unroll
            for (int rj = 0; rj < 4; ++rj) {
                int grow = wr * 64 + mi * 16 + rg * 4 + rj;
                int gcol = wc * 64 + ni * 16 + fr;
                og[(size_t)grow * CH + gcol] = acc[mi][ni][rj];
            }
}

// ---------------------------------------------------------------------------
// Fallback GEMM (fp32 A, in-staging convert) — round-5 verified.
// ---------------------------------------------------------------------------
#define LDP 40
__global__ __launch_bounds__(256) void k_gemm_f32(const float* __restrict__ x,
                                                  const u16* __restrict__ Qt,
                                                  float* __restrict__ out) {
    __shared__ u16 Al[128 * LDP];
    __shared__ u16 Bl[128 * LDP];

    int bid = blockIdx.x;
    int g  = bid >> 7;
    int tn = (bid >> 5) & 3;
    int tm = bid & 31;

    int t    = threadIdx.x;
    int lane = t & 63;
    int w    = t >> 6;
    int wr   = w >> 1, wc = w & 1;

    const float* xg = x + (size_t)g * BS * CH + (size_t)tm * 128 * CH;
    const u16* Qtg = Qt + (size_t)g * CH * CH + (size_t)tn * 128 * CH;
    float* og = out + (size_t)g * BS * CH + (size_t)tm * 128 * CH + (size_t)tn * 128;

    f32x4 acc[4][4];
#pragma unroll
    for (int mi = 0; mi < 4; ++mi)
#pragma unroll
        for (int ni = 0; ni < 4; ++ni)
#pragma unroll
            for (int z = 0; z < 4; ++z) acc[mi][ni][z] = 0.f;

    int a_k4 = t & 7;
    int a_r  = t >> 3;
    int b_n  = t & 127;
    int b_kh = t >> 7;
    int fr = lane & 15, kg = lane >> 4;

    for (int ks = 0; ks < 16; ++ks) {
        int k0 = ks * 32;
        __syncthreads();
#pragma unroll
        for (int rr = 0; rr < 4; ++rr) {
            int r = a_r + 32 * rr;
            float4 v = *(const float4*)(xg + (size_t)r * CH + k0 + a_k4 * 4);
            ushort4 h;
            h.x = f2bf(v.x); h.y = f2bf(v.y); h.z = f2bf(v.z); h.w = f2bf(v.w);
            *(ushort4*)(&Al[r * LDP + a_k4 * 4]) = h;
        }
        {
            const u16* src = Qtg + (size_t)b_n * CH + k0 + b_kh * 16;
            u16x8 lo = *(const u16x8*)src;
            u16x8 hi = *(const u16x8*)(src + 8);
            *(u16x8*)(&Bl[b_n * LDP + b_kh * 16]) = lo;
            *(u16x8*)(&Bl[b_n * LDP + b_kh * 16 + 8]) = hi;
        }
        __syncthreads();
        bf16x8 af[4], bfr[4];
#pragma unroll
        for (int mi = 0; mi < 4; ++mi)
            af[mi] = *(const bf16x8*)(&Al[(wr * 64 + mi * 16 + fr) * LDP + kg * 8]);
#pragma unroll
        for (int ni = 0; ni < 4; ++ni)
            bfr[ni] = *(const bf16x8*)(&Bl[(wc * 64 + ni * 16 + fr) * LDP + kg * 8]);
#pragma unroll
        for (int mi = 0; mi < 4; ++mi)
#pragma unroll
            for (int ni = 0; ni < 4; ++ni)
                acc[mi][ni] = MFMA(af[mi], bfr[ni], acc[mi][ni]);
    }

    int rg = lane >> 4;
#pragma unroll
    for (int mi = 0; mi < 4; ++mi)
#pragma unroll
        for (int ni = 0; ni < 4; ++ni)
#pragma unroll
            for (int rj = 0; rj < 4; ++rj) {
                int grow = wr * 64 + mi * 16 + rg * 4 + rj;
                int gcol = wc * 64 + ni * 16 + fr;
                og[(size_t)grow * CH + gcol] = acc[mi][ni][rj];
            }
}

// ---------------------------------------------------------------------------
extern "C" void kernel_launch(void* const* d_in, const int* in_sizes, int n_in,
                              void* d_out, int out_size, void* d_ws, size_t ws_size,
                              hipStream_t stream) {
    const float* x = (const float*)d_in[0];   // (8, 4096, 512)
    const float* w = (const float*)d_in[1];   // (8, 512, 512)
    float* out = (float*)d_out;

    // scratch carved from d_out (64 MiB; all dead before GEMM writes it):
    char* ob = (char*)d_out;
    u16* Yh   = (u16*)ob;                     // [0, 4MB)
    u16* Yl   = (u16*)(ob + (4u  << 20));     // [4, 8)
    u16* Mth  = (u16*)(ob + (8u  << 20));     // [8, 12)
    u16* Mtl  = (u16*)(ob + (12u << 20));     // [12, 16)
    u16* Mth2 = (u16*)(ob + (16u << 20));     // [16, 20)
    u16* Mtl2 = (u16*)(ob + (20u << 20));     // [20, 24)

    // d_ws: fat = xb (32 MB) + Qt (4 MB); else Qt only.
    int fat = (ws_size >= ((32u << 20) + (4u << 20))) ? 1 : 0;
    u16* xbp = (u16*)d_ws;
    u16* Qt  = fat ? (u16*)((char*)d_ws + (32u << 20)) : (u16*)d_ws;

    k_panelprep<<<dim3(fat ? 1152 : 128), dim3(1024), 0, stream>>>(w, x, Yh, Yl, Mth, Mtl, xbp);
    // ping-pong: A->B->A->B->A  (A = Mth/Mtl)
    k_combine<32><<<dim3(1024), dim3(256), 0, stream>>>(Yh, Yl, Mth,  Mtl,  Mth2, Mtl2);
    k_combine<64><<<dim3(1024), dim3(256), 0, stream>>>(Yh, Yl, Mth2, Mtl2, Mth,  Mtl);
    k_combine<128><<<dim3(1024), dim3(256), 0, stream>>>(Yh, Yl, Mth,  Mtl,  Mth2, Mtl2);
    k_combine<256><<<dim3(1024), dim3(256), 0, stream>>>(Yh, Yl, Mth2, Mtl2, Mth,  Mtl);
    k_qbuild2<<<dim3(512), dim3(256), 0, stream>>>(w, Mth, Mtl, Qt);
    if (fat)
        k_gemm2<<<dim3(1024), dim3(256), 0, stream>>>(xbp, Qt, out);
    else
        k_gemm_f32<<<dim3(1024), dim3(256), 0, stream>>>(x, Qt, out);
}

// Round 9
// 200.514 us; speedup vs baseline: 1.0771x; 1.0771x over previous
//
#include <hip/hip_runtime.h>

#define GROUP 8
#define BS 4096
#define CH 512
#define PW 32
#define NPANEL 16

typedef __attribute__((ext_vector_type(4))) float f32x4;
typedef __attribute__((ext_vector_type(8))) short bf16x8;
typedef __attribute__((ext_vector_type(8))) unsigned short u16x8;
typedef unsigned short u16;

static __device__ __forceinline__ u16 f2bf(float f) {
    unsigned int u = __builtin_bit_cast(unsigned int, f);
    u += 0x7FFFu + ((u >> 16) & 1u);   // RNE
    return (u16)(u >> 16);
}
static __device__ __forceinline__ float bf2f(u16 h) {
    return __builtin_bit_cast(float, (unsigned int)h << 16);
}
static __device__ __forceinline__ void split8(const float* v, bf16x8& h, bf16x8& l) {
#pragma unroll
    for (int j = 0; j < 8; ++j) {
        u16 hu = f2bf(v[j]);
        h[j] = (short)hu;
        l[j] = (short)f2bf(v[j] - bf2f(hu));
    }
}
#define MFMA(a, b, c) __builtin_amdgcn_mfma_f32_16x16x32_bf16(a, b, c, 0, 0, 0)

typedef const __attribute__((address_space(1))) void* gas_t;
typedef __attribute__((address_space(3))) void* las_t;
static __device__ __forceinline__ void gload16(const void* g, void* l) {
    __builtin_amdgcn_global_load_lds((gas_t)g, (las_t)l, 16, 0, 0);
}

// ---------------------------------------------------------------------------
// Kernel 1: per-32-panel prep, 1024 thr (16 waves).
// Blocks 0..127: prep. Blocks 128..1151 (fat only): x fp32->bf16 cast.
// T-recurrence runs in wave 0's registers (no block barriers).
// ---------------------------------------------------------------------------
__global__ __launch_bounds__(1024) void k_panelprep(const float* __restrict__ w,
                                                    const float* __restrict__ x,
                                                    u16* __restrict__ Yh,
                                                    u16* __restrict__ Yl,
                                                    u16* __restrict__ Mth,
                                                    u16* __restrict__ Mtl,
                                                    u16* __restrict__ xb) {
    __shared__ float Ylds[PW][516];      // 66048 B
    __shared__ float Sp[16][PW][36];     // 73728 B
    __shared__ float S_ls[PW][36];
    __shared__ float T_ls[PW][36];

    int bid = blockIdx.x;
    int t   = threadIdx.x;

    if (bid >= 128) {
        const int TOT8 = GROUP * BS * CH / 8;       // 2097152
        for (int i = (bid - 128) * 1024 + t; i < TOT8; i += 1024 * 1024) {
            const float4* s = (const float4*)(x + (size_t)i * 8);
            float4 a = s[0], b = s[1];
            u16x8 o;
            o[0] = f2bf(a.x); o[1] = f2bf(a.y); o[2] = f2bf(a.z); o[3] = f2bf(a.w);
            o[4] = f2bf(b.x); o[5] = f2bf(b.y); o[6] = f2bf(b.z); o[7] = f2bf(b.w);
            *(u16x8*)(xb + (size_t)i * 8) = o;
        }
        return;
    }

    int lane = t & 63;
    int wv   = t >> 6;           // 0..15
    int fr   = lane & 15;
    int kg   = lane >> 4;
    int g    = bid >> 4;
    int p    = bid & 15;
    int i0   = p * PW;

    // ---- stage Y[i][c] = w[g][c][i0+i] (transpose-read, 32x512) ----
    const float* wg = w + (size_t)g * CH * CH;
    for (int idx4 = t; idx4 < 4096; idx4 += 1024) {
        int c = idx4 >> 3, f4 = idx4 & 7;
        float4 v = *(const float4*)(wg + (size_t)c * CH + i0 + f4 * 4);
        Ylds[f4 * 4 + 0][c] = v.x;
        Ylds[f4 * 4 + 1][c] = v.y;
        Ylds[f4 * 4 + 2][c] = v.z;
        Ylds[f4 * 4 + 3][c] = v.w;
    }
    __syncthreads();

    // ---- S = Y Y^T via split MFMA; wave wv covers kk = wv ----
    {
        f32x4 sacc[2][2];
#pragma unroll
        for (int a = 0; a < 2; ++a)
#pragma unroll
            for (int b = 0; b < 2; ++b)
#pragma unroll
                for (int z = 0; z < 4; ++z) sacc[a][b][z] = 0.f;
        {
            int kk = wv;
            bf16x8 fh[2], fl[2];
#pragma unroll
            for (int h = 0; h < 2; ++h) {
                float a8[8];
                const float* src = &Ylds[h * 16 + fr][kk * 32 + kg * 8];
#pragma unroll
                for (int j = 0; j < 8; ++j) a8[j] = src[j];
                split8(a8, fh[h], fl[h]);
            }
#pragma unroll
            for (int a = 0; a < 2; ++a)
#pragma unroll
                for (int b = 0; b < 2; ++b) {
                    sacc[a][b] = MFMA(fh[a], fh[b], sacc[a][b]);
                    sacc[a][b] = MFMA(fh[a], fl[b], sacc[a][b]);
                    sacc[a][b] = MFMA(fl[a], fh[b], sacc[a][b]);
                }
        }
#pragma unroll
        for (int a = 0; a < 2; ++a)
#pragma unroll
            for (int b = 0; b < 2; ++b)
#pragma unroll
                for (int j = 0; j < 4; ++j)
                    Sp[wv][a * 16 + kg * 4 + j][b * 16 + fr] = sacc[a][b][j];
    }
    __syncthreads();
    for (int idx = t; idx < PW * PW; idx += 1024) {
        int r = idx >> 5, c = idx & 31;
        float s = 0.f;
#pragma unroll
        for (int q = 0; q < 16; ++q) s += Sp[q][r][c];
        S_ls[r][c] = s;
    }
    __syncthreads();

    // ---- T recurrence: wave 0 only, lane l = row of T in registers ----
    if (wv == 0) {
        float Trow[PW];
#pragma unroll
        for (int j = 0; j < PW; ++j) Trow[j] = 0.f;
        if (lane < PW) Trow[lane] = 2.0f / S_ls[lane][lane];
#pragma unroll
        for (int k = 1; k < PW; ++k) {
            float acc = 0.f;
#pragma unroll
            for (int j = 0; j < PW; ++j)
                if (j < k) acc += Trow[j] * S_ls[j][k];   // uniform-addr broadcast
            float bk = 2.0f / S_ls[k][k];
            if (lane < k) Trow[k] = -bk * acc;
        }
        if (lane < PW)
#pragma unroll
            for (int j = 0; j < PW; ++j) T_ls[lane][j] = Trow[j];
    }
    __syncthreads();

    // ---- M^T = Y^T * T^T (512x32, K=32): wave wv covers rf = 2wv..2wv+1 ----
    bf16x8 tbh[2], tbl[2];
#pragma unroll
    for (int cf = 0; cf < 2; ++cf) {
        float t8[8];
        const float* src = &T_ls[cf * 16 + fr][kg * 8];
#pragma unroll
        for (int j = 0; j < 8; ++j) t8[j] = src[j];
        split8(t8, tbh[cf], tbl[cf]);
    }
#pragma unroll
    for (int rfi = 0; rfi < 2; ++rfi) {
        int rf = 2 * wv + rfi;
        float a8[8];
#pragma unroll
        for (int j = 0; j < 8; ++j) a8[j] = Ylds[kg * 8 + j][rf * 16 + fr];
        bf16x8 ah, al;
        split8(a8, ah, al);
#pragma unroll
        for (int cf = 0; cf < 2; ++cf) {
            f32x4 m;
#pragma unroll
            for (int z = 0; z < 4; ++z) m[z] = 0.f;
            m = MFMA(ah, tbh[cf], m);
            m = MFMA(ah, tbl[cf], m);
            m = MFMA(al, tbh[cf], m);
#pragma unroll
            for (int j = 0; j < 4; ++j) {
                int c = rf * 16 + kg * 4 + j;
                int i = cf * 16 + fr;
                size_t off = ((size_t)g * CH + c) * CH + (i0 + i);
                u16 hu = f2bf(m[j]);
                Mth[off] = hu;
                Mtl[off] = f2bf(m[j] - bf2f(hu));
            }
        }
    }

    // ---- export Y panel bf16 hi/lo ----
    for (int idx = t; idx < PW * CH; idx += 1024) {
        int r = idx >> 9, c = idx & 511;
        float v = Ylds[r][c];
        size_t off = ((size_t)g * CH + i0 + r) * CH + c;
        u16 hu = f2bf(v);
        Yh[off] = hu;
        Yl[off] = f2bf(v - bf2f(hu));
    }
}

// ---------------------------------------------------------------------------
// Kernel 2 (x4 levels): WY merge, in-place, 256 blocks x 256 thr (4 waves).
// Block = (group, 8-row top strip). M_top' = M_top - (M_top Y_bot^T) M_bot.
// C-phase: waves K-split c (128 each) + LDS reduce. U-phase: waves split cols.
// Tops written disjoint; bottoms read-only at this level -> race-free.
// ---------------------------------------------------------------------------
template<int W>
__global__ __launch_bounds__(256) void k_combine(const u16* __restrict__ Yh,
                                                 const u16* __restrict__ Yl,
                                                 u16* __restrict__ Mth,
                                                 u16* __restrict__ Mtl) {
    __shared__ u16 MAh[8][520];
    __shared__ u16 MAl[8][520];
    __shared__ float Cpart[4][8][W + 4];
    __shared__ float Cl[8][W + 4];

    int bid = blockIdx.x;
    int t = threadIdx.x, lane = t & 63, wv = t >> 6;   // 4 waves
    int fr = lane & 15, kg = lane >> 4;
    int g = bid >> 5;
    int s = bid & 31;                    // 32 strips of 8 rows per group
    constexpr int SPT = W / 8;           // strips per pair-top
    int q  = s / SPT, rs = s % SPT;
    int i_top0 = 2 * q * W + rs * 8;
    int i_bot0 = 2 * q * W + W;

    const u16* Yh_g = Yh + (size_t)g * CH * CH;
    const u16* Yl_g = Yl + (size_t)g * CH * CH;
    u16* Mth_g = Mth + (size_t)g * CH * CH;
    u16* Mtl_g = Mtl + (size_t)g * CH * CH;

    // ---- stage M_top strip: MA[i<8][c] from Mt[c][i_top0..+8) ----
    for (int c = t; c < CH; c += 256) {
        bf16x8 hv = *(const bf16x8*)(Mth_g + (size_t)c * CH + i_top0);
        bf16x8 lv = *(const bf16x8*)(Mtl_g + (size_t)c * CH + i_top0);
#pragma unroll
        for (int j = 0; j < 8; ++j) {
            MAh[j][c] = (u16)hv[j];
            MAl[j][c] = (u16)lv[j];
        }
    }
    __syncthreads();

    // ---- C-phase: wave wv covers c in [wv*128, wv*128+128) ----
    constexpr int NF = W / 16;
    f32x4 accC[NF];
#pragma unroll
    for (int nf = 0; nf < NF; ++nf)
#pragma unroll
        for (int z = 0; z < 4; ++z) accC[nf][z] = 0.f;

#pragma unroll
    for (int ks = 0; ks < 4; ++ks) {
        int c0 = wv * 128 + ks * 32;
        bf16x8 ah, al;
#pragma unroll
        for (int j = 0; j < 8; ++j) { ah[j] = 0; al[j] = 0; }
        if (fr < 8) {
            ah = *(const bf16x8*)&MAh[fr][c0 + kg * 8];
            al = *(const bf16x8*)&MAl[fr][c0 + kg * 8];
        }
#pragma unroll
        for (int nf = 0; nf < NF; ++nf) {
            size_t yo = (size_t)(i_bot0 + nf * 16 + fr) * CH + c0 + kg * 8;
            bf16x8 bh = *(const bf16x8*)(Yh_g + yo);
            bf16x8 bl = *(const bf16x8*)(Yl_g + yo);
            accC[nf] = MFMA(ah, bh, accC[nf]);
            accC[nf] = MFMA(ah, bl, accC[nf]);
            accC[nf] = MFMA(al, bh, accC[nf]);
        }
    }
    if (kg < 2) {
#pragma unroll
        for (int nf = 0; nf < NF; ++nf)
#pragma unroll
            for (int j = 0; j < 4; ++j)
                Cpart[wv][kg * 4 + j][nf * 16 + fr] = accC[nf][j];
    }
    __syncthreads();
    for (int idx = t; idx < 8 * W; idx += 256) {
        int r = idx / W, c = idx - r * W;
        Cl[r][c] = Cpart[0][r][c] + Cpart[1][r][c] + Cpart[2][r][c] + Cpart[3][r][c];
    }
    __syncthreads();

    // ---- U-phase: wave wv covers cols [wv*128, +128): 8 col-frags ----
    f32x4 accU[8];
#pragma unroll
    for (int ni = 0; ni < 8; ++ni)
#pragma unroll
        for (int z = 0; z < 4; ++z) accU[ni][z] = 0.f;

#pragma unroll
    for (int ks2 = 0; ks2 < W / 32; ++ks2) {
        float a8[8];
#pragma unroll
        for (int j = 0; j < 8; ++j)
            a8[j] = (fr < 8) ? Cl[fr][ks2 * 32 + kg * 8 + j] : 0.f;
        bf16x8 ah2, al2;
        split8(a8, ah2, al2);
#pragma unroll
        for (int ni = 0; ni < 8; ++ni) {
            int c = wv * 128 + ni * 16 + fr;
            size_t mo = (size_t)c * CH + i_bot0 + ks2 * 32 + kg * 8;
            bf16x8 bh = *(const bf16x8*)(Mth_g + mo);
            bf16x8 bl = *(const bf16x8*)(Mtl_g + mo);
            accU[ni] = MFMA(ah2, bh, accU[ni]);
            accU[ni] = MFMA(ah2, bl, accU[ni]);
            accU[ni] = MFMA(al2, bh, accU[ni]);
        }
    }
    // ---- subtract into MA (rows kg*4+j < 8 -> kg<2) ----
    if (kg < 2) {
#pragma unroll
        for (int ni = 0; ni < 8; ++ni) {
            int c = wv * 128 + ni * 16 + fr;
#pragma unroll
            for (int jj = 0; jj < 4; ++jj) {
                int il = kg * 4 + jj;
                float ma = bf2f(MAh[il][c]) + bf2f(MAl[il][c]);
                float m2 = ma - accU[ni][jj];
                u16 hu = f2bf(m2);
                MAh[il][c] = hu;
                MAl[il][c] = f2bf(m2 - bf2f(hu));
            }
        }
    }
    __syncthreads();

    // ---- writeback strip to [c][i] layout ----
    for (int c = t; c < CH; c += 256) {
        bf16x8 hv, lv;
#pragma unroll
        for (int j = 0; j < 8; ++j) {
            hv[j] = (short)MAh[j][c];
            lv[j] = (short)MAl[j][c];
        }
        *(bf16x8*)(Mth_g + (size_t)c * CH + i_top0) = hv;
        *(bf16x8*)(Mtl_g + (size_t)c * CH + i_top0) = lv;
    }
}

// ---------------------------------------------------------------------------
// Kernel 3: Qt[g][d][c] = [I - w*M]^T. 512 blocks x 256 thr.
// ---------------------------------------------------------------------------
__global__ __launch_bounds__(256) void k_qbuild2(const float* __restrict__ w,
                                                 const u16* __restrict__ Mth,
                                                 const u16* __restrict__ Mtl,
                                                 u16* __restrict__ Qt) {
    int t = threadIdx.x, lane = t & 63, wv = t >> 6;
    int fr = lane & 15, kg = lane >> 4;
    int g  = blockIdx.x >> 6;
    int tm = (blockIdx.x >> 2) & 15, tn = blockIdx.x & 3;
    int c0 = tm * 32;
    int d0 = tn * 128 + wv * 32;

    const float* wg = w + (size_t)g * CH * CH;
    const u16* Mth_g = Mth + (size_t)g * CH * CH;
    const u16* Mtl_g = Mtl + (size_t)g * CH * CH;
    u16* Qt_g = Qt + (size_t)g * CH * CH;

    f32x4 acc[2][2];
#pragma unroll
    for (int mi = 0; mi < 2; ++mi)
#pragma unroll
        for (int ni = 0; ni < 2; ++ni)
#pragma unroll
            for (int z = 0; z < 4; ++z) acc[mi][ni][z] = 0.f;

    for (int ks = 0; ks < 16; ++ks) {
        bf16x8 ah[2], al[2], bh[2], bl[2];
#pragma unroll
        for (int mi = 0; mi < 2; ++mi) {
            const float* src = wg + (size_t)(c0 + mi * 16 + fr) * CH + ks * 32 + kg * 8;
            float4 v0 = *(const float4*)src;
            float4 v1 = *(const float4*)(src + 4);
            float a8[8] = {v0.x, v0.y, v0.z, v0.w, v1.x, v1.y, v1.z, v1.w};
            split8(a8, ah[mi], al[mi]);
        }
#pragma unroll
        for (int ni = 0; ni < 2; ++ni) {
            size_t mo = (size_t)(d0 + ni * 16 + fr) * CH + ks * 32 + kg * 8;
            bh[ni] = *(const bf16x8*)(Mth_g + mo);
            bl[ni] = *(const bf16x8*)(Mtl_g + mo);
        }
#pragma unroll
        for (int mi = 0; mi < 2; ++mi)
#pragma unroll
            for (int ni = 0; ni < 2; ++ni) {
                acc[mi][ni] = MFMA(ah[mi], bh[ni], acc[mi][ni]);
                acc[mi][ni] = MFMA(ah[mi], bl[ni], acc[mi][ni]);
                acc[mi][ni] = MFMA(al[mi], bh[ni], acc[mi][ni]);
            }
    }
#pragma unroll
    for (int mi = 0; mi < 2; ++mi)
#pragma unroll
        for (int ni = 0; ni < 2; ++ni) {
            int cb = c0 + mi * 16 + kg * 4;
            int d  = d0 + ni * 16 + fr;
            ushort4 h4;
            h4.x = f2bf(((cb + 0 == d) ? 1.0f : 0.0f) - acc[mi][ni][0]);
            h4.y = f2bf(((cb + 1 == d) ? 1.0f : 0.0f) - acc[mi][ni][1]);
            h4.z = f2bf(((cb + 2 == d) ? 1.0f : 0.0f) - acc[mi][ni][2]);
            h4.w = f2bf(((cb + 3 == d) ? 1.0f : 0.0f) - acc[mi][ni][3]);
            *(ushort4*)(Qt_g + (size_t)d * CH + cb) = h4;
        }
}

// ---------------------------------------------------------------------------
// Kernel 4 (m97-style, BK=64): out = xb @ Qt; both bf16 via global_load_lds.
// ---------------------------------------------------------------------------
__global__ __launch_bounds__(256) void k_gemm2(const u16* __restrict__ xb,
                                               const u16* __restrict__ Qt,
                                               float* __restrict__ out) {
    __shared__ u16 Ab[128 * 64];
    __shared__ u16 Bb[128 * 64];

    int bid = blockIdx.x;
    int g  = bid >> 7;
    int tn = (bid >> 5) & 3;
    int tm = bid & 31;

    int t    = threadIdx.x;
    int lane = t & 63;
    int wv   = t >> 6;
    int wr   = wv >> 1, wc = wv & 1;
    int fr   = lane & 15, kg = lane >> 4;

    const u16* xg  = xb + (size_t)g * BS * CH + (size_t)tm * 128 * CH;
    const u16* Qtg = Qt + (size_t)g * CH * CH + (size_t)tn * 128 * CH;
    float* og = out + (size_t)g * BS * CH + (size_t)tm * 128 * CH + (size_t)tn * 128;

    f32x4 acc[4][4];
#pragma unroll
    for (int mi = 0; mi < 4; ++mi)
#pragma unroll
        for (int ni = 0; ni < 4; ++ni)
#pragma unroll
            for (int z = 0; z < 4; ++z) acc[mi][ni][z] = 0.f;

    int srow8 = lane >> 3;
    int scol  = (lane & 7) * 8;

    for (int ks = 0; ks < 8; ++ks) {
        int k0 = ks * 64;
        __syncthreads();
#pragma unroll
        for (int si = 0; si < 4; ++si) {
            int s = wv * 4 + si;
            int row = s * 8 + srow8;
            gload16(xg  + (size_t)row * CH + k0 + scol, &Ab[s * 512]);
            gload16(Qtg + (size_t)row * CH + k0 + scol, &Bb[s * 512]);
        }
        __syncthreads();

#pragma unroll
        for (int kk = 0; kk < 2; ++kk) {
            bf16x8 af[4], bfr[4];
#pragma unroll
            for (int mi = 0; mi < 4; ++mi)
                af[mi] = *(const bf16x8*)&Ab[(wr * 64 + mi * 16 + fr) * 64 + kk * 32 + kg * 8];
#pragma unroll
            for (int ni = 0; ni < 4; ++ni)
                bfr[ni] = *(const bf16x8*)&Bb[(wc * 64 + ni * 16 + fr) * 64 + kk * 32 + kg * 8];
#pragma unroll
            for (int mi = 0; mi < 4; ++mi)
#pragma unroll
                for (int ni = 0; ni < 4; ++ni)
                    acc[mi][ni] = MFMA(af[mi], bfr[ni], acc[mi][ni]);
        }
    }

    int rg = lane >> 4;
#pragma unroll
    for (int mi = 0; mi < 4; ++mi)
#pragma unroll
        for (int ni = 0; ni < 4; ++ni)
#pragma unroll
            for (int rj = 0; rj < 4; ++rj) {
                int grow = wr * 64 + mi * 16 + rg * 4 + rj;
                int gcol = wc * 64 + ni * 16 + fr;
                og[(size_t)grow * CH + gcol] = acc[mi][ni][rj];
            }
}

// ---------------------------------------------------------------------------
// Fallback GEMM (fp32 A, in-staging convert) — round-5 verified.
// ---------------------------------------------------------------------------
#define LDP 40
__global__ __launch_bounds__(256) void k_gemm_f32(const float* __restrict__ x,
                                                  const u16* __restrict__ Qt,
                                                  float* __restrict__ out) {
    __shared__ u16 Al[128 * LDP];
    __shared__ u16 Bl[128 * LDP];

    int bid = blockIdx.x;
    int g  = bid >> 7;
    int tn = (bid >> 5) & 3;
    int tm = bid & 31;

    int t    = threadIdx.x;
    int lane = t & 63;
    int w    = t >> 6;
    int wr   = w >> 1, wc = w & 1;

    const float* xg = x + (size_t)g * BS * CH + (size_t)tm * 128 * CH;
    const u16* Qtg = Qt + (size_t)g * CH * CH + (size_t)tn * 128 * CH;
    float* og = out + (size_t)g * BS * CH + (size_t)tm * 128 * CH + (size_t)tn * 128;

    f32x4 acc[4][4];
#pragma unroll
    for (int mi = 0; mi < 4; ++mi)
#pragma unroll
        for (int ni = 0; ni < 4; ++ni)
#pragma unroll
            for (int z = 0; z < 4; ++z) acc[mi][ni][z] = 0.f;

    int a_k4 = t & 7;
    int a_r  = t >> 3;
    int b_n  = t & 127;
    int b_kh = t >> 7;
    int fr = lane & 15, kg = lane >> 4;

    for (int ks = 0; ks < 16; ++ks) {
        int k0 = ks * 32;
        __syncthreads();
#pragma unroll
        for (int rr = 0; rr < 4; ++rr) {
            int r = a_r + 32 * rr;
            float4 v = *(const float4*)(xg + (size_t)r * CH + k0 + a_k4 * 4);
            ushort4 h;
            h.x = f2bf(v.x); h.y = f2bf(v.y); h.z = f2bf(v.z); h.w = f2bf(v.w);
            *(ushort4*)(&Al[r * LDP + a_k4 * 4]) = h;
        }
        {
            const u16* src = Qtg + (size_t)b_n * CH + k0 + b_kh * 16;
            u16x8 lo = *(const u16x8*)src;
            u16x8 hi = *(const u16x8*)(src + 8);
            *(u16x8*)(&Bl[b_n * LDP + b_kh * 16]) = lo;
            *(u16x8*)(&Bl[b_n * LDP + b_kh * 16 + 8]) = hi;
        }
        __syncthreads();
        bf16x8 af[4], bfr[4];
#pragma unroll
        for (int mi = 0; mi < 4; ++mi)
            af[mi] = *(const bf16x8*)(&Al[(wr * 64 + mi * 16 + fr) * LDP + kg * 8]);
#pragma unroll
        for (int ni = 0; ni < 4; ++ni)
            bfr[ni] = *(const bf16x8*)(&Bl[(wc * 64 + ni * 16 + fr) * LDP + kg * 8]);
#pragma unroll
        for (int mi = 0; mi < 4; ++mi)
#pragma unroll
            for (int ni = 0; ni < 4; ++ni)
                acc[mi][ni] = MFMA(af[mi], bfr[ni], acc[mi][ni]);
    }

    int rg = lane >> 4;
#pragma unroll
    for (int mi = 0; mi < 4; ++mi)
#pragma unroll
        for (int ni = 0; ni < 4; ++ni)
#pragma unroll
            for (int rj = 0; rj < 4; ++rj) {
                int grow = wr * 64 + mi * 16 + rg * 4 + rj;
                int gcol = wc * 64 + ni * 16 + fr;
                og[(size_t)grow * CH + gcol] = acc[mi][ni][rj];
            }
}

// ---------------------------------------------------------------------------
extern "C" void kernel_launch(void* const* d_in, const int* in_sizes, int n_in,
                              void* d_out, int out_size, void* d_ws, size_t ws_size,
                              hipStream_t stream) {
    const float* x = (const float*)d_in[0];   // (8, 4096, 512)
    const float* w = (const float*)d_in[1];   // (8, 512, 512)
    float* out = (float*)d_out;

    // scratch carved from d_out (64 MiB; all dead before GEMM writes it):
    char* ob = (char*)d_out;
    u16* Yh  = (u16*)ob;                      // [0, 4MB)
    u16* Yl  = (u16*)(ob + (4u  << 20));      // [4, 8)
    u16* Mth = (u16*)(ob + (8u  << 20));      // [8, 12)
    u16* Mtl = (u16*)(ob + (12u << 20));      // [12, 16)

    // d_ws: fat = xb (32 MB) + Qt (4 MB); else Qt only.
    int fat = (ws_size >= ((32u << 20) + (4u << 20))) ? 1 : 0;
    u16* xbp = (u16*)d_ws;
    u16* Qt  = fat ? (u16*)((char*)d_ws + (32u << 20)) : (u16*)d_ws;

    k_panelprep<<<dim3(fat ? 1152 : 128), dim3(1024), 0, stream>>>(w, x, Yh, Yl, Mth, Mtl, xbp);
    k_combine<32><<<dim3(256), dim3(256), 0, stream>>>(Yh, Yl, Mth, Mtl);
    k_combine<64><<<dim3(256), dim3(256), 0, stream>>>(Yh, Yl, Mth, Mtl);
    k_combine<128><<<dim3(256), dim3(256), 0, stream>>>(Yh, Yl, Mth, Mtl);
    k_combine<256><<<dim3(256), dim3(256), 0, stream>>>(Yh, Yl, Mth, Mtl);
    k_qbuild2<<<dim3(512), dim3(256), 0, stream>>>(w, Mth, Mtl, Qt);
    if (fat)
        k_gemm2<<<dim3(1024), dim3(256), 0, stream>>>(xbp, Qt, out);
    else
        k_gemm_f32<<<dim3(1024), dim3(256), 0, stream>>>(x, Qt, out);
}

// Round 10
// 200.023 us; speedup vs baseline: 1.0797x; 1.0025x over previous
//
#include <hip/hip_runtime.h>

#define GROUP 8
#define BS 4096
#define CH 512
#define PW 32
#define NPANEL 16

typedef __attribute__((ext_vector_type(4))) float f32x4;
typedef __attribute__((ext_vector_type(8))) short bf16x8;
typedef __attribute__((ext_vector_type(8))) unsigned short u16x8;
typedef unsigned short u16;

static __device__ __forceinline__ u16 f2bf(float f) {
    unsigned int u = __builtin_bit_cast(unsigned int, f);
    u += 0x7FFFu + ((u >> 16) & 1u);   // RNE
    return (u16)(u >> 16);
}
static __device__ __forceinline__ float bf2f(u16 h) {
    return __builtin_bit_cast(float, (unsigned int)h << 16);
}
static __device__ __forceinline__ void split8(const float* v, bf16x8& h, bf16x8& l) {
#pragma unroll
    for (int j = 0; j < 8; ++j) {
        u16 hu = f2bf(v[j]);
        h[j] = (short)hu;
        l[j] = (short)f2bf(v[j] - bf2f(hu));
    }
}
#define MFMA(a, b, c) __builtin_amdgcn_mfma_f32_16x16x32_bf16(a, b, c, 0, 0, 0)

typedef const __attribute__((address_space(1))) void* gas_t;
typedef __attribute__((address_space(3))) void* las_t;
static __device__ __forceinline__ void gload16(const void* g, void* l) {
    __builtin_amdgcn_global_load_lds((gas_t)g, (las_t)l, 16, 0, 0);
}

// ---------------------------------------------------------------------------
// Kernel 1: per-32-panel prep, 1024 thr (16 waves). Blocks 0..127: prep.
// Blocks 128..1151 (fat only): x fp32->bf16 cast. (round-9 verified)
// ---------------------------------------------------------------------------
__global__ __launch_bounds__(1024) void k_panelprep(const float* __restrict__ w,
                                                    const float* __restrict__ x,
                                                    u16* __restrict__ Yh,
                                                    u16* __restrict__ Yl,
                                                    u16* __restrict__ Mth,
                                                    u16* __restrict__ Mtl,
                                                    u16* __restrict__ xb) {
    __shared__ float Ylds[PW][516];
    __shared__ float Sp[16][PW][36];
    __shared__ float S_ls[PW][36];
    __shared__ float T_ls[PW][36];

    int bid = blockIdx.x;
    int t   = threadIdx.x;

    if (bid >= 128) {
        const int TOT8 = GROUP * BS * CH / 8;
        for (int i = (bid - 128) * 1024 + t; i < TOT8; i += 1024 * 1024) {
            const float4* s = (const float4*)(x + (size_t)i * 8);
            float4 a = s[0], b = s[1];
            u16x8 o;
            o[0] = f2bf(a.x); o[1] = f2bf(a.y); o[2] = f2bf(a.z); o[3] = f2bf(a.w);
            o[4] = f2bf(b.x); o[5] = f2bf(b.y); o[6] = f2bf(b.z); o[7] = f2bf(b.w);
            *(u16x8*)(xb + (size_t)i * 8) = o;
        }
        return;
    }

    int lane = t & 63;
    int wv   = t >> 6;
    int fr   = lane & 15;
    int kg   = lane >> 4;
    int g    = bid >> 4;
    int p    = bid & 15;
    int i0   = p * PW;

    const float* wg = w + (size_t)g * CH * CH;
    for (int idx4 = t; idx4 < 4096; idx4 += 1024) {
        int c = idx4 >> 3, f4 = idx4 & 7;
        float4 v = *(const float4*)(wg + (size_t)c * CH + i0 + f4 * 4);
        Ylds[f4 * 4 + 0][c] = v.x;
        Ylds[f4 * 4 + 1][c] = v.y;
        Ylds[f4 * 4 + 2][c] = v.z;
        Ylds[f4 * 4 + 3][c] = v.w;
    }
    __syncthreads();

    {
        f32x4 sacc[2][2];
#pragma unroll
        for (int a = 0; a < 2; ++a)
#pragma unroll
            for (int b = 0; b < 2; ++b)
#pragma unroll
                for (int z = 0; z < 4; ++z) sacc[a][b][z] = 0.f;
        {
            int kk = wv;
            bf16x8 fh[2], fl[2];
#pragma unroll
            for (int h = 0; h < 2; ++h) {
                float a8[8];
                const float* src = &Ylds[h * 16 + fr][kk * 32 + kg * 8];
#pragma unroll
                for (int j = 0; j < 8; ++j) a8[j] = src[j];
                split8(a8, fh[h], fl[h]);
            }
#pragma unroll
            for (int a = 0; a < 2; ++a)
#pragma unroll
                for (int b = 0; b < 2; ++b) {
                    sacc[a][b] = MFMA(fh[a], fh[b], sacc[a][b]);
                    sacc[a][b] = MFMA(fh[a], fl[b], sacc[a][b]);
                    sacc[a][b] = MFMA(fl[a], fh[b], sacc[a][b]);
                }
        }
#pragma unroll
        for (int a = 0; a < 2; ++a)
#pragma unroll
            for (int b = 0; b < 2; ++b)
#pragma unroll
                for (int j = 0; j < 4; ++j)
                    Sp[wv][a * 16 + kg * 4 + j][b * 16 + fr] = sacc[a][b][j];
    }
    __syncthreads();
    for (int idx = t; idx < PW * PW; idx += 1024) {
        int r = idx >> 5, c = idx & 31;
        float s = 0.f;
#pragma unroll
        for (int q = 0; q < 16; ++q) s += Sp[q][r][c];
        S_ls[r][c] = s;
    }
    __syncthreads();

    if (wv == 0) {
        float Trow[PW];
#pragma unroll
        for (int j = 0; j < PW; ++j) Trow[j] = 0.f;
        if (lane < PW) Trow[lane] = 2.0f / S_ls[lane][lane];
#pragma unroll
        for (int k = 1; k < PW; ++k) {
            float acc = 0.f;
#pragma unroll
            for (int j = 0; j < PW; ++j)
                if (j < k) acc += Trow[j] * S_ls[j][k];
            float bk = 2.0f / S_ls[k][k];
            if (lane < k) Trow[k] = -bk * acc;
        }
        if (lane < PW)
#pragma unroll
            for (int j = 0; j < PW; ++j) T_ls[lane][j] = Trow[j];
    }
    __syncthreads();

    bf16x8 tbh[2], tbl[2];
#pragma unroll
    for (int cf = 0; cf < 2; ++cf) {
        float t8[8];
        const float* src = &T_ls[cf * 16 + fr][kg * 8];
#pragma unroll
        for (int j = 0; j < 8; ++j) t8[j] = src[j];
        split8(t8, tbh[cf], tbl[cf]);
    }
#pragma unroll
    for (int rfi = 0; rfi < 2; ++rfi) {
        int rf = 2 * wv + rfi;
        float a8[8];
#pragma unroll
        for (int j = 0; j < 8; ++j) a8[j] = Ylds[kg * 8 + j][rf * 16 + fr];
        bf16x8 ah, al;
        split8(a8, ah, al);
#pragma unroll
        for (int cf = 0; cf < 2; ++cf) {
            f32x4 m;
#pragma unroll
            for (int z = 0; z < 4; ++z) m[z] = 0.f;
            m = MFMA(ah, tbh[cf], m);
            m = MFMA(ah, tbl[cf], m);
            m = MFMA(al, tbh[cf], m);
#pragma unroll
            for (int j = 0; j < 4; ++j) {
                int c = rf * 16 + kg * 4 + j;
                int i = cf * 16 + fr;
                size_t off = ((size_t)g * CH + c) * CH + (i0 + i);
                u16 hu = f2bf(m[j]);
                Mth[off] = hu;
                Mtl[off] = f2bf(m[j] - bf2f(hu));
            }
        }
    }

    for (int idx = t; idx < PW * CH; idx += 1024) {
        int r = idx >> 9, c = idx & 511;
        float v = Ylds[r][c];
        size_t off = ((size_t)g * CH + i0 + r) * CH + c;
        u16 hu = f2bf(v);
        Yh[off] = hu;
        Yl[off] = f2bf(v - bf2f(hu));
    }
}

// ---------------------------------------------------------------------------
// Kernel 2 (x4 levels): WY merge, in-place, 256 blocks x 256 thr (4 waves).
// Same math as round-9 (bit-identical); loads BATCHED 4-wide so each L2
// round-trip covers 4 fragments instead of 1.
// ---------------------------------------------------------------------------
template<int W>
__global__ __launch_bounds__(256) void k_combine(const u16* __restrict__ Yh,
                                                 const u16* __restrict__ Yl,
                                                 u16* __restrict__ Mth,
                                                 u16* __restrict__ Mtl) {
    __shared__ u16 MAh[8][520];
    __shared__ u16 MAl[8][520];
    __shared__ float Cpart[4][8][W + 4];
    __shared__ float Cl[8][W + 4];

    int bid = blockIdx.x;
    int t = threadIdx.x, lane = t & 63, wv = t >> 6;
    int fr = lane & 15, kg = lane >> 4;
    int g = bid >> 5;
    int s = bid & 31;
    constexpr int SPT = W / 8;
    int q  = s / SPT, rs = s % SPT;
    int i_top0 = 2 * q * W + rs * 8;
    int i_bot0 = 2 * q * W + W;

    const u16* Yh_g = Yh + (size_t)g * CH * CH;
    const u16* Yl_g = Yl + (size_t)g * CH * CH;
    u16* Mth_g = Mth + (size_t)g * CH * CH;
    u16* Mtl_g = Mtl + (size_t)g * CH * CH;

    for (int c = t; c < CH; c += 256) {
        bf16x8 hv = *(const bf16x8*)(Mth_g + (size_t)c * CH + i_top0);
        bf16x8 lv = *(const bf16x8*)(Mtl_g + (size_t)c * CH + i_top0);
#pragma unroll
        for (int j = 0; j < 8; ++j) {
            MAh[j][c] = (u16)hv[j];
            MAl[j][c] = (u16)lv[j];
        }
    }
    __syncthreads();

    // ---- C-phase: wave wv covers c in [wv*128, +128); batch-4 fragment loads
    constexpr int NF = W / 16;
    f32x4 accC[NF];
#pragma unroll
    for (int nf = 0; nf < NF; ++nf)
#pragma unroll
        for (int z = 0; z < 4; ++z) accC[nf][z] = 0.f;

#pragma unroll
    for (int ks = 0; ks < 4; ++ks) {
        int c0 = wv * 128 + ks * 32;
        bf16x8 ah, al;
#pragma unroll
        for (int j = 0; j < 8; ++j) { ah[j] = 0; al[j] = 0; }
        if (fr < 8) {
            ah = *(const bf16x8*)&MAh[fr][c0 + kg * 8];
            al = *(const bf16x8*)&MAl[fr][c0 + kg * 8];
        }
#pragma unroll
        for (int nfb = 0; nfb < NF; nfb += 4) {
            bf16x8 bh[4], bl[4];
#pragma unroll
            for (int u = 0; u < 4; ++u) {
                int nf = nfb + u;
                if (nf < NF) {
                    size_t yo = (size_t)(i_bot0 + nf * 16 + fr) * CH + c0 + kg * 8;
                    bh[u] = *(const bf16x8*)(Yh_g + yo);
                    bl[u] = *(const bf16x8*)(Yl_g + yo);
                }
            }
#pragma unroll
            for (int u = 0; u < 4; ++u) {
                int nf = nfb + u;
                if (nf < NF) {
                    accC[nf] = MFMA(ah, bh[u], accC[nf]);
                    accC[nf] = MFMA(ah, bl[u], accC[nf]);
                    accC[nf] = MFMA(al, bh[u], accC[nf]);
                }
            }
        }
    }
    if (kg < 2) {
#pragma unroll
        for (int nf = 0; nf < NF; ++nf)
#pragma unroll
            for (int j = 0; j < 4; ++j)
                Cpart[wv][kg * 4 + j][nf * 16 + fr] = accC[nf][j];
    }
    __syncthreads();
    for (int idx = t; idx < 8 * W; idx += 256) {
        int r = idx / W, c = idx - r * W;
        Cl[r][c] = Cpart[0][r][c] + Cpart[1][r][c] + Cpart[2][r][c] + Cpart[3][r][c];
    }
    __syncthreads();

    // ---- U-phase: wave wv covers cols [wv*128, +128); batch-4 loads ----
    f32x4 accU[8];
#pragma unroll
    for (int ni = 0; ni < 8; ++ni)
#pragma unroll
        for (int z = 0; z < 4; ++z) accU[ni][z] = 0.f;

#pragma unroll
    for (int ks2 = 0; ks2 < W / 32; ++ks2) {
        float a8[8];
#pragma unroll
        for (int j = 0; j < 8; ++j)
            a8[j] = (fr < 8) ? Cl[fr][ks2 * 32 + kg * 8 + j] : 0.f;
        bf16x8 ah2, al2;
        split8(a8, ah2, al2);
#pragma unroll
        for (int nib = 0; nib < 8; nib += 4) {
            bf16x8 bh[4], bl[4];
#pragma unroll
            for (int u = 0; u < 4; ++u) {
                int c = wv * 128 + (nib + u) * 16 + fr;
                size_t mo = (size_t)c * CH + i_bot0 + ks2 * 32 + kg * 8;
                bh[u] = *(const bf16x8*)(Mth_g + mo);
                bl[u] = *(const bf16x8*)(Mtl_g + mo);
            }
#pragma unroll
            for (int u = 0; u < 4; ++u) {
                int ni = nib + u;
                accU[ni] = MFMA(ah2, bh[u], accU[ni]);
                accU[ni] = MFMA(ah2, bl[u], accU[ni]);
                accU[ni] = MFMA(al2, bh[u], accU[ni]);
            }
        }
    }
    if (kg < 2) {
#pragma unroll
        for (int ni = 0; ni < 8; ++ni) {
            int c = wv * 128 + ni * 16 + fr;
#pragma unroll
            for (int jj = 0; jj < 4; ++jj) {
                int il = kg * 4 + jj;
                float ma = bf2f(MAh[il][c]) + bf2f(MAl[il][c]);
                float m2 = ma - accU[ni][jj];
                u16 hu = f2bf(m2);
                MAh[il][c] = hu;
                MAl[il][c] = f2bf(m2 - bf2f(hu));
            }
        }
    }
    __syncthreads();

    for (int c = t; c < CH; c += 256) {
        bf16x8 hv, lv;
#pragma unroll
        for (int j = 0; j < 8; ++j) {
            hv[j] = (short)MAh[j][c];
            lv[j] = (short)MAl[j][c];
        }
        *(bf16x8*)(Mth_g + (size_t)c * CH + i_top0) = hv;
        *(bf16x8*)(Mtl_g + (size_t)c * CH + i_top0) = lv;
    }
}

// ---------------------------------------------------------------------------
// Kernel 3: Qt[g][d][c] = [I - w*M]^T. 512 blocks x 256 thr. (round-9)
// ---------------------------------------------------------------------------
__global__ __launch_bounds__(256) void k_qbuild2(const float* __restrict__ w,
                                                 const u16* __restrict__ Mth,
                                                 const u16* __restrict__ Mtl,
                                                 u16* __restrict__ Qt) {
    int t = threadIdx.x, lane = t & 63, wv = t >> 6;
    int fr = lane & 15, kg = lane >> 4;
    int g  = blockIdx.x >> 6;
    int tm = (blockIdx.x >> 2) & 15, tn = blockIdx.x & 3;
    int c0 = tm * 32;
    int d0 = tn * 128 + wv * 32;

    const float* wg = w + (size_t)g * CH * CH;
    const u16* Mth_g = Mth + (size_t)g * CH * CH;
    const u16* Mtl_g = Mtl + (size_t)g * CH * CH;
    u16* Qt_g = Qt + (size_t)g * CH * CH;

    f32x4 acc[2][2];
#pragma unroll
    for (int mi = 0; mi < 2; ++mi)
#pragma unroll
        for (int ni = 0; ni < 2; ++ni)
#pragma unroll
            for (int z = 0; z < 4; ++z) acc[mi][ni][z] = 0.f;

    for (int ks = 0; ks < 16; ++ks) {
        bf16x8 ah[2], al[2], bh[2], bl[2];
#pragma unroll
        for (int mi = 0; mi < 2; ++mi) {
            const float* src = wg + (size_t)(c0 + mi * 16 + fr) * CH + ks * 32 + kg * 8;
            float4 v0 = *(const float4*)src;
            float4 v1 = *(const float4*)(src + 4);
            float a8[8] = {v0.x, v0.y, v0.z, v0.w, v1.x, v1.y, v1.z, v1.w};
            split8(a8, ah[mi], al[mi]);
        }
#pragma unroll
        for (int ni = 0; ni < 2; ++ni) {
            size_t mo = (size_t)(d0 + ni * 16 + fr) * CH + ks * 32 + kg * 8;
            bh[ni] = *(const bf16x8*)(Mth_g + mo);
            bl[ni] = *(const bf16x8*)(Mtl_g + mo);
        }
#pragma unroll
        for (int mi = 0; mi < 2; ++mi)
#pragma unroll
            for (int ni = 0; ni < 2; ++ni) {
                acc[mi][ni] = MFMA(ah[mi], bh[ni], acc[mi][ni]);
                acc[mi][ni] = MFMA(ah[mi], bl[ni], acc[mi][ni]);
                acc[mi][ni] = MFMA(al[mi], bh[ni], acc[mi][ni]);
            }
    }
#pragma unroll
    for (int mi = 0; mi < 2; ++mi)
#pragma unroll
        for (int ni = 0; ni < 2; ++ni) {
            int cb = c0 + mi * 16 + kg * 4;
            int d  = d0 + ni * 16 + fr;
            ushort4 h4;
            h4.x = f2bf(((cb + 0 == d) ? 1.0f : 0.0f) - acc[mi][ni][0]);
            h4.y = f2bf(((cb + 1 == d) ? 1.0f : 0.0f) - acc[mi][ni][1]);
            h4.z = f2bf(((cb + 2 == d) ? 1.0f : 0.0f) - acc[mi][ni][2]);
            h4.w = f2bf(((cb + 3 == d) ? 1.0f : 0.0f) - acc[mi][ni][3]);
            *(ushort4*)(Qt_g + (size_t)d * CH + cb) = h4;
        }
}

// ---------------------------------------------------------------------------
// Kernel 4: 2-phase double-buffered GEMM (T3-min). out = xb @ Qt.
// XCD-chunked swizzle (group per XCD) + tn-inner decode for A-tile L2 reuse.
// ---------------------------------------------------------------------------
__global__ __launch_bounds__(256) void k_gemm2(const u16* __restrict__ xb,
                                               const u16* __restrict__ Qt,
                                               float* __restrict__ out) {
    __shared__ u16 Ab[2][128 * 64];
    __shared__ u16 Bb[2][128 * 64];

    int bid0 = blockIdx.x;
    int wg = (bid0 & 7) * 128 + (bid0 >> 3);  // bijective XCD chunk (1024%8==0)
    int g  = wg >> 7;
    int r  = wg & 127;
    int tm = r >> 2;      // 4 consecutive wg share tm -> A-tile reuse in-XCD
    int tn = r & 3;

    int t    = threadIdx.x;
    int lane = t & 63;
    int wv   = t >> 6;
    int wr   = wv >> 1, wc = wv & 1;
    int fr   = lane & 15, kg = lane >> 4;

    const u16* xg  = xb + (size_t)g * BS * CH + (size_t)tm * 128 * CH;
    const u16* Qtg = Qt + (size_t)g * CH * CH + (size_t)tn * 128 * CH;
    float* og = out + (size_t)g * BS * CH + (size_t)tm * 128 * CH + (size_t)tn * 128;

    f32x4 acc[4][4];
#pragma unroll
    for (int mi = 0; mi < 4; ++mi)
#pragma unroll
        for (int ni = 0; ni < 4; ++ni)
#pragma unroll
            for (int z = 0; z < 4; ++z) acc[mi][ni][z] = 0.f;

    int srow8 = lane >> 3;
    int scol  = (lane & 7) * 8;

    auto STAGE = [&](int p, int ks) {
        int k0 = ks * 64;
#pragma unroll
        for (int si = 0; si < 4; ++si) {
            int seg = wv * 4 + si;
            int row = seg * 8 + srow8;
            gload16(xg  + (size_t)row * CH + k0 + scol, &Ab[p][seg * 512]);
            gload16(Qtg + (size_t)row * CH + k0 + scol, &Bb[p][seg * 512]);
        }
    };

    STAGE(0, 0);
    __syncthreads();                       // buf0 ready

    for (int ks = 0; ks < 8; ++ks) {
        int cur = ks & 1;
        if (ks < 7) STAGE(cur ^ 1, ks + 1);   // loads fly under the MFMAs below
#pragma unroll
        for (int kk = 0; kk < 2; ++kk) {
            bf16x8 af[4], bfr[4];
#pragma unroll
            for (int mi = 0; mi < 4; ++mi)
                af[mi] = *(const bf16x8*)&Ab[cur][(wr * 64 + mi * 16 + fr) * 64 + kk * 32 + kg * 8];
#pragma unroll
            for (int ni = 0; ni < 4; ++ni)
                bfr[ni] = *(const bf16x8*)&Bb[cur][(wc * 64 + ni * 16 + fr) * 64 + kk * 32 + kg * 8];
#pragma unroll
            for (int mi = 0; mi < 4; ++mi)
#pragma unroll
                for (int ni = 0; ni < 4; ++ni)
                    acc[mi][ni] = MFMA(af[mi], bfr[ni], acc[mi][ni]);
        }
        __syncthreads();                   // drains next-buf loads; guards reuse
    }

    int rg = lane >> 4;
#pragma unroll
    for (int mi = 0; mi < 4; ++mi)
#pragma unroll
        for (int ni = 0; ni < 4; ++ni)
#pragma unroll
            for (int rj = 0; rj < 4; ++rj) {
                int grow = wr * 64 + mi * 16 + rg * 4 + rj;
                int gcol = wc * 64 + ni * 16 + fr;
                og[(size_t)grow * CH + gcol] = acc[mi][ni][rj];
            }
}

// ---------------------------------------------------------------------------
// Fallback GEMM (fp32 A, in-staging convert) — round-5 verified.
// ---------------------------------------------------------------------------
#define LDP 40
__global__ __launch_bounds__(256) void k_gemm_f32(const float* __restrict__ x,
                                                  const u16* __restrict__ Qt,
                                                  float* __restrict__ out) {
    __shared__ u16 Al[128 * LDP];
    __shared__ u16 Bl[128 * LDP];

    int bid = blockIdx.x;
    int g  = bid >> 7;
    int tn = (bid >> 5) & 3;
    int tm = bid & 31;

    int t    = threadIdx.x;
    int lane = t & 63;
    int w    = t >> 6;
    int wr   = w >> 1, wc = w & 1;

    const float* xg = x + (size_t)g * BS * CH + (size_t)tm * 128 * CH;
    const u16* Qtg = Qt + (size_t)g * CH * CH + (size_t)tn * 128 * CH;
    float* og = out + (size_t)g * BS * CH + (size_t)tm * 128 * CH + (size_t)tn * 128;

    f32x4 acc[4][4];
#pragma unroll
    for (int mi = 0; mi < 4; ++mi)
#pragma unroll
        for (int ni = 0; ni < 4; ++ni)
#pragma unroll
            for (int z = 0; z < 4; ++z) acc[mi][ni][z] = 0.f;

    int a_k4 = t & 7;
    int a_r  = t >> 3;
    int b_n  = t & 127;
    int b_kh = t >> 7;
    int fr = lane & 15, kg = lane >> 4;

    for (int ks = 0; ks < 16; ++ks) {
        int k0 = ks * 32;
        __syncthreads();
#pragma unroll
        for (int rr = 0; rr < 4; ++rr) {
            int r = a_r + 32 * rr;
            float4 v = *(const float4*)(xg + (size_t)r * CH + k0 + a_k4 * 4);
            ushort4 h;
            h.x = f2bf(v.x); h.y = f2bf(v.y); h.z = f2bf(v.z); h.w = f2bf(v.w);
            *(ushort4*)(&Al[r * LDP + a_k4 * 4]) = h;
        }
        {
            const u16* src = Qtg + (size_t)b_n * CH + k0 + b_kh * 16;
            u16x8 lo = *(const u16x8*)src;
            u16x8 hi = *(const u16x8*)(src + 8);
            *(u16x8*)(&Bl[b_n * LDP + b_kh * 16]) = lo;
            *(u16x8*)(&Bl[b_n * LDP + b_kh * 16 + 8]) = hi;
        }
        __syncthreads();
        bf16x8 af[4], bfr[4];
#pragma unroll
        for (int mi = 0; mi < 4; ++mi)
            af[mi] = *(const bf16x8*)(&Al[(wr * 64 + mi * 16 + fr) * LDP + kg * 8]);
#pragma unroll
        for (int ni = 0; ni < 4; ++ni)
            bfr[ni] = *(const bf16x8*)(&Bl[(wc * 64 + ni * 16 + fr) * LDP + kg * 8]);
#pragma unroll
        for (int mi = 0; mi < 4; ++mi)
#pragma unroll
            for (int ni = 0; ni < 4; ++ni)
                acc[mi][ni] = MFMA(af[mi], bfr[ni], acc[mi][ni]);
    }

    int rg = lane >> 4;
#pragma unroll
    for (int mi = 0; mi < 4; ++mi)
#pragma unroll
        for (int ni = 0; ni < 4; ++ni)
#pragma unroll
            for (int rj = 0; rj < 4; ++rj) {
                int grow = wr * 64 + mi * 16 + rg * 4 + rj;
                int gcol = wc * 64 + ni * 16 + fr;
                og[(size_t)grow * CH + gcol] = acc[mi][ni][rj];
            }
}

// ---------------------------------------------------------------------------
extern "C" void kernel_launch(void* const* d_in, const int* in_sizes, int n_in,
                              void* d_out, int out_size, void* d_ws, size_t ws_size,
                              hipStream_t stream) {
    const float* x = (const float*)d_in[0];   // (8, 4096, 512)
    const float* w = (const float*)d_in[1];   // (8, 512, 512)
    float* out = (float*)d_out;

    char* ob = (char*)d_out;
    u16* Yh  = (u16*)ob;                      // [0, 4MB)
    u16* Yl  = (u16*)(ob + (4u  << 20));      // [4, 8)
    u16* Mth = (u16*)(ob + (8u  << 20));      // [8, 12)
    u16* Mtl = (u16*)(ob + (12u << 20));      // [12, 16)

    int fat = (ws_size >= ((32u << 20) + (4u << 20))) ? 1 : 0;
    u16* xbp = (u16*)d_ws;
    u16* Qt  = fat ? (u16*)((char*)d_ws + (32u << 20)) : (u16*)d_ws;

    k_panelprep<<<dim3(fat ? 1152 : 128), dim3(1024), 0, stream>>>(w, x, Yh, Yl, Mth, Mtl, xbp);
    k_combine<32><<<dim3(256), dim3(256), 0, stream>>>(Yh, Yl, Mth, Mtl);
    k_combine<64><<<dim3(256), dim3(256), 0, stream>>>(Yh, Yl, Mth, Mtl);
    k_combine<128><<<dim3(256), dim3(256), 0, stream>>>(Yh, Yl, Mth, Mtl);
    k_combine<256><<<dim3(256), dim3(256), 0, stream>>>(Yh, Yl, Mth, Mtl);
    k_qbuild2<<<dim3(512), dim3(256), 0, stream>>>(w, Mth, Mtl, Qt);
    if (fat)
        k_gemm2<<<dim3(1024), dim3(256), 0, stream>>>(xbp, Qt, out);
    else
        k_gemm_f32<<<dim3(1024), dim3(256), 0, stream>>>(x, Qt, out);
}

// Round 11
// 165.464 us; speedup vs baseline: 1.3053x; 1.2089x over previous
//
#include <hip/hip_runtime.h>

#define GROUP 8
#define BS 4096
#define CH 512
#define PW 32
#define NPANEL 16

typedef __attribute__((ext_vector_type(4))) float f32x4;
typedef __attribute__((ext_vector_type(8))) short bf16x8;
typedef __attribute__((ext_vector_type(8))) unsigned short u16x8;
typedef unsigned short u16;

static __device__ __forceinline__ u16 f2bf(float f) {
    unsigned int u = __builtin_bit_cast(unsigned int, f);
    u += 0x7FFFu + ((u >> 16) & 1u);   // RNE
    return (u16)(u >> 16);
}
static __device__ __forceinline__ float bf2f(u16 h) {
    return __builtin_bit_cast(float, (unsigned int)h << 16);
}
static __device__ __forceinline__ void split8(const float* v, bf16x8& h, bf16x8& l) {
#pragma unroll
    for (int j = 0; j < 8; ++j) {
        u16 hu = f2bf(v[j]);
        h[j] = (short)hu;
        l[j] = (short)f2bf(v[j] - bf2f(hu));
    }
}
#define MFMA(a, b, c) __builtin_amdgcn_mfma_f32_16x16x32_bf16(a, b, c, 0, 0, 0)

typedef const __attribute__((address_space(1))) void* gas_t;
typedef __attribute__((address_space(3))) void* las_t;
static __device__ __forceinline__ void gload16(const void* g, void* l) {
    __builtin_amdgcn_global_load_lds((gas_t)g, (las_t)l, 16, 0, 0);
}

// Y fragment-tiled layout, per group: tile (it<32, ct<16) = rows [it*16,+16) x
// cols [ct*32,+32); u16 offset = (it*16+ct)*512 + lane*8, lane = kg*16+fr
// holding row fr, cols kg*8..+7.  One MFMA B-frag = one coalesced 1KB chunk.

// ---------------------------------------------------------------------------
// Kernel 1: per-32-panel prep, 1024 thr. Blocks 0..127: prep.
// Blocks 128..1151 (fat only): x fp32->bf16 cast. (round-9/10 verified,
// Y export now fragment-tiled.)
// ---------------------------------------------------------------------------
__global__ __launch_bounds__(1024) void k_panelprep(const float* __restrict__ w,
                                                    const float* __restrict__ x,
                                                    u16* __restrict__ Yfh,
                                                    u16* __restrict__ Yfl,
                                                    u16* __restrict__ Mth,
                                                    u16* __restrict__ Mtl,
                                                    u16* __restrict__ xb) {
    __shared__ float Ylds[PW][516];
    __shared__ float Sp[16][PW][36];
    __shared__ float S_ls[PW][36];
    __shared__ float T_ls[PW][36];

    int bid = blockIdx.x;
    int t   = threadIdx.x;

    if (bid >= 128) {
        const int TOT8 = GROUP * BS * CH / 8;
        for (int i = (bid - 128) * 1024 + t; i < TOT8; i += 1024 * 1024) {
            const float4* s = (const float4*)(x + (size_t)i * 8);
            float4 a = s[0], b = s[1];
            u16x8 o;
            o[0] = f2bf(a.x); o[1] = f2bf(a.y); o[2] = f2bf(a.z); o[3] = f2bf(a.w);
            o[4] = f2bf(b.x); o[5] = f2bf(b.y); o[6] = f2bf(b.z); o[7] = f2bf(b.w);
            *(u16x8*)(xb + (size_t)i * 8) = o;
        }
        return;
    }

    int lane = t & 63;
    int wv   = t >> 6;
    int fr   = lane & 15;
    int kg   = lane >> 4;
    int g    = bid >> 4;
    int p    = bid & 15;
    int i0   = p * PW;

    const float* wg = w + (size_t)g * CH * CH;
    for (int idx4 = t; idx4 < 4096; idx4 += 1024) {
        int c = idx4 >> 3, f4 = idx4 & 7;
        float4 v = *(const float4*)(wg + (size_t)c * CH + i0 + f4 * 4);
        Ylds[f4 * 4 + 0][c] = v.x;
        Ylds[f4 * 4 + 1][c] = v.y;
        Ylds[f4 * 4 + 2][c] = v.z;
        Ylds[f4 * 4 + 3][c] = v.w;
    }
    __syncthreads();

    {
        f32x4 sacc[2][2];
#pragma unroll
        for (int a = 0; a < 2; ++a)
#pragma unroll
            for (int b = 0; b < 2; ++b)
#pragma unroll
                for (int z = 0; z < 4; ++z) sacc[a][b][z] = 0.f;
        {
            int kk = wv;
            bf16x8 fh[2], fl[2];
#pragma unroll
            for (int h = 0; h < 2; ++h) {
                float a8[8];
                const float* src = &Ylds[h * 16 + fr][kk * 32 + kg * 8];
#pragma unroll
                for (int j = 0; j < 8; ++j) a8[j] = src[j];
                split8(a8, fh[h], fl[h]);
            }
#pragma unroll
            for (int a = 0; a < 2; ++a)
#pragma unroll
                for (int b = 0; b < 2; ++b) {
                    sacc[a][b] = MFMA(fh[a], fh[b], sacc[a][b]);
                    sacc[a][b] = MFMA(fh[a], fl[b], sacc[a][b]);
                    sacc[a][b] = MFMA(fl[a], fh[b], sacc[a][b]);
                }
        }
#pragma unroll
        for (int a = 0; a < 2; ++a)
#pragma unroll
            for (int b = 0; b < 2; ++b)
#pragma unroll
                for (int j = 0; j < 4; ++j)
                    Sp[wv][a * 16 + kg * 4 + j][b * 16 + fr] = sacc[a][b][j];
    }
    __syncthreads();
    for (int idx = t; idx < PW * PW; idx += 1024) {
        int r = idx >> 5, c = idx & 31;
        float s = 0.f;
#pragma unroll
        for (int q = 0; q < 16; ++q) s += Sp[q][r][c];
        S_ls[r][c] = s;
    }
    __syncthreads();

    if (wv == 0) {
        float Trow[PW];
#pragma unroll
        for (int j = 0; j < PW; ++j) Trow[j] = 0.f;
        if (lane < PW) Trow[lane] = 2.0f / S_ls[lane][lane];
#pragma unroll
        for (int k = 1; k < PW; ++k) {
            float acc = 0.f;
#pragma unroll
            for (int j = 0; j < PW; ++j)
                if (j < k) acc += Trow[j] * S_ls[j][k];
            float bk = 2.0f / S_ls[k][k];
            if (lane < k) Trow[k] = -bk * acc;
        }
        if (lane < PW)
#pragma unroll
            for (int j = 0; j < PW; ++j) T_ls[lane][j] = Trow[j];
    }
    __syncthreads();

    bf16x8 tbh[2], tbl[2];
#pragma unroll
    for (int cf = 0; cf < 2; ++cf) {
        float t8[8];
        const float* src = &T_ls[cf * 16 + fr][kg * 8];
#pragma unroll
        for (int j = 0; j < 8; ++j) t8[j] = src[j];
        split8(t8, tbh[cf], tbl[cf]);
    }
#pragma unroll
    for (int rfi = 0; rfi < 2; ++rfi) {
        int rf = 2 * wv + rfi;
        float a8[8];
#pragma unroll
        for (int j = 0; j < 8; ++j) a8[j] = Ylds[kg * 8 + j][rf * 16 + fr];
        bf16x8 ah, al;
        split8(a8, ah, al);
#pragma unroll
        for (int cf = 0; cf < 2; ++cf) {
            f32x4 m;
#pragma unroll
            for (int z = 0; z < 4; ++z) m[z] = 0.f;
            m = MFMA(ah, tbh[cf], m);
            m = MFMA(ah, tbl[cf], m);
            m = MFMA(al, tbh[cf], m);
#pragma unroll
            for (int j = 0; j < 4; ++j) {
                int c = rf * 16 + kg * 4 + j;
                int i = cf * 16 + fr;
                size_t off = ((size_t)g * CH + c) * CH + (i0 + i);  // Mt [c][i]
                u16 hu = f2bf(m[j]);
                Mth[off] = hu;
                Mtl[off] = f2bf(m[j] - bf2f(hu));
            }
        }
    }

    // ---- export Y panel bf16 hi/lo in FRAGMENT-TILED layout ----
    // panel p covers tile-rows it = 2p, 2p+1 (32 tiles of 1KB each).
    {
        u16* Yfh_g = Yfh + (size_t)g * CH * CH;
        u16* Yfl_g = Yfl + (size_t)g * CH * CH;
        for (int idx = t; idx < 32 * 64; idx += 1024) {
            int tile = idx >> 6, l2 = idx & 63;
            int itl = tile >> 4, ct = tile & 15;
            int row = l2 & 15, kgg = l2 >> 4;
            float a8[8];
            const float* src = &Ylds[itl * 16 + row][ct * 32 + kgg * 8];
#pragma unroll
            for (int j = 0; j < 8; ++j) a8[j] = src[j];
            bf16x8 h, l;
            split8(a8, h, l);
            size_t off = ((size_t)((2 * p + itl) * 16 + ct)) * 512 + (size_t)l2 * 8;
            *(bf16x8*)(Yfh_g + off) = h;
            *(bf16x8*)(Yfl_g + off) = l;
        }
    }
}

// ---------------------------------------------------------------------------
// Kernel 2 (x4 levels): WY merge — round-7 proven structure (128 blocks x
// 512 thr, 16-row strips, nf-split waves), C-phase B-loads from frag-tiled Y
// (fully coalesced). In-place on Mt; race-free.
// ---------------------------------------------------------------------------
template<int W>
__global__ __launch_bounds__(512) void k_combine(const u16* __restrict__ Yfh,
                                                 const u16* __restrict__ Yfl,
                                                 u16* __restrict__ Mth,
                                                 u16* __restrict__ Mtl) {
    __shared__ u16 MAh[16][520];
    __shared__ u16 MAl[16][520];
    __shared__ float Cl[16][260];

    int t = threadIdx.x, lane = t & 63, wv = t >> 6;   // 8 waves
    int fr = lane & 15, kg = lane >> 4;
    int g  = blockIdx.x >> 4;
    int sg = blockIdx.x & 15;
    constexpr int SP = W / 16;
    int q  = sg / SP, rs = sg % SP;
    int i_top0 = 2 * q * W + rs * 16;
    int i_bot0 = 2 * q * W + W;

    const u16* Yfh_g = Yfh + (size_t)g * CH * CH;
    const u16* Yfl_g = Yfl + (size_t)g * CH * CH;
    u16* Mth_g = Mth + (size_t)g * CH * CH;
    u16* Mtl_g = Mtl + (size_t)g * CH * CH;

    // ---- stage M_top strip transposed to MA[i][c] (16 x 512) ----
    for (int idx = t; idx < 1024; idx += 512) {
        int c = idx >> 1, ch = idx & 1;
        bf16x8 hv = *(const bf16x8*)(Mth_g + (size_t)c * CH + i_top0 + ch * 8);
        bf16x8 lv = *(const bf16x8*)(Mtl_g + (size_t)c * CH + i_top0 + ch * 8);
#pragma unroll
        for (int j = 0; j < 8; ++j) {
            MAh[ch * 8 + j][c] = (u16)hv[j];
            MAl[ch * 8 + j][c] = (u16)lv[j];
        }
    }
    __syncthreads();

    // ---- C[i][jb] = sum_c MA[i][c] Ybot[jb][c]  (16 x W, K=512) ----
    constexpr int NF = W / 16;
    constexpr int CPW = (NF + 7) / 8;
    f32x4 accC[CPW];
#pragma unroll
    for (int nfi = 0; nfi < CPW; ++nfi)
#pragma unroll
        for (int z = 0; z < 4; ++z) accC[nfi][z] = 0.f;

    int ibt = i_bot0 >> 4;     // bottom's first tile-row
    for (int ks = 0; ks < 16; ++ks) {
        bf16x8 ah = *(const bf16x8*)&MAh[fr][ks * 32 + kg * 8];
        bf16x8 al = *(const bf16x8*)&MAl[fr][ks * 32 + kg * 8];
#pragma unroll
        for (int nfi = 0; nfi < CPW; ++nfi) {
            int nf = wv + 8 * nfi;
            if (nf < NF) {
                size_t yo = ((size_t)((ibt + nf) * 16 + ks)) * 512 + (size_t)lane * 8;
                bf16x8 bh = *(const bf16x8*)(Yfh_g + yo);   // coalesced frag
                bf16x8 bl = *(const bf16x8*)(Yfl_g + yo);
                accC[nfi] = MFMA(ah, bh, accC[nfi]);
                accC[nfi] = MFMA(ah, bl, accC[nfi]);
                accC[nfi] = MFMA(al, bh, accC[nfi]);
            }
        }
    }
#pragma unroll
    for (int nfi = 0; nfi < CPW; ++nfi) {
        int nf = wv + 8 * nfi;
        if (nf < NF)
#pragma unroll
            for (int jj = 0; jj < 4; ++jj)
                Cl[kg * 4 + jj][nf * 16 + fr] = accC[nfi][jj];
    }
    __syncthreads();

    // ---- U[i][c] = sum_j C[i][j] MB[j][c]  (16 x 512, K=W); M' = MA - U ----
    f32x4 accU[4];
#pragma unroll
    for (int ni = 0; ni < 4; ++ni)
#pragma unroll
        for (int z = 0; z < 4; ++z) accU[ni][z] = 0.f;

    for (int ks2 = 0; ks2 < W / 32; ++ks2) {
        float a8[8];
#pragma unroll
        for (int j = 0; j < 8; ++j) a8[j] = Cl[fr][ks2 * 32 + kg * 8 + j];
        bf16x8 ah2, al2;
        split8(a8, ah2, al2);
#pragma unroll
        for (int ni = 0; ni < 4; ++ni) {
            int c = (wv * 4 + ni) * 16 + fr;
            size_t mo = (size_t)c * CH + i_bot0 + ks2 * 32 + kg * 8;
            bf16x8 bh = *(const bf16x8*)(Mth_g + mo);
            bf16x8 bl = *(const bf16x8*)(Mtl_g + mo);
            accU[ni] = MFMA(ah2, bh, accU[ni]);
            accU[ni] = MFMA(ah2, bl, accU[ni]);
            accU[ni] = MFMA(al2, bh, accU[ni]);
        }
    }
#pragma unroll
    for (int ni = 0; ni < 4; ++ni) {
        int c = (wv * 4 + ni) * 16 + fr;
#pragma unroll
        for (int jj = 0; jj < 4; ++jj) {
            int il = kg * 4 + jj;
            float ma = bf2f(MAh[il][c]) + bf2f(MAl[il][c]);
            float m2 = ma - accU[ni][jj];
            u16 hu = f2bf(m2);
            MAh[il][c] = hu;
            MAl[il][c] = f2bf(m2 - bf2f(hu));
        }
    }
    __syncthreads();

    // ---- writeback strip to Mt [c][i] layout ----
    for (int idx = t; idx < 1024; idx += 512) {
        int c = idx >> 1, ch = idx & 1;
        bf16x8 hv, lv;
#pragma unroll
        for (int j = 0; j < 8; ++j) {
            hv[j] = (short)MAh[ch * 8 + j][c];
            lv[j] = (short)MAl[ch * 8 + j][c];
        }
        *(bf16x8*)(Mth_g + (size_t)c * CH + i_top0 + ch * 8) = hv;
        *(bf16x8*)(Mtl_g + (size_t)c * CH + i_top0 + ch * 8) = lv;
    }
}

// ---------------------------------------------------------------------------
// Kernel 3: Qt[g][d][c] = [I - w*M]^T. 512 blocks x 256 thr. (round-9/10)
// ---------------------------------------------------------------------------
__global__ __launch_bounds__(256) void k_qbuild2(const float* __restrict__ w,
                                                 const u16* __restrict__ Mth,
                                                 const u16* __restrict__ Mtl,
                                                 u16* __restrict__ Qt) {
    int t = threadIdx.x, lane = t & 63, wv = t >> 6;
    int fr = lane & 15, kg = lane >> 4;
    int g  = blockIdx.x >> 6;
    int tm = (blockIdx.x >> 2) & 15, tn = blockIdx.x & 3;
    int c0 = tm * 32;
    int d0 = tn * 128 + wv * 32;

    const float* wg = w + (size_t)g * CH * CH;
    const u16* Mth_g = Mth + (size_t)g * CH * CH;
    const u16* Mtl_g = Mtl + (size_t)g * CH * CH;
    u16* Qt_g = Qt + (size_t)g * CH * CH;

    f32x4 acc[2][2];
#pragma unroll
    for (int mi = 0; mi < 2; ++mi)
#pragma unroll
        for (int ni = 0; ni < 2; ++ni)
#pragma unroll
            for (int z = 0; z < 4; ++z) acc[mi][ni][z] = 0.f;

    for (int ks = 0; ks < 16; ++ks) {
        bf16x8 ah[2], al[2], bh[2], bl[2];
#pragma unroll
        for (int mi = 0; mi < 2; ++mi) {
            const float* src = wg + (size_t)(c0 + mi * 16 + fr) * CH + ks * 32 + kg * 8;
            float4 v0 = *(const float4*)src;
            float4 v1 = *(const float4*)(src + 4);
            float a8[8] = {v0.x, v0.y, v0.z, v0.w, v1.x, v1.y, v1.z, v1.w};
            split8(a8, ah[mi], al[mi]);
        }
#pragma unroll
        for (int ni = 0; ni < 2; ++ni) {
            size_t mo = (size_t)(d0 + ni * 16 + fr) * CH + ks * 32 + kg * 8;
            bh[ni] = *(const bf16x8*)(Mth_g + mo);
            bl[ni] = *(const bf16x8*)(Mtl_g + mo);
        }
#pragma unroll
        for (int mi = 0; mi < 2; ++mi)
#pragma unroll
            for (int ni = 0; ni < 2; ++ni) {
                acc[mi][ni] = MFMA(ah[mi], bh[ni], acc[mi][ni]);
                acc[mi][ni] = MFMA(ah[mi], bl[ni], acc[mi][ni]);
                acc[mi][ni] = MFMA(al[mi], bh[ni], acc[mi][ni]);
            }
    }
#pragma unroll
    for (int mi = 0; mi < 2; ++mi)
#pragma unroll
        for (int ni = 0; ni < 2; ++ni) {
            int cb = c0 + mi * 16 + kg * 4;
            int d  = d0 + ni * 16 + fr;
            ushort4 h4;
            h4.x = f2bf(((cb + 0 == d) ? 1.0f : 0.0f) - acc[mi][ni][0]);
            h4.y = f2bf(((cb + 1 == d) ? 1.0f : 0.0f) - acc[mi][ni][1]);
            h4.z = f2bf(((cb + 2 == d) ? 1.0f : 0.0f) - acc[mi][ni][2]);
            h4.w = f2bf(((cb + 3 == d) ? 1.0f : 0.0f) - acc[mi][ni][3]);
            *(ushort4*)(Qt_g + (size_t)d * CH + cb) = h4;
        }
}

// ---------------------------------------------------------------------------
// Kernel 4: 2-phase double-buffered GEMM (round-10). out = xb @ Qt.
// ---------------------------------------------------------------------------
__global__ __launch_bounds__(256) void k_gemm2(const u16* __restrict__ xb,
                                               const u16* __restrict__ Qt,
                                               float* __restrict__ out) {
    __shared__ u16 Ab[2][128 * 64];
    __shared__ u16 Bb[2][128 * 64];

    int bid0 = blockIdx.x;
    int wg = (bid0 & 7) * 128 + (bid0 >> 3);  // bijective XCD chunk
    int g  = wg >> 7;
    int r  = wg & 127;
    int tm = r >> 2;
    int tn = r & 3;

    int t    = threadIdx.x;
    int lane = t & 63;
    int wv   = t >> 6;
    int wr   = wv >> 1, wc = wv & 1;
    int fr   = lane & 15, kg = lane >> 4;

    const u16* xg  = xb + (size_t)g * BS * CH + (size_t)tm * 128 * CH;
    const u16* Qtg = Qt + (size_t)g * CH * CH + (size_t)tn * 128 * CH;
    float* og = out + (size_t)g * BS * CH + (size_t)tm * 128 * CH + (size_t)tn * 128;

    f32x4 acc[4][4];
#pragma unroll
    for (int mi = 0; mi < 4; ++mi)
#pragma unroll
        for (int ni = 0; ni < 4; ++ni)
#pragma unroll
            for (int z = 0; z < 4; ++z) acc[mi][ni][z] = 0.f;

    int srow8 = lane >> 3;
    int scol  = (lane & 7) * 8;

    auto STAGE = [&](int p, int ks) {
        int k0 = ks * 64;
#pragma unroll
        for (int si = 0; si < 4; ++si) {
            int seg = wv * 4 + si;
            int row = seg * 8 + srow8;
            gload16(xg  + (size_t)row * CH + k0 + scol, &Ab[p][seg * 512]);
            gload16(Qtg + (size_t)row * CH + k0 + scol, &Bb[p][seg * 512]);
        }
    };

    STAGE(0, 0);
    __syncthreads();

    for (int ks = 0; ks < 8; ++ks) {
        int cur = ks & 1;
        if (ks < 7) STAGE(cur ^ 1, ks + 1);
#pragma unroll
        for (int kk = 0; kk < 2; ++kk) {
            bf16x8 af[4], bfr[4];
#pragma unroll
            for (int mi = 0; mi < 4; ++mi)
                af[mi] = *(const bf16x8*)&Ab[cur][(wr * 64 + mi * 16 + fr) * 64 + kk * 32 + kg * 8];
#pragma unroll
            for (int ni = 0; ni < 4; ++ni)
                bfr[ni] = *(const bf16x8*)&Bb[cur][(wc * 64 + ni * 16 + fr) * 64 + kk * 32 + kg * 8];
#pragma unroll
            for (int mi = 0; mi < 4; ++mi)
#pragma unroll
                for (int ni = 0; ni < 4; ++ni)
                    acc[mi][ni] = MFMA(af[mi], bfr[ni], acc[mi][ni]);
        }
        __syncthreads();
    }

    int rg = lane >> 4;
#pragma unroll
    for (int mi = 0; mi < 4; ++mi)
#pragma unroll
        for (int ni = 0; ni < 4; ++ni)
#pragma unroll
            for (int rj = 0; rj < 4; ++rj) {
                int grow = wr * 64 + mi * 16 + rg * 4 + rj;
                int gcol = wc * 64 + ni * 16 + fr;
                og[(size_t)grow * CH + gcol] = acc[mi][ni][rj];
            }
}

// ---------------------------------------------------------------------------
// Fallback GEMM (fp32 A, in-staging convert) — round-5 verified.
// ---------------------------------------------------------------------------
#define LDP 40
__global__ __launch_bounds__(256) void k_gemm_f32(const float* __restrict__ x,
                                                  const u16* __restrict__ Qt,
                                                  float* __restrict__ out) {
    __shared__ u16 Al[128 * LDP];
    __shared__ u16 Bl[128 * LDP];

    int bid = blockIdx.x;
    int g  = bid >> 7;
    int tn = (bid >> 5) & 3;
    int tm = bid & 31;

    int t    = threadIdx.x;
    int lane = t & 63;
    int w    = t >> 6;
    int wr   = w >> 1, wc = w & 1;

    const float* xg = x + (size_t)g * BS * CH + (size_t)tm * 128 * CH;
    const u16* Qtg = Qt + (size_t)g * CH * CH + (size_t)tn * 128 * CH;
    float* og = out + (size_t)g * BS * CH + (size_t)tm * 128 * CH + (size_t)tn * 128;

    f32x4 acc[4][4];
#pragma unroll
    for (int mi = 0; mi < 4; ++mi)
#pragma unroll
        for (int ni = 0; ni < 4; ++ni)
#pragma unroll
            for (int z = 0; z < 4; ++z) acc[mi][ni][z] = 0.f;

    int a_k4 = t & 7;
    int a_r  = t >> 3;
    int b_n  = t & 127;
    int b_kh = t >> 7;
    int fr = lane & 15, kg = lane >> 4;

    for (int ks = 0; ks < 16; ++ks) {
        int k0 = ks * 32;
        __syncthreads();
#pragma unroll
        for (int rr = 0; rr < 4; ++rr) {
            int r = a_r + 32 * rr;
            float4 v = *(const float4*)(xg + (size_t)r * CH + k0 + a_k4 * 4);
            ushort4 h;
            h.x = f2bf(v.x); h.y = f2bf(v.y); h.z = f2bf(v.z); h.w = f2bf(v.w);
            *(ushort4*)(&Al[r * LDP + a_k4 * 4]) = h;
        }
        {
            const u16* src = Qtg + (size_t)b_n * CH + k0 + b_kh * 16;
            u16x8 lo = *(const u16x8*)src;
            u16x8 hi = *(const u16x8*)(src + 8);
            *(u16x8*)(&Bl[b_n * LDP + b_kh * 16]) = lo;
            *(u16x8*)(&Bl[b_n * LDP + b_kh * 16 + 8]) = hi;
        }
        __syncthreads();
        bf16x8 af[4], bfr[4];
#pragma unroll
        for (int mi = 0; mi < 4; ++mi)
            af[mi] = *(const bf16x8*)(&Al[(wr * 64 + mi * 16 + fr) * LDP + kg * 8]);
#pragma unroll
        for (int ni = 0; ni < 4; ++ni)
            bfr[ni] = *(const bf16x8*)(&Bl[(wc * 64 + ni * 16 + fr) * LDP + kg * 8]);
#pragma unroll
        for (int mi = 0; mi < 4; ++mi)
#pragma unroll
            for (int ni = 0; ni < 4; ++ni)
                acc[mi][ni] = MFMA(af[mi], bfr[ni], acc[mi][ni]);
    }

    int rg = lane >> 4;
#pragma unroll
    for (int mi = 0; mi < 4; ++mi)
#pragma unroll
        for (int ni = 0; ni < 4; ++ni)
#pragma unroll
            for (int rj = 0; rj < 4; ++rj) {
                int grow = wr * 64 + mi * 16 + rg * 4 + rj;
                int gcol = wc * 64 + ni * 16 + fr;
                og[(size_t)grow * CH + gcol] = acc[mi][ni][rj];
            }
}

// ---------------------------------------------------------------------------
extern "C" void kernel_launch(void* const* d_in, const int* in_sizes, int n_in,
                              void* d_out, int out_size, void* d_ws, size_t ws_size,
                              hipStream_t stream) {
    const float* x = (const float*)d_in[0];   // (8, 4096, 512)
    const float* w = (const float*)d_in[1];   // (8, 512, 512)
    float* out = (float*)d_out;

    char* ob = (char*)d_out;
    u16* Yfh = (u16*)ob;                      // [0, 4MB)  frag-tiled Y hi
    u16* Yfl = (u16*)(ob + (4u  << 20));      // [4, 8)    frag-tiled Y lo
    u16* Mth = (u16*)(ob + (8u  << 20));      // [8, 12)   Mt [c][i] hi
    u16* Mtl = (u16*)(ob + (12u << 20));      // [12, 16)  Mt [c][i] lo

    int fat = (ws_size >= ((32u << 20) + (4u << 20))) ? 1 : 0;
    u16* xbp = (u16*)d_ws;
    u16* Qt  = fat ? (u16*)((char*)d_ws + (32u << 20)) : (u16*)d_ws;

    k_panelprep<<<dim3(fat ? 1152 : 128), dim3(1024), 0, stream>>>(w, x, Yfh, Yfl, Mth, Mtl, xbp);
    k_combine<32><<<dim3(128), dim3(512), 0, stream>>>(Yfh, Yfl, Mth, Mtl);
    k_combine<64><<<dim3(128), dim3(512), 0, stream>>>(Yfh, Yfl, Mth, Mtl);
    k_combine<128><<<dim3(128), dim3(512), 0, stream>>>(Yfh, Yfl, Mth, Mtl);
    k_combine<256><<<dim3(128), dim3(512), 0, stream>>>(Yfh, Yfl, Mth, Mtl);
    k_qbuild2<<<dim3(512), dim3(256), 0, stream>>>(w, Mth, Mtl, Qt);
    if (fat)
        k_gemm2<<<dim3(1024), dim3(256), 0, stream>>>(xbp, Qt, out);
    else
        k_gemm_f32<<<dim3(1024), dim3(256), 0, stream>>>(x, Qt, out);
}

// Round 12
// 136.773 us; speedup vs baseline: 1.5791x; 1.2098x over previous
//
#include <hip/hip_runtime.h>

#define GROUP 8
#define BS 4096
#define CH 512
#define PW 32
#define NPANEL 16

typedef __attribute__((ext_vector_type(4))) float f32x4;
typedef __attribute__((ext_vector_type(8))) short bf16x8;
typedef __attribute__((ext_vector_type(8))) unsigned short u16x8;
typedef unsigned short u16;

static __device__ __forceinline__ u16 f2bf(float f) {
    unsigned int u = __builtin_bit_cast(unsigned int, f);
    u += 0x7FFFu + ((u >> 16) & 1u);   // RNE
    return (u16)(u >> 16);
}
static __device__ __forceinline__ float bf2f(u16 h) {
    return __builtin_bit_cast(float, (unsigned int)h << 16);
}
static __device__ __forceinline__ void split8(const float* v, bf16x8& h, bf16x8& l) {
#pragma unroll
    for (int j = 0; j < 8; ++j) {
        u16 hu = f2bf(v[j]);
        h[j] = (short)hu;
        l[j] = (short)f2bf(v[j] - bf2f(hu));
    }
}
#define MFMA(a, b, c) __builtin_amdgcn_mfma_f32_16x16x32_bf16(a, b, c, 0, 0, 0)

typedef const __attribute__((address_space(1))) void* gas_t;
typedef __attribute__((address_space(3))) void* las_t;
static __device__ __forceinline__ void gload16(const void* g, void* l) {
    __builtin_amdgcn_global_load_lds((gas_t)g, (las_t)l, 16, 0, 0);
}

// Yf layout (B-frag tiles over k=c): tile (it<32, ct<16): rows[it*16,+16) x
// cols[ct*32,+32); off = (it*16+ct)*512 + lane*8, lane=kg*16+fr -> (row=fr,
// col=kg*8..+7).
// Mf layout (B-frag tiles over k=i): tile (kt<16, ct<32): i in [kt*32,+32),
// c in [ct*16,+16); off(i,c) = (kt*32+ct)*512 + ((i>>3)&3)*128 + (c&15)*8
// + (i&7).  One MFMA B-frag (k=i, n=c) = tile_base + lane*8 (coalesced).

// ---------------------------------------------------------------------------
// Kernel 1: per-32-panel prep, 1024 thr. Blocks 0..127: prep.
// Blocks 128..1151 (fat only): x fp32->bf16 cast.
// ---------------------------------------------------------------------------
__global__ __launch_bounds__(1024) void k_panelprep(const float* __restrict__ w,
                                                    const float* __restrict__ x,
                                                    u16* __restrict__ Yfh,
                                                    u16* __restrict__ Yfl,
                                                    u16* __restrict__ Mfh,
                                                    u16* __restrict__ Mfl,
                                                    u16* __restrict__ xb) {
    __shared__ float Ylds[PW][516];
    __shared__ float Sp[16][PW][36];
    __shared__ float S_ls[PW][36];
    __shared__ float T_ls[PW][36];

    int bid = blockIdx.x;
    int t   = threadIdx.x;

    if (bid >= 128) {
        const int TOT8 = GROUP * BS * CH / 8;
        for (int i = (bid - 128) * 1024 + t; i < TOT8; i += 1024 * 1024) {
            const float4* s = (const float4*)(x + (size_t)i * 8);
            float4 a = s[0], b = s[1];
            u16x8 o;
            o[0] = f2bf(a.x); o[1] = f2bf(a.y); o[2] = f2bf(a.z); o[3] = f2bf(a.w);
            o[4] = f2bf(b.x); o[5] = f2bf(b.y); o[6] = f2bf(b.z); o[7] = f2bf(b.w);
            *(u16x8*)(xb + (size_t)i * 8) = o;
        }
        return;
    }

    int lane = t & 63;
    int wv   = t >> 6;
    int fr   = lane & 15;
    int kg   = lane >> 4;
    int g    = bid >> 4;
    int p    = bid & 15;
    int i0   = p * PW;

    const float* wg = w + (size_t)g * CH * CH;
    for (int idx4 = t; idx4 < 4096; idx4 += 1024) {
        int c = idx4 >> 3, f4 = idx4 & 7;
        float4 v = *(const float4*)(wg + (size_t)c * CH + i0 + f4 * 4);
        Ylds[f4 * 4 + 0][c] = v.x;
        Ylds[f4 * 4 + 1][c] = v.y;
        Ylds[f4 * 4 + 2][c] = v.z;
        Ylds[f4 * 4 + 3][c] = v.w;
    }
    __syncthreads();

    {
        f32x4 sacc[2][2];
#pragma unroll
        for (int a = 0; a < 2; ++a)
#pragma unroll
            for (int b = 0; b < 2; ++b)
#pragma unroll
                for (int z = 0; z < 4; ++z) sacc[a][b][z] = 0.f;
        {
            int kk = wv;
            bf16x8 fh[2], fl[2];
#pragma unroll
            for (int h = 0; h < 2; ++h) {
                float a8[8];
                const float* src = &Ylds[h * 16 + fr][kk * 32 + kg * 8];
#pragma unroll
                for (int j = 0; j < 8; ++j) a8[j] = src[j];
                split8(a8, fh[h], fl[h]);
            }
#pragma unroll
            for (int a = 0; a < 2; ++a)
#pragma unroll
                for (int b = 0; b < 2; ++b) {
                    sacc[a][b] = MFMA(fh[a], fh[b], sacc[a][b]);
                    sacc[a][b] = MFMA(fh[a], fl[b], sacc[a][b]);
                    sacc[a][b] = MFMA(fl[a], fh[b], sacc[a][b]);
                }
        }
#pragma unroll
        for (int a = 0; a < 2; ++a)
#pragma unroll
            for (int b = 0; b < 2; ++b)
#pragma unroll
                for (int j = 0; j < 4; ++j)
                    Sp[wv][a * 16 + kg * 4 + j][b * 16 + fr] = sacc[a][b][j];
    }
    __syncthreads();
    for (int idx = t; idx < PW * PW; idx += 1024) {
        int r = idx >> 5, c = idx & 31;
        float s = 0.f;
#pragma unroll
        for (int q = 0; q < 16; ++q) s += Sp[q][r][c];
        S_ls[r][c] = s;
    }
    __syncthreads();

    if (wv == 0) {
        float Trow[PW];
#pragma unroll
        for (int j = 0; j < PW; ++j) Trow[j] = 0.f;
        if (lane < PW) Trow[lane] = 2.0f / S_ls[lane][lane];
#pragma unroll
        for (int k = 1; k < PW; ++k) {
            float acc = 0.f;
#pragma unroll
            for (int j = 0; j < PW; ++j)
                if (j < k) acc += Trow[j] * S_ls[j][k];
            float bk = 2.0f / S_ls[k][k];
            if (lane < k) Trow[k] = -bk * acc;
        }
        if (lane < PW)
#pragma unroll
            for (int j = 0; j < PW; ++j) T_ls[lane][j] = Trow[j];
    }
    __syncthreads();

    bf16x8 tbh[2], tbl[2];
#pragma unroll
    for (int cf = 0; cf < 2; ++cf) {
        float t8[8];
        const float* src = &T_ls[cf * 16 + fr][kg * 8];
#pragma unroll
        for (int j = 0; j < 8; ++j) t8[j] = src[j];
        split8(t8, tbh[cf], tbl[cf]);
    }
    {
        u16* Mfh_g = Mfh + (size_t)g * CH * CH;
        u16* Mfl_g = Mfl + (size_t)g * CH * CH;
#pragma unroll
        for (int rfi = 0; rfi < 2; ++rfi) {
            int rf = 2 * wv + rfi;
            float a8[8];
#pragma unroll
            for (int j = 0; j < 8; ++j) a8[j] = Ylds[kg * 8 + j][rf * 16 + fr];
            bf16x8 ah, al;
            split8(a8, ah, al);
#pragma unroll
            for (int cf = 0; cf < 2; ++cf) {
                f32x4 m;
#pragma unroll
                for (int z = 0; z < 4; ++z) m[z] = 0.f;
                m = MFMA(ah, tbh[cf], m);
                m = MFMA(ah, tbl[cf], m);
                m = MFMA(al, tbh[cf], m);
#pragma unroll
                for (int j = 0; j < 4; ++j) {
                    int c  = rf * 16 + kg * 4 + j;
                    int ii = cf * 16 + fr;              // i within panel; kt = p
                    size_t off = ((size_t)(p * 32 + (c >> 4))) * 512
                               + (size_t)((ii >> 3) * 16 + (c & 15)) * 8 + (ii & 7);
                    u16 hu = f2bf(m[j]);
                    Mfh_g[off] = hu;
                    Mfl_g[off] = f2bf(m[j] - bf2f(hu));
                }
            }
        }
    }

    // ---- export Y panel bf16 hi/lo in fragment-tiled layout ----
    {
        u16* Yfh_g = Yfh + (size_t)g * CH * CH;
        u16* Yfl_g = Yfl + (size_t)g * CH * CH;
        for (int idx = t; idx < 32 * 64; idx += 1024) {
            int tile = idx >> 6, l2 = idx & 63;
            int itl = tile >> 4, ct = tile & 15;
            int row = l2 & 15, kgg = l2 >> 4;
            float a8[8];
            const float* src = &Ylds[itl * 16 + row][ct * 32 + kgg * 8];
#pragma unroll
            for (int j = 0; j < 8; ++j) a8[j] = src[j];
            bf16x8 h, l;
            split8(a8, h, l);
            size_t off = ((size_t)((2 * p + itl) * 16 + ct)) * 512 + (size_t)l2 * 8;
            *(bf16x8*)(Yfh_g + off) = h;
            *(bf16x8*)(Yfl_g + off) = l;
        }
    }
}

// ---------------------------------------------------------------------------
// Kernel 2 (x4 levels): WY merge, 128 blocks x 512 thr, 16-row strips.
// All M accesses now via frag-tiled Mf (coalesced). In-place; race-free.
// ---------------------------------------------------------------------------
template<int W>
__global__ __launch_bounds__(512) void k_combine(const u16* __restrict__ Yfh,
                                                 const u16* __restrict__ Yfl,
                                                 u16* __restrict__ Mfh,
                                                 u16* __restrict__ Mfl) {
    __shared__ u16 MAh[16][520];
    __shared__ u16 MAl[16][520];
    __shared__ float Cl[16][260];

    int t = threadIdx.x, lane = t & 63, wv = t >> 6;   // 8 waves
    int fr = lane & 15, kg = lane >> 4;
    int g  = blockIdx.x >> 4;
    int sg = blockIdx.x & 15;
    constexpr int SP = W / 16;
    int q  = sg / SP, rs = sg % SP;
    int i_top0 = 2 * q * W + rs * 16;
    int i_bot0 = 2 * q * W + W;

    const u16* Yfh_g = Yfh + (size_t)g * CH * CH;
    const u16* Yfl_g = Yfl + (size_t)g * CH * CH;
    u16* Mfh_g = Mfh + (size_t)g * CH * CH;
    u16* Mfl_g = Mfl + (size_t)g * CH * CH;

    int kt_top = i_top0 >> 5;
    int hh     = (i_top0 & 31) >> 3;     // 0 or 2 (strip = half a k-tile)

    // ---- stage M_top strip -> MA[i][c] (16 x 512); 256B-contiguous runs ----
    for (int idx = t; idx < 1024; idx += 512) {
        int c = idx >> 1, sub = idx & 1;
        size_t off = ((size_t)(kt_top * 32 + (c >> 4))) * 512
                   + (size_t)((hh + sub) * 16 + (c & 15)) * 8;
        bf16x8 hv = *(const bf16x8*)(Mfh_g + off);
        bf16x8 lv = *(const bf16x8*)(Mfl_g + off);
#pragma unroll
        for (int j = 0; j < 8; ++j) {
            MAh[sub * 8 + j][c] = (u16)hv[j];
            MAl[sub * 8 + j][c] = (u16)lv[j];
        }
    }
    __syncthreads();

    // ---- C[i][jb] = sum_c MA[i][c] Ybot[jb][c]  (16 x W, K=512) ----
    constexpr int NF = W / 16;
    constexpr int CPW = (NF + 7) / 8;
    f32x4 accC[CPW];
#pragma unroll
    for (int nfi = 0; nfi < CPW; ++nfi)
#pragma unroll
        for (int z = 0; z < 4; ++z) accC[nfi][z] = 0.f;

    int ibt = i_bot0 >> 4;
    for (int ks = 0; ks < 16; ++ks) {
        bf16x8 ah = *(const bf16x8*)&MAh[fr][ks * 32 + kg * 8];
        bf16x8 al = *(const bf16x8*)&MAl[fr][ks * 32 + kg * 8];
#pragma unroll
        for (int nfi = 0; nfi < CPW; ++nfi) {
            int nf = wv + 8 * nfi;
            if (nf < NF) {
                size_t yo = ((size_t)((ibt + nf) * 16 + ks)) * 512 + (size_t)lane * 8;
                bf16x8 bh = *(const bf16x8*)(Yfh_g + yo);
                bf16x8 bl = *(const bf16x8*)(Yfl_g + yo);
                accC[nfi] = MFMA(ah, bh, accC[nfi]);
                accC[nfi] = MFMA(ah, bl, accC[nfi]);
                accC[nfi] = MFMA(al, bh, accC[nfi]);
            }
        }
    }
#pragma unroll
    for (int nfi = 0; nfi < CPW; ++nfi) {
        int nf = wv + 8 * nfi;
        if (nf < NF)
#pragma unroll
            for (int jj = 0; jj < 4; ++jj)
                Cl[kg * 4 + jj][nf * 16 + fr] = accC[nfi][jj];
    }
    __syncthreads();

    // ---- U[i][c] = sum_j C[i][j] M_bot[j][c]  (16x512, K=W); coalesced B ----
    f32x4 accU[4];
#pragma unroll
    for (int ni = 0; ni < 4; ++ni)
#pragma unroll
        for (int z = 0; z < 4; ++z) accU[ni][z] = 0.f;

    int kt_bot = i_bot0 >> 5;
    for (int ks2 = 0; ks2 < W / 32; ++ks2) {
        float a8[8];
#pragma unroll
        for (int j = 0; j < 8; ++j) a8[j] = Cl[fr][ks2 * 32 + kg * 8 + j];
        bf16x8 ah2, al2;
        split8(a8, ah2, al2);
#pragma unroll
        for (int ni = 0; ni < 4; ++ni) {
            int ct = wv * 4 + ni;
            size_t mo = ((size_t)((kt_bot + ks2) * 32 + ct)) * 512 + (size_t)lane * 8;
            bf16x8 bh = *(const bf16x8*)(Mfh_g + mo);
            bf16x8 bl = *(const bf16x8*)(Mfl_g + mo);
            accU[ni] = MFMA(ah2, bh, accU[ni]);
            accU[ni] = MFMA(ah2, bl, accU[ni]);
            accU[ni] = MFMA(al2, bh, accU[ni]);
        }
    }
#pragma unroll
    for (int ni = 0; ni < 4; ++ni) {
        int c = (wv * 4 + ni) * 16 + fr;
#pragma unroll
        for (int jj = 0; jj < 4; ++jj) {
            int il = kg * 4 + jj;
            float ma = bf2f(MAh[il][c]) + bf2f(MAl[il][c]);
            float m2 = ma - accU[ni][jj];
            u16 hu = f2bf(m2);
            MAh[il][c] = hu;
            MAl[il][c] = f2bf(m2 - bf2f(hu));
        }
    }
    __syncthreads();

    // ---- writeback strip to Mf ----
    for (int idx = t; idx < 1024; idx += 512) {
        int c = idx >> 1, sub = idx & 1;
        bf16x8 hv, lv;
#pragma unroll
        for (int j = 0; j < 8; ++j) {
            hv[j] = (short)MAh[sub * 8 + j][c];
            lv[j] = (short)MAl[sub * 8 + j][c];
        }
        size_t off = ((size_t)(kt_top * 32 + (c >> 4))) * 512
                   + (size_t)((hh + sub) * 16 + (c & 15)) * 8;
        *(bf16x8*)(Mfh_g + off) = hv;
        *(bf16x8*)(Mfl_g + off) = lv;
    }
}

// ---------------------------------------------------------------------------
// Kernel 3: Qt[g][d][c] = [I - w*M]^T. 512 blocks x 256 thr.
// B-loads from Mf (coalesced frags).
// ---------------------------------------------------------------------------
__global__ __launch_bounds__(256) void k_qbuild2(const float* __restrict__ w,
                                                 const u16* __restrict__ Mfh,
                                                 const u16* __restrict__ Mfl,
                                                 u16* __restrict__ Qt) {
    int t = threadIdx.x, lane = t & 63, wv = t >> 6;
    int fr = lane & 15, kg = lane >> 4;
    int g  = blockIdx.x >> 6;
    int tm = (blockIdx.x >> 2) & 15, tn = blockIdx.x & 3;
    int c0 = tm * 32;
    int d0 = tn * 128 + wv * 32;

    const float* wg = w + (size_t)g * CH * CH;
    const u16* Mfh_g = Mfh + (size_t)g * CH * CH;
    const u16* Mfl_g = Mfl + (size_t)g * CH * CH;
    u16* Qt_g = Qt + (size_t)g * CH * CH;

    f32x4 acc[2][2];
#pragma unroll
    for (int mi = 0; mi < 2; ++mi)
#pragma unroll
        for (int ni = 0; ni < 2; ++ni)
#pragma unroll
            for (int z = 0; z < 4; ++z) acc[mi][ni][z] = 0.f;

    for (int ks = 0; ks < 16; ++ks) {
        bf16x8 ah[2], al[2], bh[2], bl[2];
#pragma unroll
        for (int mi = 0; mi < 2; ++mi) {
            const float* src = wg + (size_t)(c0 + mi * 16 + fr) * CH + ks * 32 + kg * 8;
            float4 v0 = *(const float4*)src;
            float4 v1 = *(const float4*)(src + 4);
            float a8[8] = {v0.x, v0.y, v0.z, v0.w, v1.x, v1.y, v1.z, v1.w};
            split8(a8, ah[mi], al[mi]);
        }
#pragma unroll
        for (int ni = 0; ni < 2; ++ni) {
            int ct = (d0 >> 4) + ni;
            size_t mo = ((size_t)(ks * 32 + ct)) * 512 + (size_t)lane * 8;
            bh[ni] = *(const bf16x8*)(Mfh_g + mo);
            bl[ni] = *(const bf16x8*)(Mfl_g + mo);
        }
#pragma unroll
        for (int mi = 0; mi < 2; ++mi)
#pragma unroll
            for (int ni = 0; ni < 2; ++ni) {
                acc[mi][ni] = MFMA(ah[mi], bh[ni], acc[mi][ni]);
                acc[mi][ni] = MFMA(ah[mi], bl[ni], acc[mi][ni]);
                acc[mi][ni] = MFMA(al[mi], bh[ni], acc[mi][ni]);
            }
    }
#pragma unroll
    for (int mi = 0; mi < 2; ++mi)
#pragma unroll
        for (int ni = 0; ni < 2; ++ni) {
            int cb = c0 + mi * 16 + kg * 4;
            int d  = d0 + ni * 16 + fr;
            ushort4 h4;
            h4.x = f2bf(((cb + 0 == d) ? 1.0f : 0.0f) - acc[mi][ni][0]);
            h4.y = f2bf(((cb + 1 == d) ? 1.0f : 0.0f) - acc[mi][ni][1]);
            h4.z = f2bf(((cb + 2 == d) ? 1.0f : 0.0f) - acc[mi][ni][2]);
            h4.w = f2bf(((cb + 3 == d) ? 1.0f : 0.0f) - acc[mi][ni][3]);
            *(ushort4*)(Qt_g + (size_t)d * CH + cb) = h4;
        }
}

// ---------------------------------------------------------------------------
// Kernel 4: 2-phase double-buffered GEMM (round-10/11). out = xb @ Qt.
// ---------------------------------------------------------------------------
__global__ __launch_bounds__(256) void k_gemm2(const u16* __restrict__ xb,
                                               const u16* __restrict__ Qt,
                                               float* __restrict__ out) {
    __shared__ u16 Ab[2][128 * 64];
    __shared__ u16 Bb[2][128 * 64];

    int bid0 = blockIdx.x;
    int wg = (bid0 & 7) * 128 + (bid0 >> 3);
    int g  = wg >> 7;
    int r  = wg & 127;
    int tm = r >> 2;
    int tn = r & 3;

    int t    = threadIdx.x;
    int lane = t & 63;
    int wv   = t >> 6;
    int wr   = wv >> 1, wc = wv & 1;
    int fr   = lane & 15, kg = lane >> 4;

    const u16* xg  = xb + (size_t)g * BS * CH + (size_t)tm * 128 * CH;
    const u16* Qtg = Qt + (size_t)g * CH * CH + (size_t)tn * 128 * CH;
    float* og = out + (size_t)g * BS * CH + (size_t)tm * 128 * CH + (size_t)tn * 128;

    f32x4 acc[4][4];
#pragma unroll
    for (int mi = 0; mi < 4; ++mi)
#pragma unroll
        for (int ni = 0; ni < 4; ++ni)
#pragma unroll
            for (int z = 0; z < 4; ++z) acc[mi][ni][z] = 0.f;

    int srow8 = lane >> 3;
    int scol  = (lane & 7) * 8;

    auto STAGE = [&](int p, int ks) {
        int k0 = ks * 64;
#pragma unroll
        for (int si = 0; si < 4; ++si) {
            int seg = wv * 4 + si;
            int row = seg * 8 + srow8;
            gload16(xg  + (size_t)row * CH + k0 + scol, &Ab[p][seg * 512]);
            gload16(Qtg + (size_t)row * CH + k0 + scol, &Bb[p][seg * 512]);
        }
    };

    STAGE(0, 0);
    __syncthreads();

    for (int ks = 0; ks < 8; ++ks) {
        int cur = ks & 1;
        if (ks < 7) STAGE(cur ^ 1, ks + 1);
#pragma unroll
        for (int kk = 0; kk < 2; ++kk) {
            bf16x8 af[4], bfr[4];
#pragma unroll
            for (int mi = 0; mi < 4; ++mi)
                af[mi] = *(const bf16x8*)&Ab[cur][(wr * 64 + mi * 16 + fr) * 64 + kk * 32 + kg * 8];
#pragma unroll
            for (int ni = 0; ni < 4; ++ni)
                bfr[ni] = *(const bf16x8*)&Bb[cur][(wc * 64 + ni * 16 + fr) * 64 + kk * 32 + kg * 8];
#pragma unroll
            for (int mi = 0; mi < 4; ++mi)
#pragma unroll
                for (int ni = 0; ni < 4; ++ni)
                    acc[mi][ni] = MFMA(af[mi], bfr[ni], acc[mi][ni]);
        }
        __syncthreads();
    }

    int rg = lane >> 4;
#pragma unroll
    for (int mi = 0; mi < 4; ++mi)
#pragma unroll
        for (int ni = 0; ni < 4; ++ni)
#pragma unroll
            for (int rj = 0; rj < 4; ++rj) {
                int grow = wr * 64 + mi * 16 + rg * 4 + rj;
                int gcol = wc * 64 + ni * 16 + fr;
                og[(size_t)grow * CH + gcol] = acc[mi][ni][rj];
            }
}

// ---------------------------------------------------------------------------
// Fallback GEMM (fp32 A, in-staging convert) — round-5 verified.
// ---------------------------------------------------------------------------
#define LDP 40
__global__ __launch_bounds__(256) void k_gemm_f32(const float* __restrict__ x,
                                                  const u16* __restrict__ Qt,
                                                  float* __restrict__ out) {
    __shared__ u16 Al[128 * LDP];
    __shared__ u16 Bl[128 * LDP];

    int bid = blockIdx.x;
    int g  = bid >> 7;
    int tn = (bid >> 5) & 3;
    int tm = bid & 31;

    int t    = threadIdx.x;
    int lane = t & 63;
    int w    = t >> 6;
    int wr   = w >> 1, wc = w & 1;

    const float* xg = x + (size_t)g * BS * CH + (size_t)tm * 128 * CH;
    const u16* Qtg = Qt + (size_t)g * CH * CH + (size_t)tn * 128 * CH;
    float* og = out + (size_t)g * BS * CH + (size_t)tm * 128 * CH + (size_t)tn * 128;

    f32x4 acc[4][4];
#pragma unroll
    for (int mi = 0; mi < 4; ++mi)
#pragma unroll
        for (int ni = 0; ni < 4; ++ni)
#pragma unroll
            for (int z = 0; z < 4; ++z) acc[mi][ni][z] = 0.f;

    int a_k4 = t & 7;
    int a_r  = t >> 3;
    int b_n  = t & 127;
    int b_kh = t >> 7;
    int fr = lane & 15, kg = lane >> 4;

    for (int ks = 0; ks < 16; ++ks) {
        int k0 = ks * 32;
        __syncthreads();
#pragma unroll
        for (int rr = 0; rr < 4; ++rr) {
            int r = a_r + 32 * rr;
            float4 v = *(const float4*)(xg + (size_t)r * CH + k0 + a_k4 * 4);
            ushort4 h;
            h.x = f2bf(v.x); h.y = f2bf(v.y); h.z = f2bf(v.z); h.w = f2bf(v.w);
            *(ushort4*)(&Al[r * LDP + a_k4 * 4]) = h;
        }
        {
            const u16* src = Qtg + (size_t)b_n * CH + k0 + b_kh * 16;
            u16x8 lo = *(const u16x8*)src;
            u16x8 hi = *(const u16x8*)(src + 8);
            *(u16x8*)(&Bl[b_n * LDP + b_kh * 16]) = lo;
            *(u16x8*)(&Bl[b_n * LDP + b_kh * 16 + 8]) = hi;
        }
        __syncthreads();
        bf16x8 af[4], bfr[4];
#pragma unroll
        for (int mi = 0; mi < 4; ++mi)
            af[mi] = *(const bf16x8*)(&Al[(wr * 64 + mi * 16 + fr) * LDP + kg * 8]);
#pragma unroll
        for (int ni = 0; ni < 4; ++ni)
            bfr[ni] = *(const bf16x8*)(&Bl[(wc * 64 + ni * 16 + fr) * LDP + kg * 8]);
#pragma unroll
        for (int mi = 0; mi < 4; ++mi)
#pragma unroll
            for (int ni = 0; ni < 4; ++ni)
                acc[mi][ni] = MFMA(af[mi], bfr[ni], acc[mi][ni]);
    }

    int rg = lane >> 4;
#pragma unroll
    for (int mi = 0; mi < 4; ++mi)
#pragma unroll
        for (int ni = 0; ni < 4; ++ni)
#pragma unroll
            for (int rj = 0; rj < 4; ++rj) {
                int grow = wr * 64 + mi * 16 + rg * 4 + rj;
                int gcol = wc * 64 + ni * 16 + fr;
                og[(size_t)grow * CH + gcol] = acc[mi][ni][rj];
            }
}

// ---------------------------------------------------------------------------
extern "C" void kernel_launch(void* const* d_in, const int* in_sizes, int n_in,
                              void* d_out, int out_size, void* d_ws, size_t ws_size,
                              hipStream_t stream) {
    const float* x = (const float*)d_in[0];   // (8, 4096, 512)
    const float* w = (const float*)d_in[1];   // (8, 512, 512)
    float* out = (float*)d_out;

    char* ob = (char*)d_out;
    u16* Yfh = (u16*)ob;                      // [0, 4MB)  frag-tiled Y hi
    u16* Yfl = (u16*)(ob + (4u  << 20));      // [4, 8)    frag-tiled Y lo
    u16* Mfh = (u16*)(ob + (8u  << 20));      // [8, 12)   frag-tiled M hi
    u16* Mfl = (u16*)(ob + (12u << 20));      // [12, 16)  frag-tiled M lo

    int fat = (ws_size >= ((32u << 20) + (4u << 20))) ? 1 : 0;
    u16* xbp = (u16*)d_ws;
    u16* Qt  = fat ? (u16*)((char*)d_ws + (32u << 20)) : (u16*)d_ws;

    k_panelprep<<<dim3(fat ? 1152 : 128), dim3(1024), 0, stream>>>(w, x, Yfh, Yfl, Mfh, Mfl, xbp);
    k_combine<32><<<dim3(128), dim3(512), 0, stream>>>(Yfh, Yfl, Mfh, Mfl);
    k_combine<64><<<dim3(128), dim3(512), 0, stream>>>(Yfh, Yfl, Mfh, Mfl);
    k_combine<128><<<dim3(128), dim3(512), 0, stream>>>(Yfh, Yfl, Mfh, Mfl);
    k_combine<256><<<dim3(128), dim3(512), 0, stream>>>(Yfh, Yfl, Mfh, Mfl);
    k_qbuild2<<<dim3(512), dim3(256), 0, stream>>>(w, Mfh, Mfl, Qt);
    if (fat)
        k_gemm2<<<dim3(1024), dim3(256), 0, stream>>>(xbp, Qt, out);
    else
        k_gemm_f32<<<dim3(1024), dim3(256), 0, stream>>>(x, Qt, out);
}

// Round 13
// 134.172 us; speedup vs baseline: 1.6097x; 1.0194x over previous
//
#include <hip/hip_runtime.h>

#define GROUP 8
#define BS 4096
#define CH 512
#define PW 32
#define NPANEL 16

typedef __attribute__((ext_vector_type(4))) float f32x4;
typedef __attribute__((ext_vector_type(8))) short bf16x8;
typedef __attribute__((ext_vector_type(8))) unsigned short u16x8;
typedef unsigned short u16;

static __device__ __forceinline__ u16 f2bf(float f) {
    unsigned int u = __builtin_bit_cast(unsigned int, f);
    u += 0x7FFFu + ((u >> 16) & 1u);   // RNE
    return (u16)(u >> 16);
}
static __device__ __forceinline__ float bf2f(u16 h) {
    return __builtin_bit_cast(float, (unsigned int)h << 16);
}
static __device__ __forceinline__ void split8(const float* v, bf16x8& h, bf16x8& l) {
#pragma unroll
    for (int j = 0; j < 8; ++j) {
        u16 hu = f2bf(v[j]);
        h[j] = (short)hu;
        l[j] = (short)f2bf(v[j] - bf2f(hu));
    }
}
#define MFMA(a, b, c) __builtin_amdgcn_mfma_f32_16x16x32_bf16(a, b, c, 0, 0, 0)

typedef const __attribute__((address_space(1))) void* gas_t;
typedef __attribute__((address_space(3))) void* las_t;
static __device__ __forceinline__ void gload16(const void* g, void* l) {
    __builtin_amdgcn_global_load_lds((gas_t)g, (las_t)l, 16, 0, 0);
}

// Yf layout: tile (it<32, ct<16) = rows[it*16,+16) x cols[ct*32,+32);
//   off = (it*16+ct)*512 + lane*8 (lane = kg*16+fr -> row fr, col kg*8..+7).
// Mf layout: tile (kt<16, ct<32) = i in [kt*32,+32), c in [ct*16,+16);
//   off(i,c) = (kt*32+ct)*512 + ((i>>3)&3)*128 + (c&15)*8 + (i&7).
//   One MFMA B-frag (k=i, n=c) = tile_base + lane*8 (coalesced).

// ---------------------------------------------------------------------------
// Kernel 1: per-32-panel prep, 1024 thr. Blocks 0..127: prep.
// Blocks 128..1151 (fat only): x fp32->bf16 cast.
// M export now staged in LDS (exact Mf byte layout) -> coalesced bulk stores.
// ---------------------------------------------------------------------------
__global__ __launch_bounds__(1024) void k_panelprep(const float* __restrict__ w,
                                                    const float* __restrict__ x,
                                                    u16* __restrict__ Yfh,
                                                    u16* __restrict__ Yfl,
                                                    u16* __restrict__ Mfh,
                                                    u16* __restrict__ Mfl,
                                                    u16* __restrict__ xb) {
    __shared__ float Ylds[PW][516];
    __shared__ float Sp[16][PW][36];     // reused as M staging after S-reduce
    __shared__ float S_ls[PW][36];
    __shared__ float T_ls[PW][36];

    int bid = blockIdx.x;
    int t   = threadIdx.x;

    if (bid >= 128) {
        const int TOT8 = GROUP * BS * CH / 8;
        for (int i = (bid - 128) * 1024 + t; i < TOT8; i += 1024 * 1024) {
            const float4* s = (const float4*)(x + (size_t)i * 8);
            float4 a = s[0], b = s[1];
            u16x8 o;
            o[0] = f2bf(a.x); o[1] = f2bf(a.y); o[2] = f2bf(a.z); o[3] = f2bf(a.w);
            o[4] = f2bf(b.x); o[5] = f2bf(b.y); o[6] = f2bf(b.z); o[7] = f2bf(b.w);
            *(u16x8*)(xb + (size_t)i * 8) = o;
        }
        return;
    }

    int lane = t & 63;
    int wv   = t >> 6;
    int fr   = lane & 15;
    int kg   = lane >> 4;
    int g    = bid >> 4;
    int p    = bid & 15;
    int i0   = p * PW;

    const float* wg = w + (size_t)g * CH * CH;
    for (int idx4 = t; idx4 < 4096; idx4 += 1024) {
        int c = idx4 >> 3, f4 = idx4 & 7;
        float4 v = *(const float4*)(wg + (size_t)c * CH + i0 + f4 * 4);
        Ylds[f4 * 4 + 0][c] = v.x;
        Ylds[f4 * 4 + 1][c] = v.y;
        Ylds[f4 * 4 + 2][c] = v.z;
        Ylds[f4 * 4 + 3][c] = v.w;
    }
    __syncthreads();

    {
        f32x4 sacc[2][2];
#pragma unroll
        for (int a = 0; a < 2; ++a)
#pragma unroll
            for (int b = 0; b < 2; ++b)
#pragma unroll
                for (int z = 0; z < 4; ++z) sacc[a][b][z] = 0.f;
        {
            int kk = wv;
            bf16x8 fh[2], fl[2];
#pragma unroll
            for (int h = 0; h < 2; ++h) {
                float a8[8];
                const float* src = &Ylds[h * 16 + fr][kk * 32 + kg * 8];
#pragma unroll
                for (int j = 0; j < 8; ++j) a8[j] = src[j];
                split8(a8, fh[h], fl[h]);
            }
#pragma unroll
            for (int a = 0; a < 2; ++a)
#pragma unroll
                for (int b = 0; b < 2; ++b) {
                    sacc[a][b] = MFMA(fh[a], fh[b], sacc[a][b]);
                    sacc[a][b] = MFMA(fh[a], fl[b], sacc[a][b]);
                    sacc[a][b] = MFMA(fl[a], fh[b], sacc[a][b]);
                }
        }
#pragma unroll
        for (int a = 0; a < 2; ++a)
#pragma unroll
            for (int b = 0; b < 2; ++b)
#pragma unroll
                for (int j = 0; j < 4; ++j)
                    Sp[wv][a * 16 + kg * 4 + j][b * 16 + fr] = sacc[a][b][j];
    }
    __syncthreads();
    for (int idx = t; idx < PW * PW; idx += 1024) {
        int r = idx >> 5, c = idx & 31;
        float s = 0.f;
#pragma unroll
        for (int q = 0; q < 16; ++q) s += Sp[q][r][c];
        S_ls[r][c] = s;
    }
    __syncthreads();

    if (wv == 0) {
        float Trow[PW];
#pragma unroll
        for (int j = 0; j < PW; ++j) Trow[j] = 0.f;
        if (lane < PW) Trow[lane] = 2.0f / S_ls[lane][lane];
#pragma unroll
        for (int k = 1; k < PW; ++k) {
            float acc = 0.f;
#pragma unroll
            for (int j = 0; j < PW; ++j)
                if (j < k) acc += Trow[j] * S_ls[j][k];
            float bk = 2.0f / S_ls[k][k];
            if (lane < k) Trow[k] = -bk * acc;
        }
        if (lane < PW)
#pragma unroll
            for (int j = 0; j < PW; ++j) T_ls[lane][j] = Trow[j];
    }
    __syncthreads();

    // ---- M^T = Y^T * T^T; results staged in LDS in exact Mf byte layout ----
    u16* Msth = (u16*)Sp;            // 16384 u16 = 32 KB
    u16* Mstl = Msth + 16384;        // 32 KB (total 64 KB <= sizeof(Sp))
    {
        bf16x8 tbh[2], tbl[2];
#pragma unroll
        for (int cf = 0; cf < 2; ++cf) {
            float t8[8];
            const float* src = &T_ls[cf * 16 + fr][kg * 8];
#pragma unroll
            for (int j = 0; j < 8; ++j) t8[j] = src[j];
            split8(t8, tbh[cf], tbl[cf]);
        }
#pragma unroll
        for (int rfi = 0; rfi < 2; ++rfi) {
            int rf = 2 * wv + rfi;
            float a8[8];
#pragma unroll
            for (int j = 0; j < 8; ++j) a8[j] = Ylds[kg * 8 + j][rf * 16 + fr];
            bf16x8 ah, al;
            split8(a8, ah, al);
#pragma unroll
            for (int cf = 0; cf < 2; ++cf) {
                f32x4 m;
#pragma unroll
                for (int z = 0; z < 4; ++z) m[z] = 0.f;
                m = MFMA(ah, tbh[cf], m);
                m = MFMA(ah, tbl[cf], m);
                m = MFMA(al, tbh[cf], m);
#pragma unroll
                for (int j = 0; j < 4; ++j) {
                    int c  = rf * 16 + kg * 4 + j;
                    int ii = cf * 16 + fr;
                    int off = ((c >> 4)) * 512 + ((ii >> 3) * 16 + (c & 15)) * 8 + (ii & 7);
                    u16 hu = f2bf(m[j]);
                    Msth[off] = hu;
                    Mstl[off] = f2bf(m[j] - bf2f(hu));
                }
            }
        }
    }
    __syncthreads();
    // ---- coalesced bulk export of M (panel p = tile-row kt = p) ----
    {
        u16* Mfh_g = Mfh + (size_t)g * CH * CH + (size_t)p * 16384;
        u16* Mfl_g = Mfl + (size_t)g * CH * CH + (size_t)p * 16384;
        for (int idx = t; idx < 2048; idx += 1024) {
            *(bf16x8*)(Mfh_g + (size_t)idx * 8) = *(const bf16x8*)(Msth + idx * 8);
            *(bf16x8*)(Mfl_g + (size_t)idx * 8) = *(const bf16x8*)(Mstl + idx * 8);
        }
    }

    // ---- export Y panel bf16 hi/lo in fragment-tiled layout ----
    {
        u16* Yfh_g = Yfh + (size_t)g * CH * CH;
        u16* Yfl_g = Yfl + (size_t)g * CH * CH;
        for (int idx = t; idx < 32 * 64; idx += 1024) {
            int tile = idx >> 6, l2 = idx & 63;
            int itl = tile >> 4, ct = tile & 15;
            int row = l2 & 15, kgg = l2 >> 4;
            float a8[8];
            const float* src = &Ylds[itl * 16 + row][ct * 32 + kgg * 8];
#pragma unroll
            for (int j = 0; j < 8; ++j) a8[j] = src[j];
            bf16x8 h, l;
            split8(a8, h, l);
            size_t off = ((size_t)((2 * p + itl) * 16 + ct)) * 512 + (size_t)l2 * 8;
            *(bf16x8*)(Yfh_g + off) = h;
            *(bf16x8*)(Yfl_g + off) = l;
        }
    }
}

// ---------------------------------------------------------------------------
// Kernel 2 (x4 levels): WY merge, 128 blocks x 512 thr, 16-row strips.
// For W<128 (NF<8) the C-phase K-splits across spare waves (Cpart reduce),
// so all 8 waves stay busy at every level.
// ---------------------------------------------------------------------------
template<int W>
__global__ __launch_bounds__(512) void k_combine(const u16* __restrict__ Yfh,
                                                 const u16* __restrict__ Yfl,
                                                 u16* __restrict__ Mfh,
                                                 u16* __restrict__ Mfl) {
    constexpr int NF   = W / 16;                 // 2,4,8,16
    constexpr int KSPL = (NF >= 8) ? 1 : 8 / NF; // 4,2,1,1
    constexpr int CPW  = (NF + 7) / 8;           // frags/wave when NF>=8

    __shared__ u16 MAh[16][520];
    __shared__ u16 MAl[16][520];
    __shared__ float Cl[16][W + 4];
    __shared__ float Cpart[(KSPL > 1) ? (KSPL - 1) : 1][16][W + 4];

    int t = threadIdx.x, lane = t & 63, wv = t >> 6;   // 8 waves
    int fr = lane & 15, kg = lane >> 4;
    int g  = blockIdx.x >> 4;
    int sg = blockIdx.x & 15;
    constexpr int SP = W / 16;
    int q  = sg / SP, rs = sg % SP;
    int i_top0 = 2 * q * W + rs * 16;
    int i_bot0 = 2 * q * W + W;

    const u16* Yfh_g = Yfh + (size_t)g * CH * CH;
    const u16* Yfl_g = Yfl + (size_t)g * CH * CH;
    u16* Mfh_g = Mfh + (size_t)g * CH * CH;
    u16* Mfl_g = Mfl + (size_t)g * CH * CH;

    int kt_top = i_top0 >> 5;
    int hh     = (i_top0 & 31) >> 3;

    // ---- stage M_top strip -> MA[i][c] (16 x 512) ----
    for (int idx = t; idx < 1024; idx += 512) {
        int c = idx >> 1, sub = idx & 1;
        size_t off = ((size_t)(kt_top * 32 + (c >> 4))) * 512
                   + (size_t)((hh + sub) * 16 + (c & 15)) * 8;
        bf16x8 hv = *(const bf16x8*)(Mfh_g + off);
        bf16x8 lv = *(const bf16x8*)(Mfl_g + off);
#pragma unroll
        for (int j = 0; j < 8; ++j) {
            MAh[sub * 8 + j][c] = (u16)hv[j];
            MAl[sub * 8 + j][c] = (u16)lv[j];
        }
    }
    __syncthreads();

    int ibt = i_bot0 >> 4;

    if constexpr (KSPL == 1) {
        // ---- C-phase, NF>=8: wave = nf (+8 stride), full K ----
        f32x4 accC[CPW];
#pragma unroll
        for (int nfi = 0; nfi < CPW; ++nfi)
#pragma unroll
            for (int z = 0; z < 4; ++z) accC[nfi][z] = 0.f;

        for (int ks = 0; ks < 16; ++ks) {
            bf16x8 ah = *(const bf16x8*)&MAh[fr][ks * 32 + kg * 8];
            bf16x8 al = *(const bf16x8*)&MAl[fr][ks * 32 + kg * 8];
#pragma unroll
            for (int nfi = 0; nfi < CPW; ++nfi) {
                int nf = wv + 8 * nfi;
                if (nf < NF) {
                    size_t yo = ((size_t)((ibt + nf) * 16 + ks)) * 512 + (size_t)lane * 8;
                    bf16x8 bh = *(const bf16x8*)(Yfh_g + yo);
                    bf16x8 bl = *(const bf16x8*)(Yfl_g + yo);
                    accC[nfi] = MFMA(ah, bh, accC[nfi]);
                    accC[nfi] = MFMA(ah, bl, accC[nfi]);
                    accC[nfi] = MFMA(al, bh, accC[nfi]);
                }
            }
        }
#pragma unroll
        for (int nfi = 0; nfi < CPW; ++nfi) {
            int nf = wv + 8 * nfi;
            if (nf < NF)
#pragma unroll
                for (int jj = 0; jj < 4; ++jj)
                    Cl[kg * 4 + jj][nf * 16 + fr] = accC[nfi][jj];
        }
        __syncthreads();
    } else {
        // ---- C-phase, NF<8: wave = (nf, k-slice); partials reduced in LDS ----
        int nf  = wv % NF;
        int ksl = wv / NF;                  // 0..KSPL-1
        constexpr int KCH = 16 / KSPL;
        f32x4 accC;
#pragma unroll
        for (int z = 0; z < 4; ++z) accC[z] = 0.f;

        for (int ki = 0; ki < KCH; ++ki) {
            int ks = ksl * KCH + ki;
            bf16x8 ah = *(const bf16x8*)&MAh[fr][ks * 32 + kg * 8];
            bf16x8 al = *(const bf16x8*)&MAl[fr][ks * 32 + kg * 8];
            size_t yo = ((size_t)((ibt + nf) * 16 + ks)) * 512 + (size_t)lane * 8;
            bf16x8 bh = *(const bf16x8*)(Yfh_g + yo);
            bf16x8 bl = *(const bf16x8*)(Yfl_g + yo);
            accC = MFMA(ah, bh, accC);
            accC = MFMA(ah, bl, accC);
            accC = MFMA(al, bh, accC);
        }
        if (ksl == 0) {
#pragma unroll
            for (int jj = 0; jj < 4; ++jj)
                Cl[kg * 4 + jj][nf * 16 + fr] = accC[jj];
        } else {
#pragma unroll
            for (int jj = 0; jj < 4; ++jj)
                Cpart[ksl - 1][kg * 4 + jj][nf * 16 + fr] = accC[jj];
        }
        __syncthreads();
        for (int idx = t; idx < 16 * W; idx += 512) {
            int r = idx / W, c = idx - r * W;
            float s = Cl[r][c];
#pragma unroll
            for (int u = 0; u < KSPL - 1; ++u) s += Cpart[u][r][c];
            Cl[r][c] = s;
        }
        __syncthreads();
    }

    // ---- U[i][c] = sum_j C[i][j] M_bot[j][c]; coalesced Mf B-frags ----
    f32x4 accU[4];
#pragma unroll
    for (int ni = 0; ni < 4; ++ni)
#pragma unroll
        for (int z = 0; z < 4; ++z) accU[ni][z] = 0.f;

    int kt_bot = i_bot0 >> 5;
    for (int ks2 = 0; ks2 < W / 32; ++ks2) {
        float a8[8];
#pragma unroll
        for (int j = 0; j < 8; ++j) a8[j] = Cl[fr][ks2 * 32 + kg * 8 + j];
        bf16x8 ah2, al2;
        split8(a8, ah2, al2);
#pragma unroll
        for (int ni = 0; ni < 4; ++ni) {
            int ct = wv * 4 + ni;
            size_t mo = ((size_t)((kt_bot + ks2) * 32 + ct)) * 512 + (size_t)lane * 8;
            bf16x8 bh = *(const bf16x8*)(Mfh_g + mo);
            bf16x8 bl = *(const bf16x8*)(Mfl_g + mo);
            accU[ni] = MFMA(ah2, bh, accU[ni]);
            accU[ni] = MFMA(ah2, bl, accU[ni]);
            accU[ni] = MFMA(al2, bh, accU[ni]);
        }
    }
#pragma unroll
    for (int ni = 0; ni < 4; ++ni) {
        int c = (wv * 4 + ni) * 16 + fr;
#pragma unroll
        for (int jj = 0; jj < 4; ++jj) {
            int il = kg * 4 + jj;
            float ma = bf2f(MAh[il][c]) + bf2f(MAl[il][c]);
            float m2 = ma - accU[ni][jj];
            u16 hu = f2bf(m2);
            MAh[il][c] = hu;
            MAl[il][c] = f2bf(m2 - bf2f(hu));
        }
    }
    __syncthreads();

    // ---- writeback strip to Mf ----
    for (int idx = t; idx < 1024; idx += 512) {
        int c = idx >> 1, sub = idx & 1;
        bf16x8 hv, lv;
#pragma unroll
        for (int j = 0; j < 8; ++j) {
            hv[j] = (short)MAh[sub * 8 + j][c];
            lv[j] = (short)MAl[sub * 8 + j][c];
        }
        size_t off = ((size_t)(kt_top * 32 + (c >> 4))) * 512
                   + (size_t)((hh + sub) * 16 + (c & 15)) * 8;
        *(bf16x8*)(Mfh_g + off) = hv;
        *(bf16x8*)(Mfl_g + off) = lv;
    }
}

// ---------------------------------------------------------------------------
// Kernel 3: Qt[g][d][c] = [I - w*M]^T. 512 blocks x 256 thr. (round-12)
// ---------------------------------------------------------------------------
__global__ __launch_bounds__(256) void k_qbuild2(const float* __restrict__ w,
                                                 const u16* __restrict__ Mfh,
                                                 const u16* __restrict__ Mfl,
                                                 u16* __restrict__ Qt) {
    int t = threadIdx.x, lane = t & 63, wv = t >> 6;
    int fr = lane & 15, kg = lane >> 4;
    int g  = blockIdx.x >> 6;
    int tm = (blockIdx.x >> 2) & 15, tn = blockIdx.x & 3;
    int c0 = tm * 32;
    int d0 = tn * 128 + wv * 32;

    const float* wg = w + (size_t)g * CH * CH;
    const u16* Mfh_g = Mfh + (size_t)g * CH * CH;
    const u16* Mfl_g = Mfl + (size_t)g * CH * CH;
    u16* Qt_g = Qt + (size_t)g * CH * CH;

    f32x4 acc[2][2];
#pragma unroll
    for (int mi = 0; mi < 2; ++mi)
#pragma unroll
        for (int ni = 0; ni < 2; ++ni)
#pragma unroll
            for (int z = 0; z < 4; ++z) acc[mi][ni][z] = 0.f;

    for (int ks = 0; ks < 16; ++ks) {
        bf16x8 ah[2], al[2], bh[2], bl[2];
#pragma unroll
        for (int mi = 0; mi < 2; ++mi) {
            const float* src = wg + (size_t)(c0 + mi * 16 + fr) * CH + ks * 32 + kg * 8;
            float4 v0 = *(const float4*)src;
            float4 v1 = *(const float4*)(src + 4);
            float a8[8] = {v0.x, v0.y, v0.z, v0.w, v1.x, v1.y, v1.z, v1.w};
            split8(a8, ah[mi], al[mi]);
        }
#pragma unroll
        for (int ni = 0; ni < 2; ++ni) {
            int ct = (d0 >> 4) + ni;
            size_t mo = ((size_t)(ks * 32 + ct)) * 512 + (size_t)lane * 8;
            bh[ni] = *(const bf16x8*)(Mfh_g + mo);
            bl[ni] = *(const bf16x8*)(Mfl_g + mo);
        }
#pragma unroll
        for (int mi = 0; mi < 2; ++mi)
#pragma unroll
            for (int ni = 0; ni < 2; ++ni) {
                acc[mi][ni] = MFMA(ah[mi], bh[ni], acc[mi][ni]);
                acc[mi][ni] = MFMA(ah[mi], bl[ni], acc[mi][ni]);
                acc[mi][ni] = MFMA(al[mi], bh[ni], acc[mi][ni]);
            }
    }
#pragma unroll
    for (int mi = 0; mi < 2; ++mi)
#pragma unroll
        for (int ni = 0; ni < 2; ++ni) {
            int cb = c0 + mi * 16 + kg * 4;
            int d  = d0 + ni * 16 + fr;
            ushort4 h4;
            h4.x = f2bf(((cb + 0 == d) ? 1.0f : 0.0f) - acc[mi][ni][0]);
            h4.y = f2bf(((cb + 1 == d) ? 1.0f : 0.0f) - acc[mi][ni][1]);
            h4.z = f2bf(((cb + 2 == d) ? 1.0f : 0.0f) - acc[mi][ni][2]);
            h4.w = f2bf(((cb + 3 == d) ? 1.0f : 0.0f) - acc[mi][ni][3]);
            *(ushort4*)(Qt_g + (size_t)d * CH + cb) = h4;
        }
}

// ---------------------------------------------------------------------------
// Kernel 4: 2-phase double-buffered GEMM (round-10/11/12). out = xb @ Qt.
// ---------------------------------------------------------------------------
__global__ __launch_bounds__(256) void k_gemm2(const u16* __restrict__ xb,
                                               const u16* __restrict__ Qt,
                                               float* __restrict__ out) {
    __shared__ u16 Ab[2][128 * 64];
    __shared__ u16 Bb[2][128 * 64];

    int bid0 = blockIdx.x;
    int wg = (bid0 & 7) * 128 + (bid0 >> 3);
    int g  = wg >> 7;
    int r  = wg & 127;
    int tm = r >> 2;
    int tn = r & 3;

    int t    = threadIdx.x;
    int lane = t & 63;
    int wv   = t >> 6;
    int wr   = wv >> 1, wc = wv & 1;
    int fr   = lane & 15, kg = lane >> 4;

    const u16* xg  = xb + (size_t)g * BS * CH + (size_t)tm * 128 * CH;
    const u16* Qtg = Qt + (size_t)g * CH * CH + (size_t)tn * 128 * CH;
    float* og = out + (size_t)g * BS * CH + (size_t)tm * 128 * CH + (size_t)tn * 128;

    f32x4 acc[4][4];
#pragma unroll
    for (int mi = 0; mi < 4; ++mi)
#pragma unroll
        for (int ni = 0; ni < 4; ++ni)
#pragma unroll
            for (int z = 0; z < 4; ++z) acc[mi][ni][z] = 0.f;

    int srow8 = lane >> 3;
    int scol  = (lane & 7) * 8;

    auto STAGE = [&](int p, int ks) {
        int k0 = ks * 64;
#pragma unroll
        for (int si = 0; si < 4; ++si) {
            int seg = wv * 4 + si;
            int row = seg * 8 + srow8;
            gload16(xg  + (size_t)row * CH + k0 + scol, &Ab[p][seg * 512]);
            gload16(Qtg + (size_t)row * CH + k0 + scol, &Bb[p][seg * 512]);
        }
    };

    STAGE(0, 0);
    __syncthreads();

    for (int ks = 0; ks < 8; ++ks) {
        int cur = ks & 1;
        if (ks < 7) STAGE(cur ^ 1, ks + 1);
#pragma unroll
        for (int kk = 0; kk < 2; ++kk) {
            bf16x8 af[4], bfr[4];
#pragma unroll
            for (int mi = 0; mi < 4; ++mi)
                af[mi] = *(const bf16x8*)&Ab[cur][(wr * 64 + mi * 16 + fr) * 64 + kk * 32 + kg * 8];
#pragma unroll
            for (int ni = 0; ni < 4; ++ni)
                bfr[ni] = *(const bf16x8*)&Bb[cur][(wc * 64 + ni * 16 + fr) * 64 + kk * 32 + kg * 8];
#pragma unroll
            for (int mi = 0; mi < 4; ++mi)
#pragma unroll
                for (int ni = 0; ni < 4; ++ni)
                    acc[mi][ni] = MFMA(af[mi], bfr[ni], acc[mi][ni]);
        }
        __syncthreads();
    }

    int rg = lane >> 4;
#pragma unroll
    for (int mi = 0; mi < 4; ++mi)
#pragma unroll
        for (int ni = 0; ni < 4; ++ni)
#pragma unroll
            for (int rj = 0; rj < 4; ++rj) {
                int grow = wr * 64 + mi * 16 + rg * 4 + rj;
                int gcol = wc * 64 + ni * 16 + fr;
                og[(size_t)grow * CH + gcol] = acc[mi][ni][rj];
            }
}

// ---------------------------------------------------------------------------
// Fallback GEMM (fp32 A, in-staging convert) — round-5 verified.
// ---------------------------------------------------------------------------
#define LDP 40
__global__ __launch_bounds__(256) void k_gemm_f32(const float* __restrict__ x,
                                                  const u16* __restrict__ Qt,
                                                  float* __restrict__ out) {
    __shared__ u16 Al[128 * LDP];
    __shared__ u16 Bl[128 * LDP];

    int bid = blockIdx.x;
    int g  = bid >> 7;
    int tn = (bid >> 5) & 3;
    int tm = bid & 31;

    int t    = threadIdx.x;
    int lane = t & 63;
    int w    = t >> 6;
    int wr   = w >> 1, wc = w & 1;

    const float* xg = x + (size_t)g * BS * CH + (size_t)tm * 128 * CH;
    const u16* Qtg = Qt + (size_t)g * CH * CH + (size_t)tn * 128 * CH;
    float* og = out + (size_t)g * BS * CH + (size_t)tm * 128 * CH + (size_t)tn * 128;

    f32x4 acc[4][4];
#pragma unroll
    for (int mi = 0; mi < 4; ++mi)
#pragma unroll
        for (int ni = 0; ni < 4; ++ni)
#pragma unroll
            for (int z = 0; z < 4; ++z) acc[mi][ni][z] = 0.f;

    int a_k4 = t & 7;
    int a_r  = t >> 3;
    int b_n  = t & 127;
    int b_kh = t >> 7;
    int fr = lane & 15, kg = lane >> 4;

    for (int ks = 0; ks < 16; ++ks) {
        int k0 = ks * 32;
        __syncthreads();
#pragma unroll
        for (int rr = 0; rr < 4; ++rr) {
            int r = a_r + 32 * rr;
            float4 v = *(const float4*)(xg + (size_t)r * CH + k0 + a_k4 * 4);
            ushort4 h;
            h.x = f2bf(v.x); h.y = f2bf(v.y); h.z = f2bf(v.z); h.w = f2bf(v.w);
            *(ushort4*)(&Al[r * LDP + a_k4 * 4]) = h;
        }
        {
            const u16* src = Qtg + (size_t)b_n * CH + k0 + b_kh * 16;
            u16x8 lo = *(const u16x8*)src;
            u16x8 hi = *(const u16x8*)(src + 8);
            *(u16x8*)(&Bl[b_n * LDP + b_kh * 16]) = lo;
            *(u16x8*)(&Bl[b_n * LDP + b_kh * 16 + 8]) = hi;
        }
        __syncthreads();
        bf16x8 af[4], bfr[4];
#pragma unroll
        for (int mi = 0; mi < 4; ++mi)
            af[mi] = *(const bf16x8*)(&Al[(wr * 64 + mi * 16 + fr) * LDP + kg * 8]);
#pragma unroll
        for (int ni = 0; ni < 4; ++ni)
            bfr[ni] = *(const bf16x8*)(&Bl[(wc * 64 + ni * 16 + fr) * LDP + kg * 8]);
#pragma unroll
        for (int mi = 0; mi < 4; ++mi)
#pragma unroll
            for (int ni = 0; ni < 4; ++ni)
                acc[mi][ni] = MFMA(af[mi], bfr[ni], acc[mi][ni]);
    }

    int rg = lane >> 4;
#pragma unroll
    for (int mi = 0; mi < 4; ++mi)
#pragma unroll
        for (int ni = 0; ni < 4; ++ni)
#pragma unroll
            for (int rj = 0; rj < 4; ++rj) {
                int grow = wr * 64 + mi * 16 + rg * 4 + rj;
                int gcol = wc * 64 + ni * 16 + fr;
                og[(size_t)grow * CH + gcol] = acc[mi][ni][rj];
            }
}

// ---------------------------------------------------------------------------
extern "C" void kernel_launch(void* const* d_in, const int* in_sizes, int n_in,
                              void* d_out, int out_size, void* d_ws, size_t ws_size,
                              hipStream_t stream) {
    const float* x = (const float*)d_in[0];   // (8, 4096, 512)
    const float* w = (const float*)d_in[1];   // (8, 512, 512)
    float* out = (float*)d_out;

    char* ob = (char*)d_out;
    u16* Yfh = (u16*)ob;                      // [0, 4MB)  frag-tiled Y hi
    u16* Yfl = (u16*)(ob + (4u  << 20));      // [4, 8)    frag-tiled Y lo
    u16* Mfh = (u16*)(ob + (8u  << 20));      // [8, 12)   frag-tiled M hi
    u16* Mfl = (u16*)(ob + (12u << 20));      // [12, 16)  frag-tiled M lo

    int fat = (ws_size >= ((32u << 20) + (4u << 20))) ? 1 : 0;
    u16* xbp = (u16*)d_ws;
    u16* Qt  = fat ? (u16*)((char*)d_ws + (32u << 20)) : (u16*)d_ws;

    k_panelprep<<<dim3(fat ? 1152 : 128), dim3(1024), 0, stream>>>(w, x, Yfh, Yfl, Mfh, Mfl, xbp);
    k_combine<32><<<dim3(128), dim3(512), 0, stream>>>(Yfh, Yfl, Mfh, Mfl);
    k_combine<64><<<dim3(128), dim3(512), 0, stream>>>(Yfh, Yfl, Mfh, Mfl);
    k_combine<128><<<dim3(128), dim3(512), 0, stream>>>(Yfh, Yfl, Mfh, Mfl);
    k_combine<256><<<dim3(128), dim3(512), 0, stream>>>(Yfh, Yfl, Mfh, Mfl);
    k_qbuild2<<<dim3(512), dim3(256), 0, stream>>>(w, Mfh, Mfl, Qt);
    if (fat)
        k_gemm2<<<dim3(1024), dim3(256), 0, stream>>>(xbp, Qt, out);
    else
        k_gemm_f32<<<dim3(1024), dim3(256), 0, stream>>>(x, Qt, out);
}

// Round 14
// 112.058 us; speedup vs baseline: 1.9273x; 1.1973x over previous
//
#include <hip/hip_runtime.h>

#define GROUP 8
#define BS 4096
#define CH 512
#define PW 32
#define NPANEL 16

typedef __attribute__((ext_vector_type(4))) float f32x4;
typedef __attribute__((ext_vector_type(8))) short bf16x8;
typedef __attribute__((ext_vector_type(8))) unsigned short u16x8;
typedef unsigned short u16;

static __device__ __forceinline__ u16 f2bf(float f) {
    unsigned int u = __builtin_bit_cast(unsigned int, f);
    u += 0x7FFFu + ((u >> 16) & 1u);   // RNE
    return (u16)(u >> 16);
}
static __device__ __forceinline__ float bf2f(u16 h) {
    return __builtin_bit_cast(float, (unsigned int)h << 16);
}
static __device__ __forceinline__ void split8(const float* v, bf16x8& h, bf16x8& l) {
#pragma unroll
    for (int j = 0; j < 8; ++j) {
        u16 hu = f2bf(v[j]);
        h[j] = (short)hu;
        l[j] = (short)f2bf(v[j] - bf2f(hu));
    }
}
#define MFMA(a, b, c) __builtin_amdgcn_mfma_f32_16x16x32_bf16(a, b, c, 0, 0, 0)

typedef const __attribute__((address_space(1))) void* gas_t;
typedef __attribute__((address_space(3))) void* las_t;
static __device__ __forceinline__ void gload16(const void* g, void* l) {
    __builtin_amdgcn_global_load_lds((gas_t)g, (las_t)l, 16, 0, 0);
}

// Yf layout: tile (it<32, ct<16) = rows[it*16,+16) x cols[ct*32,+32);
//   off = (it*16+ct)*512 + lane*8.
// Mf layout: tile (kt<16, ct<32) = i in [kt*32,+32), c in [ct*16,+16);
//   off(i,c) = (kt*32+ct)*512 + ((i>>3)&3)*128 + (c&15)*8 + (i&7).
// XCD swizzle convention (all prep kernels share it): group g owns XCD g.

// ---------------------------------------------------------------------------
// Kernel 1: per-32-panel prep, 1024 thr. Blocks 0..127: prep (XCD-swizzled).
// Blocks 128..1151 (fat only): x fp32->bf16 cast.
// ---------------------------------------------------------------------------
__global__ __launch_bounds__(1024) void k_panelprep(const float* __restrict__ w,
                                                    const float* __restrict__ x,
                                                    u16* __restrict__ Yfh,
                                                    u16* __restrict__ Yfl,
                                                    u16* __restrict__ Mfh,
                                                    u16* __restrict__ Mfl,
                                                    u16* __restrict__ xb) {
    __shared__ float Ylds[PW][516];
    __shared__ float Sp[16][PW][36];     // reused as M staging after S-reduce
    __shared__ float S_ls[PW][36];
    __shared__ float T_ls[PW][36];

    int bid = blockIdx.x;
    int t   = threadIdx.x;

    if (bid >= 128) {
        const int TOT8 = GROUP * BS * CH / 8;
        for (int i = (bid - 128) * 1024 + t; i < TOT8; i += 1024 * 1024) {
            const float4* s = (const float4*)(x + (size_t)i * 8);
            float4 a = s[0], b = s[1];
            u16x8 o;
            o[0] = f2bf(a.x); o[1] = f2bf(a.y); o[2] = f2bf(a.z); o[3] = f2bf(a.w);
            o[4] = f2bf(b.x); o[5] = f2bf(b.y); o[6] = f2bf(b.z); o[7] = f2bf(b.w);
            *(u16x8*)(xb + (size_t)i * 8) = o;
        }
        return;
    }

    int pb   = (bid & 7) * 16 + (bid >> 3);   // XCD-chunked (128%8==0)
    int lane = t & 63;
    int wv   = t >> 6;
    int fr   = lane & 15;
    int kg   = lane >> 4;
    int g    = pb >> 4;
    int p    = pb & 15;
    int i0   = p * PW;

    const float* wg = w + (size_t)g * CH * CH;
    for (int idx4 = t; idx4 < 4096; idx4 += 1024) {
        int c = idx4 >> 3, f4 = idx4 & 7;
        float4 v = *(const float4*)(wg + (size_t)c * CH + i0 + f4 * 4);
        Ylds[f4 * 4 + 0][c] = v.x;
        Ylds[f4 * 4 + 1][c] = v.y;
        Ylds[f4 * 4 + 2][c] = v.z;
        Ylds[f4 * 4 + 3][c] = v.w;
    }
    __syncthreads();

    {
        f32x4 sacc[2][2];
#pragma unroll
        for (int a = 0; a < 2; ++a)
#pragma unroll
            for (int b = 0; b < 2; ++b)
#pragma unroll
                for (int z = 0; z < 4; ++z) sacc[a][b][z] = 0.f;
        {
            int kk = wv;
            bf16x8 fh[2], fl[2];
#pragma unroll
            for (int h = 0; h < 2; ++h) {
                float a8[8];
                const float* src = &Ylds[h * 16 + fr][kk * 32 + kg * 8];
#pragma unroll
                for (int j = 0; j < 8; ++j) a8[j] = src[j];
                split8(a8, fh[h], fl[h]);
            }
#pragma unroll
            for (int a = 0; a < 2; ++a)
#pragma unroll
                for (int b = 0; b < 2; ++b) {
                    sacc[a][b] = MFMA(fh[a], fh[b], sacc[a][b]);
                    sacc[a][b] = MFMA(fh[a], fl[b], sacc[a][b]);
                    sacc[a][b] = MFMA(fl[a], fh[b], sacc[a][b]);
                }
        }
#pragma unroll
        for (int a = 0; a < 2; ++a)
#pragma unroll
            for (int b = 0; b < 2; ++b)
#pragma unroll
                for (int j = 0; j < 4; ++j)
                    Sp[wv][a * 16 + kg * 4 + j][b * 16 + fr] = sacc[a][b][j];
    }
    __syncthreads();
    for (int idx = t; idx < PW * PW; idx += 1024) {
        int r = idx >> 5, c = idx & 31;
        float s = 0.f;
#pragma unroll
        for (int q = 0; q < 16; ++q) s += Sp[q][r][c];
        S_ls[r][c] = s;
    }
    __syncthreads();

    if (wv == 0) {
        float Trow[PW];
#pragma unroll
        for (int j = 0; j < PW; ++j) Trow[j] = 0.f;
        if (lane < PW) Trow[lane] = 2.0f / S_ls[lane][lane];
#pragma unroll
        for (int k = 1; k < PW; ++k) {
            float acc = 0.f;
#pragma unroll
            for (int j = 0; j < PW; ++j)
                if (j < k) acc += Trow[j] * S_ls[j][k];
            float bk = 2.0f / S_ls[k][k];
            if (lane < k) Trow[k] = -bk * acc;
        }
        if (lane < PW)
#pragma unroll
            for (int j = 0; j < PW; ++j) T_ls[lane][j] = Trow[j];
    }
    __syncthreads();

    // ---- M^T = Y^T * T^T; staged in LDS in exact Mf byte layout ----
    u16* Msth = (u16*)Sp;
    u16* Mstl = Msth + 16384;
    {
        bf16x8 tbh[2], tbl[2];
#pragma unroll
        for (int cf = 0; cf < 2; ++cf) {
            float t8[8];
            const float* src = &T_ls[cf * 16 + fr][kg * 8];
#pragma unroll
            for (int j = 0; j < 8; ++j) t8[j] = src[j];
            split8(t8, tbh[cf], tbl[cf]);
        }
#pragma unroll
        for (int rfi = 0; rfi < 2; ++rfi) {
            int rf = 2 * wv + rfi;
            float a8[8];
#pragma unroll
            for (int j = 0; j < 8; ++j) a8[j] = Ylds[kg * 8 + j][rf * 16 + fr];
            bf16x8 ah, al;
            split8(a8, ah, al);
#pragma unroll
            for (int cf = 0; cf < 2; ++cf) {
                f32x4 m;
#pragma unroll
                for (int z = 0; z < 4; ++z) m[z] = 0.f;
                m = MFMA(ah, tbh[cf], m);
                m = MFMA(ah, tbl[cf], m);
                m = MFMA(al, tbh[cf], m);
#pragma unroll
                for (int j = 0; j < 4; ++j) {
                    int c  = rf * 16 + kg * 4 + j;
                    int ii = cf * 16 + fr;
                    int off = ((c >> 4)) * 512 + ((ii >> 3) * 16 + (c & 15)) * 8 + (ii & 7);
                    u16 hu = f2bf(m[j]);
                    Msth[off] = hu;
                    Mstl[off] = f2bf(m[j] - bf2f(hu));
                }
            }
        }
    }
    __syncthreads();
    {
        u16* Mfh_g = Mfh + (size_t)g * CH * CH + (size_t)p * 16384;
        u16* Mfl_g = Mfl + (size_t)g * CH * CH + (size_t)p * 16384;
        for (int idx = t; idx < 2048; idx += 1024) {
            *(bf16x8*)(Mfh_g + (size_t)idx * 8) = *(const bf16x8*)(Msth + idx * 8);
            *(bf16x8*)(Mfl_g + (size_t)idx * 8) = *(const bf16x8*)(Mstl + idx * 8);
        }
    }

    // ---- export Y panel bf16 hi/lo in fragment-tiled layout ----
    {
        u16* Yfh_g = Yfh + (size_t)g * CH * CH;
        u16* Yfl_g = Yfl + (size_t)g * CH * CH;
        for (int idx = t; idx < 32 * 64; idx += 1024) {
            int tile = idx >> 6, l2 = idx & 63;
            int itl = tile >> 4, ct = tile & 15;
            int row = l2 & 15, kgg = l2 >> 4;
            float a8[8];
            const float* src = &Ylds[itl * 16 + row][ct * 32 + kgg * 8];
#pragma unroll
            for (int j = 0; j < 8; ++j) a8[j] = src[j];
            bf16x8 h, l;
            split8(a8, h, l);
            size_t off = ((size_t)((2 * p + itl) * 16 + ct)) * 512 + (size_t)l2 * 8;
            *(bf16x8*)(Yfh_g + off) = h;
            *(bf16x8*)(Yfl_g + off) = l;
        }
    }
}

// ---------------------------------------------------------------------------
// Kernel 2 (x4 levels): WY merge, 128 blocks x 512 thr, 16-row strips,
// XCD-swizzled (group g -> XCD g). K-split C-phase for NF<8.
// ---------------------------------------------------------------------------
template<int W>
__global__ __launch_bounds__(512) void k_combine(const u16* __restrict__ Yfh,
                                                 const u16* __restrict__ Yfl,
                                                 u16* __restrict__ Mfh,
                                                 u16* __restrict__ Mfl) {
    constexpr int NF   = W / 16;
    constexpr int KSPL = (NF >= 8) ? 1 : 8 / NF;
    constexpr int CPW  = (NF + 7) / 8;

    __shared__ u16 MAh[16][520];
    __shared__ u16 MAl[16][520];
    __shared__ float Cl[16][W + 4];
    __shared__ float Cpart[(KSPL > 1) ? (KSPL - 1) : 1][16][W + 4];

    int bid = blockIdx.x;
    int cb  = (bid & 7) * 16 + (bid >> 3);    // XCD-chunked (128%8==0)
    int t = threadIdx.x, lane = t & 63, wv = t >> 6;
    int fr = lane & 15, kg = lane >> 4;
    int g  = cb >> 4;
    int sg = cb & 15;
    constexpr int SP = W / 16;
    int q  = sg / SP, rs = sg % SP;
    int i_top0 = 2 * q * W + rs * 16;
    int i_bot0 = 2 * q * W + W;

    const u16* Yfh_g = Yfh + (size_t)g * CH * CH;
    const u16* Yfl_g = Yfl + (size_t)g * CH * CH;
    u16* Mfh_g = Mfh + (size_t)g * CH * CH;
    u16* Mfl_g = Mfl + (size_t)g * CH * CH;

    int kt_top = i_top0 >> 5;
    int hh     = (i_top0 & 31) >> 3;

    for (int idx = t; idx < 1024; idx += 512) {
        int c = idx >> 1, sub = idx & 1;
        size_t off = ((size_t)(kt_top * 32 + (c >> 4))) * 512
                   + (size_t)((hh + sub) * 16 + (c & 15)) * 8;
        bf16x8 hv = *(const bf16x8*)(Mfh_g + off);
        bf16x8 lv = *(const bf16x8*)(Mfl_g + off);
#pragma unroll
        for (int j = 0; j < 8; ++j) {
            MAh[sub * 8 + j][c] = (u16)hv[j];
            MAl[sub * 8 + j][c] = (u16)lv[j];
        }
    }
    __syncthreads();

    int ibt = i_bot0 >> 4;

    if constexpr (KSPL == 1) {
        f32x4 accC[CPW];
#pragma unroll
        for (int nfi = 0; nfi < CPW; ++nfi)
#pragma unroll
            for (int z = 0; z < 4; ++z) accC[nfi][z] = 0.f;

        for (int ks = 0; ks < 16; ++ks) {
            bf16x8 ah = *(const bf16x8*)&MAh[fr][ks * 32 + kg * 8];
            bf16x8 al = *(const bf16x8*)&MAl[fr][ks * 32 + kg * 8];
#pragma unroll
            for (int nfi = 0; nfi < CPW; ++nfi) {
                int nf = wv + 8 * nfi;
                if (nf < NF) {
                    size_t yo = ((size_t)((ibt + nf) * 16 + ks)) * 512 + (size_t)lane * 8;
                    bf16x8 bh = *(const bf16x8*)(Yfh_g + yo);
                    bf16x8 bl = *(const bf16x8*)(Yfl_g + yo);
                    accC[nfi] = MFMA(ah, bh, accC[nfi]);
                    accC[nfi] = MFMA(ah, bl, accC[nfi]);
                    accC[nfi] = MFMA(al, bh, accC[nfi]);
                }
            }
        }
#pragma unroll
        for (int nfi = 0; nfi < CPW; ++nfi) {
            int nf = wv + 8 * nfi;
            if (nf < NF)
#pragma unroll
                for (int jj = 0; jj < 4; ++jj)
                    Cl[kg * 4 + jj][nf * 16 + fr] = accC[nfi][jj];
        }
        __syncthreads();
    } else {
        int nf  = wv % NF;
        int ksl = wv / NF;
        constexpr int KCH = 16 / KSPL;
        f32x4 accC;
#pragma unroll
        for (int z = 0; z < 4; ++z) accC[z] = 0.f;

        for (int ki = 0; ki < KCH; ++ki) {
            int ks = ksl * KCH + ki;
            bf16x8 ah = *(const bf16x8*)&MAh[fr][ks * 32 + kg * 8];
            bf16x8 al = *(const bf16x8*)&MAl[fr][ks * 32 + kg * 8];
            size_t yo = ((size_t)((ibt + nf) * 16 + ks)) * 512 + (size_t)lane * 8;
            bf16x8 bh = *(const bf16x8*)(Yfh_g + yo);
            bf16x8 bl = *(const bf16x8*)(Yfl_g + yo);
            accC = MFMA(ah, bh, accC);
            accC = MFMA(ah, bl, accC);
            accC = MFMA(al, bh, accC);
        }
        if (ksl == 0) {
#pragma unroll
            for (int jj = 0; jj < 4; ++jj)
                Cl[kg * 4 + jj][nf * 16 + fr] = accC[jj];
        } else {
#pragma unroll
            for (int jj = 0; jj < 4; ++jj)
                Cpart[ksl - 1][kg * 4 + jj][nf * 16 + fr] = accC[jj];
        }
        __syncthreads();
        for (int idx = t; idx < 16 * W; idx += 512) {
            int r = idx / W, c = idx - r * W;
            float s = Cl[r][c];
#pragma unroll
            for (int u = 0; u < KSPL - 1; ++u) s += Cpart[u][r][c];
            Cl[r][c] = s;
        }
        __syncthreads();
    }

    f32x4 accU[4];
#pragma unroll
    for (int ni = 0; ni < 4; ++ni)
#pragma unroll
        for (int z = 0; z < 4; ++z) accU[ni][z] = 0.f;

    int kt_bot = i_bot0 >> 5;
    for (int ks2 = 0; ks2 < W / 32; ++ks2) {
        float a8[8];
#pragma unroll
        for (int j = 0; j < 8; ++j) a8[j] = Cl[fr][ks2 * 32 + kg * 8 + j];
        bf16x8 ah2, al2;
        split8(a8, ah2, al2);
#pragma unroll
        for (int ni = 0; ni < 4; ++ni) {
            int ct = wv * 4 + ni;
            size_t mo = ((size_t)((kt_bot + ks2) * 32 + ct)) * 512 + (size_t)lane * 8;
            bf16x8 bh = *(const bf16x8*)(Mfh_g + mo);
            bf16x8 bl = *(const bf16x8*)(Mfl_g + mo);
            accU[ni] = MFMA(ah2, bh, accU[ni]);
            accU[ni] = MFMA(ah2, bl, accU[ni]);
            accU[ni] = MFMA(al2, bh, accU[ni]);
        }
    }
#pragma unroll
    for (int ni = 0; ni < 4; ++ni) {
        int c = (wv * 4 + ni) * 16 + fr;
#pragma unroll
        for (int jj = 0; jj < 4; ++jj) {
            int il = kg * 4 + jj;
            float ma = bf2f(MAh[il][c]) + bf2f(MAl[il][c]);
            float m2 = ma - accU[ni][jj];
            u16 hu = f2bf(m2);
            MAh[il][c] = hu;
            MAl[il][c] = f2bf(m2 - bf2f(hu));
        }
    }
    __syncthreads();

    for (int idx = t; idx < 1024; idx += 512) {
        int c = idx >> 1, sub = idx & 1;
        bf16x8 hv, lv;
#pragma unroll
        for (int j = 0; j < 8; ++j) {
            hv[j] = (short)MAh[sub * 8 + j][c];
            lv[j] = (short)MAl[sub * 8 + j][c];
        }
        size_t off = ((size_t)(kt_top * 32 + (c >> 4))) * 512
                   + (size_t)((hh + sub) * 16 + (c & 15)) * 8;
        *(bf16x8*)(Mfh_g + off) = hv;
        *(bf16x8*)(Mfl_g + off) = lv;
    }
}

// ---------------------------------------------------------------------------
// Kernel 3: Qt[g][d][c] = [I - w*M]^T. 512 blocks x 256 thr, XCD-swizzled
// (group g -> XCD g, matching prep/combine so Mf is L2-resident).
// ---------------------------------------------------------------------------
__global__ __launch_bounds__(256) void k_qbuild2(const float* __restrict__ w,
                                                 const u16* __restrict__ Mfh,
                                                 const u16* __restrict__ Mfl,
                                                 u16* __restrict__ Qt) {
    int bid = blockIdx.x;
    int qb  = (bid & 7) * 64 + (bid >> 3);    // XCD-chunked (512%8==0)
    int t = threadIdx.x, lane = t & 63, wv = t >> 6;
    int fr = lane & 15, kg = lane >> 4;
    int g  = qb >> 6;
    int tm = (qb >> 2) & 15, tn = qb & 3;
    int c0 = tm * 32;
    int d0 = tn * 128 + wv * 32;

    const float* wg = w + (size_t)g * CH * CH;
    const u16* Mfh_g = Mfh + (size_t)g * CH * CH;
    const u16* Mfl_g = Mfl + (size_t)g * CH * CH;
    u16* Qt_g = Qt + (size_t)g * CH * CH;

    f32x4 acc[2][2];
#pragma unroll
    for (int mi = 0; mi < 2; ++mi)
#pragma unroll
        for (int ni = 0; ni < 2; ++ni)
#pragma unroll
            for (int z = 0; z < 4; ++z) acc[mi][ni][z] = 0.f;

    for (int ks = 0; ks < 16; ++ks) {
        bf16x8 ah[2], al[2], bh[2], bl[2];
#pragma unroll
        for (int mi = 0; mi < 2; ++mi) {
            const float* src = wg + (size_t)(c0 + mi * 16 + fr) * CH + ks * 32 + kg * 8;
            float4 v0 = *(const float4*)src;
            float4 v1 = *(const float4*)(src + 4);
            float a8[8] = {v0.x, v0.y, v0.z, v0.w, v1.x, v1.y, v1.z, v1.w};
            split8(a8, ah[mi], al[mi]);
        }
#pragma unroll
        for (int ni = 0; ni < 2; ++ni) {
            int ct = (d0 >> 4) + ni;
            size_t mo = ((size_t)(ks * 32 + ct)) * 512 + (size_t)lane * 8;
            bh[ni] = *(const bf16x8*)(Mfh_g + mo);
            bl[ni] = *(const bf16x8*)(Mfl_g + mo);
        }
#pragma unroll
        for (int mi = 0; mi < 2; ++mi)
#pragma unroll
            for (int ni = 0; ni < 2; ++ni) {
                acc[mi][ni] = MFMA(ah[mi], bh[ni], acc[mi][ni]);
                acc[mi][ni] = MFMA(ah[mi], bl[ni], acc[mi][ni]);
                acc[mi][ni] = MFMA(al[mi], bh[ni], acc[mi][ni]);
            }
    }
#pragma unroll
    for (int mi = 0; mi < 2; ++mi)
#pragma unroll
        for (int ni = 0; ni < 2; ++ni) {
            int cb2 = c0 + mi * 16 + kg * 4;
            int d   = d0 + ni * 16 + fr;
            ushort4 h4;
            h4.x = f2bf(((cb2 + 0 == d) ? 1.0f : 0.0f) - acc[mi][ni][0]);
            h4.y = f2bf(((cb2 + 1 == d) ? 1.0f : 0.0f) - acc[mi][ni][1]);
            h4.z = f2bf(((cb2 + 2 == d) ? 1.0f : 0.0f) - acc[mi][ni][2]);
            h4.w = f2bf(((cb2 + 3 == d) ? 1.0f : 0.0f) - acc[mi][ni][3]);
            *(ushort4*)(Qt_g + (size_t)d * CH + cb2) = h4;
        }
}

// ---------------------------------------------------------------------------
// Kernel 4: 2-phase double-buffered GEMM, BK=32 (32 KB LDS -> 4-5 blocks/CU
// so cross-block TLP hides the barrier drain). out = xb @ Qt.
// ---------------------------------------------------------------------------
__global__ __launch_bounds__(256) void k_gemm2(const u16* __restrict__ xb,
                                               const u16* __restrict__ Qt,
                                               float* __restrict__ out) {
    __shared__ u16 Ab[2][128 * 32];
    __shared__ u16 Bb[2][128 * 32];

    int bid0 = blockIdx.x;
    int wg = (bid0 & 7) * 128 + (bid0 >> 3);  // bijective XCD chunk
    int g  = wg >> 7;
    int r  = wg & 127;
    int tm = r >> 2;
    int tn = r & 3;

    int t    = threadIdx.x;
    int lane = t & 63;
    int wv   = t >> 6;
    int wr   = wv >> 1, wc = wv & 1;
    int fr   = lane & 15, kg = lane >> 4;

    const u16* xg  = xb + (size_t)g * BS * CH + (size_t)tm * 128 * CH;
    const u16* Qtg = Qt + (size_t)g * CH * CH + (size_t)tn * 128 * CH;
    float* og = out + (size_t)g * BS * CH + (size_t)tm * 128 * CH + (size_t)tn * 128;

    f32x4 acc[4][4];
#pragma unroll
    for (int mi = 0; mi < 4; ++mi)
#pragma unroll
        for (int ni = 0; ni < 4; ++ni)
#pragma unroll
            for (int z = 0; z < 4; ++z) acc[mi][ni][z] = 0.f;

    int srow = lane >> 2;        // 0..15 within 16-row segment
    int scol = (lane & 3) * 8;   // bf16 col offset within 32-wide K

    auto STAGE = [&](int p, int ks) {
        int k0 = ks * 32;
#pragma unroll
        for (int si = 0; si < 2; ++si) {
            int seg = wv * 2 + si;           // 8 segments of 16 rows
            int row = seg * 16 + srow;
            gload16(xg  + (size_t)row * CH + k0 + scol, &Ab[p][seg * 512]);
            gload16(Qtg + (size_t)row * CH + k0 + scol, &Bb[p][seg * 512]);
        }
    };

    STAGE(0, 0);
    __syncthreads();

    for (int ks = 0; ks < 16; ++ks) {
        int cur = ks & 1;
        if (ks < 15) STAGE(cur ^ 1, ks + 1);   // loads fly under the MFMAs
        bf16x8 af[4], bfr[4];
#pragma unroll
        for (int mi = 0; mi < 4; ++mi)
            af[mi] = *(const bf16x8*)&Ab[cur][(wr * 64 + mi * 16 + fr) * 32 + kg * 8];
#pragma unroll
        for (int ni = 0; ni < 4; ++ni)
            bfr[ni] = *(const bf16x8*)&Bb[cur][(wc * 64 + ni * 16 + fr) * 32 + kg * 8];
#pragma unroll
        for (int mi = 0; mi < 4; ++mi)
#pragma unroll
            for (int ni = 0; ni < 4; ++ni)
                acc[mi][ni] = MFMA(af[mi], bfr[ni], acc[mi][ni]);
        __syncthreads();
    }

    int rg = lane >> 4;
#pragma unroll
    for (int mi = 0; mi < 4; ++mi)
#pragma unroll
        for (int ni = 0; ni < 4; ++ni)
#pragma unroll
            for (int rj = 0; rj < 4; ++rj) {
                int grow = wr * 64 + mi * 16 + rg * 4 + rj;
                int gcol = wc * 64 + ni * 16 + fr;
                og[(size_t)grow * CH + gcol] = acc[mi][ni][rj];
            }
}

// ---------------------------------------------------------------------------
// Fallback GEMM (fp32 A, in-staging convert) — round-5 verified.
// ---------------------------------------------------------------------------
#define LDP 40
__global__ __launch_bounds__(256) void k_gemm_f32(const float* __restrict__ x,
                                                  const u16* __restrict__ Qt,
                                                  float* __restrict__ out) {
    __shared__ u16 Al[128 * LDP];
    __shared__ u16 Bl[128 * LDP];

    int bid = blockIdx.x;
    int g  = bid >> 7;
    int tn = (bid >> 5) & 3;
    int tm = bid & 31;

    int t    = threadIdx.x;
    int lane = t & 63;
    int w    = t >> 6;
    int wr   = w >> 1, wc = w & 1;

    const float* xg = x + (size_t)g * BS * CH + (size_t)tm * 128 * CH;
    const u16* Qtg = Qt + (size_t)g * CH * CH + (size_t)tn * 128 * CH;
    float* og = out + (size_t)g * BS * CH + (size_t)tm * 128 * CH + (size_t)tn * 128;

    f32x4 acc[4][4];
#pragma unroll
    for (int mi = 0; mi < 4; ++mi)
#pragma unroll
        for (int ni = 0; ni < 4; ++ni)
#pragma unroll
            for (int z = 0; z < 4; ++z) acc[mi][ni][z] = 0.f;

    int a_k4 = t & 7;
    int a_r  = t >> 3;
    int b_n  = t & 127;
    int b_kh = t >> 7;
    int fr = lane & 15, kg = lane >> 4;

    for (int ks = 0; ks < 16; ++ks) {
        int k0 = ks * 32;
        __syncthreads();
#pragma unroll
        for (int rr = 0; rr < 4; ++rr) {
            int r = a_r + 32 * rr;
            float4 v = *(const float4*)(xg + (size_t)r * CH + k0 + a_k4 * 4);
            ushort4 h;
            h.x = f2bf(v.x); h.y = f2bf(v.y); h.z = f2bf(v.z); h.w = f2bf(v.w);
            *(ushort4*)(&Al[r * LDP + a_k4 * 4]) = h;
        }
        {
            const u16* src = Qtg + (size_t)b_n * CH + k0 + b_kh * 16;
            u16x8 lo = *(const u16x8*)src;
            u16x8 hi = *(const u16x8*)(src + 8);
            *(u16x8*)(&Bl[b_n * LDP + b_kh * 16]) = lo;
            *(u16x8*)(&Bl[b_n * LDP + b_kh * 16 + 8]) = hi;
        }
        __syncthreads();
        bf16x8 af[4], bfr[4];
#pragma unroll
        for (int mi = 0; mi < 4; ++mi)
            af[mi] = *(const bf16x8*)(&Al[(wr * 64 + mi * 16 + fr) * LDP + kg * 8]);
#pragma unroll
        for (int ni = 0; ni < 4; ++ni)
            bfr[ni] = *(const bf16x8*)(&Bl[(wc * 64 + ni * 16 + fr) * LDP + kg * 8]);
#pragma unroll
        for (int mi = 0; mi < 4; ++mi)
#pragma unroll
            for (int ni = 0; ni < 4; ++ni)
                acc[mi][ni] = MFMA(af[mi], bfr[ni], acc[mi][ni]);
    }

    int rg = lane >> 4;
#pragma unroll
    for (int mi = 0; mi < 4; ++mi)
#pragma unroll
        for (int ni = 0; ni < 4; ++ni)
#pragma unroll
            for (int rj = 0; rj < 4; ++rj) {
                int grow = wr * 64 + mi * 16 + rg * 4 + rj;
                int gcol = wc * 64 + ni * 16 + fr;
                og[(size_t)grow * CH + gcol] = acc[mi][ni][rj];
            }
}

// ---------------------------------------------------------------------------
extern "C" void kernel_launch(void* const* d_in, const int* in_sizes, int n_in,
                              void* d_out, int out_size, void* d_ws, size_t ws_size,
                              hipStream_t stream) {
    const float* x = (const float*)d_in[0];   // (8, 4096, 512)
    const float* w = (const float*)d_in[1];   // (8, 512, 512)
    float* out = (float*)d_out;

    char* ob = (char*)d_out;
    u16* Yfh = (u16*)ob;                      // [0, 4MB)  frag-tiled Y hi
    u16* Yfl = (u16*)(ob + (4u  << 20));      // [4, 8)    frag-tiled Y lo
    u16* Mfh = (u16*)(ob + (8u  << 20));      // [8, 12)   frag-tiled M hi
    u16* Mfl = (u16*)(ob + (12u << 20));      // [12, 16)  frag-tiled M lo

    int fat = (ws_size >= ((32u << 20) + (4u << 20))) ? 1 : 0;
    u16* xbp = (u16*)d_ws;
    u16* Qt  = fat ? (u16*)((char*)d_ws + (32u << 20)) : (u16*)d_ws;

    k_panelprep<<<dim3(fat ? 1152 : 128), dim3(1024), 0, stream>>>(w, x, Yfh, Yfl, Mfh, Mfl, xbp);
    k_combine<32><<<dim3(128), dim3(512), 0, stream>>>(Yfh, Yfl, Mfh, Mfl);
    k_combine<64><<<dim3(128), dim3(512), 0, stream>>>(Yfh, Yfl, Mfh, Mfl);
    k_combine<128><<<dim3(128), dim3(512), 0, stream>>>(Yfh, Yfl, Mfh, Mfl);
    k_combine<256><<<dim3(128), dim3(512), 0, stream>>>(Yfh, Yfl, Mfh, Mfl);
    k_qbuild2<<<dim3(512), dim3(256), 0, stream>>>(w, Mfh, Mfl, Qt);
    if (fat)
        k_gemm2<<<dim3(1024), dim3(256), 0, stream>>>(xbp, Qt, out);
    else
        k_gemm_f32<<<dim3(1024), dim3(256), 0, stream>>>(x, Qt, out);
}

// Round 15
// 105.998 us; speedup vs baseline: 2.0375x; 1.0572x over previous
//
#include <hip/hip_runtime.h>

#define GROUP 8
#define BS 4096
#define CH 512
#define PW 32
#define NPANEL 16

typedef __attribute__((ext_vector_type(4))) float f32x4;
typedef __attribute__((ext_vector_type(8))) short bf16x8;
typedef __attribute__((ext_vector_type(8))) unsigned short u16x8;
typedef unsigned short u16;

static __device__ __forceinline__ u16 f2bf(float f) {
    unsigned int u = __builtin_bit_cast(unsigned int, f);
    u += 0x7FFFu + ((u >> 16) & 1u);   // RNE
    return (u16)(u >> 16);
}
static __device__ __forceinline__ float bf2f(u16 h) {
    return __builtin_bit_cast(float, (unsigned int)h << 16);
}
static __device__ __forceinline__ void split8(const float* v, bf16x8& h, bf16x8& l) {
#pragma unroll
    for (int j = 0; j < 8; ++j) {
        u16 hu = f2bf(v[j]);
        h[j] = (short)hu;
        l[j] = (short)f2bf(v[j] - bf2f(hu));
    }
}
#define MFMA(a, b, c) __builtin_amdgcn_mfma_f32_16x16x32_bf16(a, b, c, 0, 0, 0)

typedef const __attribute__((address_space(1))) void* gas_t;
typedef __attribute__((address_space(3))) void* las_t;
static __device__ __forceinline__ void gload16(const void* g, void* l) {
    __builtin_amdgcn_global_load_lds((gas_t)g, (las_t)l, 16, 0, 0);
}

// Yf: B-frag tiles over k=c. tile (it<32, ct<16); off = (it*16+ct)*512 + lane*8.
// Mf: B-frag tiles over k=i. tile (kt<16, ct<32);
//   off(i,c) = (kt*32+ct)*512 + ((i>>3)&3)*128 + (c&15)*8 + (i&7).
// Af: A-frag tiles (m=c, k=i). tile (kt<16, mt<32) = c in [mt*16,+16),
//   i in [kt*32,+32); off = (kt*32+mt)*512 + lane*8, lane l -> (m=l&15,
//   k=(l>>4)*8..+7).
// XCD swizzle convention: group g owns XCD g across the whole prep chain.

// ---------------------------------------------------------------------------
// Kernel 1: per-32-panel prep, 1024 thr. Blocks 0..127: prep (XCD-swizzled).
// Blocks 128..1151 (fat only): x fp32->bf16 cast.
// Exports Yf, Mf, and NEW Af (frag-tiled bf16 hi/lo of w for qbuild2's A side).
// ---------------------------------------------------------------------------
__global__ __launch_bounds__(1024) void k_panelprep(const float* __restrict__ w,
                                                    const float* __restrict__ x,
                                                    u16* __restrict__ Yfh,
                                                    u16* __restrict__ Yfl,
                                                    u16* __restrict__ Mfh,
                                                    u16* __restrict__ Mfl,
                                                    u16* __restrict__ Afh,
                                                    u16* __restrict__ Afl,
                                                    u16* __restrict__ xb) {
    __shared__ float Ylds[PW][516];
    __shared__ float Sp[16][PW][36];     // reused as M staging after S-reduce
    __shared__ float S_ls[PW][36];
    __shared__ float T_ls[PW][36];

    int bid = blockIdx.x;
    int t   = threadIdx.x;

    if (bid >= 128) {
        const int TOT8 = GROUP * BS * CH / 8;
        for (int i = (bid - 128) * 1024 + t; i < TOT8; i += 1024 * 1024) {
            const float4* s = (const float4*)(x + (size_t)i * 8);
            float4 a = s[0], b = s[1];
            u16x8 o;
            o[0] = f2bf(a.x); o[1] = f2bf(a.y); o[2] = f2bf(a.z); o[3] = f2bf(a.w);
            o[4] = f2bf(b.x); o[5] = f2bf(b.y); o[6] = f2bf(b.z); o[7] = f2bf(b.w);
            *(u16x8*)(xb + (size_t)i * 8) = o;
        }
        return;
    }

    int pb   = (bid & 7) * 16 + (bid >> 3);   // XCD-chunked (128%8==0)
    int lane = t & 63;
    int wv   = t >> 6;
    int fr   = lane & 15;
    int kg   = lane >> 4;
    int g    = pb >> 4;
    int p    = pb & 15;
    int i0   = p * PW;

    const float* wg = w + (size_t)g * CH * CH;
    for (int idx4 = t; idx4 < 4096; idx4 += 1024) {
        int c = idx4 >> 3, f4 = idx4 & 7;
        float4 v = *(const float4*)(wg + (size_t)c * CH + i0 + f4 * 4);
        Ylds[f4 * 4 + 0][c] = v.x;
        Ylds[f4 * 4 + 1][c] = v.y;
        Ylds[f4 * 4 + 2][c] = v.z;
        Ylds[f4 * 4 + 3][c] = v.w;
    }
    __syncthreads();

    {
        f32x4 sacc[2][2];
#pragma unroll
        for (int a = 0; a < 2; ++a)
#pragma unroll
            for (int b = 0; b < 2; ++b)
#pragma unroll
                for (int z = 0; z < 4; ++z) sacc[a][b][z] = 0.f;
        {
            int kk = wv;
            bf16x8 fh[2], fl[2];
#pragma unroll
            for (int h = 0; h < 2; ++h) {
                float a8[8];
                const float* src = &Ylds[h * 16 + fr][kk * 32 + kg * 8];
#pragma unroll
                for (int j = 0; j < 8; ++j) a8[j] = src[j];
                split8(a8, fh[h], fl[h]);
            }
#pragma unroll
            for (int a = 0; a < 2; ++a)
#pragma unroll
                for (int b = 0; b < 2; ++b) {
                    sacc[a][b] = MFMA(fh[a], fh[b], sacc[a][b]);
                    sacc[a][b] = MFMA(fh[a], fl[b], sacc[a][b]);
                    sacc[a][b] = MFMA(fl[a], fh[b], sacc[a][b]);
                }
        }
#pragma unroll
        for (int a = 0; a < 2; ++a)
#pragma unroll
            for (int b = 0; b < 2; ++b)
#pragma unroll
                for (int j = 0; j < 4; ++j)
                    Sp[wv][a * 16 + kg * 4 + j][b * 16 + fr] = sacc[a][b][j];
    }
    __syncthreads();
    for (int idx = t; idx < PW * PW; idx += 1024) {
        int r = idx >> 5, c = idx & 31;
        float s = 0.f;
#pragma unroll
        for (int q = 0; q < 16; ++q) s += Sp[q][r][c];
        S_ls[r][c] = s;
    }
    __syncthreads();

    if (wv == 0) {
        float Trow[PW];
#pragma unroll
        for (int j = 0; j < PW; ++j) Trow[j] = 0.f;
        if (lane < PW) Trow[lane] = 2.0f / S_ls[lane][lane];
#pragma unroll
        for (int k = 1; k < PW; ++k) {
            float acc = 0.f;
#pragma unroll
            for (int j = 0; j < PW; ++j)
                if (j < k) acc += Trow[j] * S_ls[j][k];
            float bk = 2.0f / S_ls[k][k];
            if (lane < k) Trow[k] = -bk * acc;
        }
        if (lane < PW)
#pragma unroll
            for (int j = 0; j < PW; ++j) T_ls[lane][j] = Trow[j];
    }
    __syncthreads();

    // ---- M^T = Y^T * T^T; staged in LDS in exact Mf byte layout ----
    u16* Msth = (u16*)Sp;
    u16* Mstl = Msth + 16384;
    {
        bf16x8 tbh[2], tbl[2];
#pragma unroll
        for (int cf = 0; cf < 2; ++cf) {
            float t8[8];
            const float* src = &T_ls[cf * 16 + fr][kg * 8];
#pragma unroll
            for (int j = 0; j < 8; ++j) t8[j] = src[j];
            split8(t8, tbh[cf], tbl[cf]);
        }
#pragma unroll
        for (int rfi = 0; rfi < 2; ++rfi) {
            int rf = 2 * wv + rfi;
            float a8[8];
#pragma unroll
            for (int j = 0; j < 8; ++j) a8[j] = Ylds[kg * 8 + j][rf * 16 + fr];
            bf16x8 ah, al;
            split8(a8, ah, al);
#pragma unroll
            for (int cf = 0; cf < 2; ++cf) {
                f32x4 m;
#pragma unroll
                for (int z = 0; z < 4; ++z) m[z] = 0.f;
                m = MFMA(ah, tbh[cf], m);
                m = MFMA(ah, tbl[cf], m);
                m = MFMA(al, tbh[cf], m);
#pragma unroll
                for (int j = 0; j < 4; ++j) {
                    int c  = rf * 16 + kg * 4 + j;
                    int ii = cf * 16 + fr;
                    int off = ((c >> 4)) * 512 + ((ii >> 3) * 16 + (c & 15)) * 8 + (ii & 7);
                    u16 hu = f2bf(m[j]);
                    Msth[off] = hu;
                    Mstl[off] = f2bf(m[j] - bf2f(hu));
                }
            }
        }
    }
    __syncthreads();
    {
        u16* Mfh_g = Mfh + (size_t)g * CH * CH + (size_t)p * 16384;
        u16* Mfl_g = Mfl + (size_t)g * CH * CH + (size_t)p * 16384;
        for (int idx = t; idx < 2048; idx += 1024) {
            *(bf16x8*)(Mfh_g + (size_t)idx * 8) = *(const bf16x8*)(Msth + idx * 8);
            *(bf16x8*)(Mfl_g + (size_t)idx * 8) = *(const bf16x8*)(Mstl + idx * 8);
        }
    }

    // ---- export Y panel (Yf) ----
    {
        u16* Yfh_g = Yfh + (size_t)g * CH * CH;
        u16* Yfl_g = Yfl + (size_t)g * CH * CH;
        for (int idx = t; idx < 32 * 64; idx += 1024) {
            int tile = idx >> 6, l2 = idx & 63;
            int itl = tile >> 4, ct = tile & 15;
            int row = l2 & 15, kgg = l2 >> 4;
            float a8[8];
            const float* src = &Ylds[itl * 16 + row][ct * 32 + kgg * 8];
#pragma unroll
            for (int j = 0; j < 8; ++j) a8[j] = src[j];
            bf16x8 h, l;
            split8(a8, h, l);
            size_t off = ((size_t)((2 * p + itl) * 16 + ct)) * 512 + (size_t)l2 * 8;
            *(bf16x8*)(Yfh_g + off) = h;
            *(bf16x8*)(Yfl_g + off) = l;
        }
    }

    // ---- export Af: A-frag tiles (kt=p, mt=0..31), value w[c][i]=Ylds[i'][c]
    //      lane l2: m-row = l2&15 (c within mt), k-part = l2>>4 (i within kt) ----
    {
        u16* Afh_g = Afh + (size_t)g * CH * CH;
        u16* Afl_g = Afl + (size_t)g * CH * CH;
        for (int idx = t; idx < 32 * 64; idx += 1024) {
            int mt = idx >> 6, l2 = idx & 63;
            int row = l2 & 15, kg2 = l2 >> 4;
            float a8[8];
#pragma unroll
            for (int j = 0; j < 8; ++j) a8[j] = Ylds[kg2 * 8 + j][mt * 16 + row];
            bf16x8 h, l;
            split8(a8, h, l);
            size_t off = ((size_t)(p * 32 + mt)) * 512 + (size_t)l2 * 8;
            *(bf16x8*)(Afh_g + off) = h;
            *(bf16x8*)(Afl_g + off) = l;
        }
    }
}

// ---------------------------------------------------------------------------
// Kernel 2 (x4 levels): WY merge, 128 blocks x 512 thr, 16-row strips,
// XCD-swizzled. K-split C-phase for NF<8. (round-13/14 verified)
// ---------------------------------------------------------------------------
template<int W>
__global__ __launch_bounds__(512) void k_combine(const u16* __restrict__ Yfh,
                                                 const u16* __restrict__ Yfl,
                                                 u16* __restrict__ Mfh,
                                                 u16* __restrict__ Mfl) {
    constexpr int NF   = W / 16;
    constexpr int KSPL = (NF >= 8) ? 1 : 8 / NF;
    constexpr int CPW  = (NF + 7) / 8;

    __shared__ u16 MAh[16][520];
    __shared__ u16 MAl[16][520];
    __shared__ float Cl[16][W + 4];
    __shared__ float Cpart[(KSPL > 1) ? (KSPL - 1) : 1][16][W + 4];

    int bid = blockIdx.x;
    int cb  = (bid & 7) * 16 + (bid >> 3);    // XCD-chunked
    int t = threadIdx.x, lane = t & 63, wv = t >> 6;
    int fr = lane & 15, kg = lane >> 4;
    int g  = cb >> 4;
    int sg = cb & 15;
    constexpr int SP = W / 16;
    int q  = sg / SP, rs = sg % SP;
    int i_top0 = 2 * q * W + rs * 16;
    int i_bot0 = 2 * q * W + W;

    const u16* Yfh_g = Yfh + (size_t)g * CH * CH;
    const u16* Yfl_g = Yfl + (size_t)g * CH * CH;
    u16* Mfh_g = Mfh + (size_t)g * CH * CH;
    u16* Mfl_g = Mfl + (size_t)g * CH * CH;

    int kt_top = i_top0 >> 5;
    int hh     = (i_top0 & 31) >> 3;

    for (int idx = t; idx < 1024; idx += 512) {
        int c = idx >> 1, sub = idx & 1;
        size_t off = ((size_t)(kt_top * 32 + (c >> 4))) * 512
                   + (size_t)((hh + sub) * 16 + (c & 15)) * 8;
        bf16x8 hv = *(const bf16x8*)(Mfh_g + off);
        bf16x8 lv = *(const bf16x8*)(Mfl_g + off);
#pragma unroll
        for (int j = 0; j < 8; ++j) {
            MAh[sub * 8 + j][c] = (u16)hv[j];
            MAl[sub * 8 + j][c] = (u16)lv[j];
        }
    }
    __syncthreads();

    int ibt = i_bot0 >> 4;

    if constexpr (KSPL == 1) {
        f32x4 accC[CPW];
#pragma unroll
        for (int nfi = 0; nfi < CPW; ++nfi)
#pragma unroll
            for (int z = 0; z < 4; ++z) accC[nfi][z] = 0.f;

        for (int ks = 0; ks < 16; ++ks) {
            bf16x8 ah = *(const bf16x8*)&MAh[fr][ks * 32 + kg * 8];
            bf16x8 al = *(const bf16x8*)&MAl[fr][ks * 32 + kg * 8];
#pragma unroll
            for (int nfi = 0; nfi < CPW; ++nfi) {
                int nf = wv + 8 * nfi;
                if (nf < NF) {
                    size_t yo = ((size_t)((ibt + nf) * 16 + ks)) * 512 + (size_t)lane * 8;
                    bf16x8 bh = *(const bf16x8*)(Yfh_g + yo);
                    bf16x8 bl = *(const bf16x8*)(Yfl_g + yo);
                    accC[nfi] = MFMA(ah, bh, accC[nfi]);
                    accC[nfi] = MFMA(ah, bl, accC[nfi]);
                    accC[nfi] = MFMA(al, bh, accC[nfi]);
                }
            }
        }
#pragma unroll
        for (int nfi = 0; nfi < CPW; ++nfi) {
            int nf = wv + 8 * nfi;
            if (nf < NF)
#pragma unroll
                for (int jj = 0; jj < 4; ++jj)
                    Cl[kg * 4 + jj][nf * 16 + fr] = accC[nfi][jj];
        }
        __syncthreads();
    } else {
        int nf  = wv % NF;
        int ksl = wv / NF;
        constexpr int KCH = 16 / KSPL;
        f32x4 accC;
#pragma unroll
        for (int z = 0; z < 4; ++z) accC[z] = 0.f;

        for (int ki = 0; ki < KCH; ++ki) {
            int ks = ksl * KCH + ki;
            bf16x8 ah = *(const bf16x8*)&MAh[fr][ks * 32 + kg * 8];
            bf16x8 al = *(const bf16x8*)&MAl[fr][ks * 32 + kg * 8];
            size_t yo = ((size_t)((ibt + nf) * 16 + ks)) * 512 + (size_t)lane * 8;
            bf16x8 bh = *(const bf16x8*)(Yfh_g + yo);
            bf16x8 bl = *(const bf16x8*)(Yfl_g + yo);
            accC = MFMA(ah, bh, accC);
            accC = MFMA(ah, bl, accC);
            accC = MFMA(al, bh, accC);
        }
        if (ksl == 0) {
#pragma unroll
            for (int jj = 0; jj < 4; ++jj)
                Cl[kg * 4 + jj][nf * 16 + fr] = accC[jj];
        } else {
#pragma unroll
            for (int jj = 0; jj < 4; ++jj)
                Cpart[ksl - 1][kg * 4 + jj][nf * 16 + fr] = accC[jj];
        }
        __syncthreads();
        for (int idx = t; idx < 16 * W; idx += 512) {
            int r = idx / W, c = idx - r * W;
            float s = Cl[r][c];
#pragma unroll
            for (int u = 0; u < KSPL - 1; ++u) s += Cpart[u][r][c];
            Cl[r][c] = s;
        }
        __syncthreads();
    }

    f32x4 accU[4];
#pragma unroll
    for (int ni = 0; ni < 4; ++ni)
#pragma unroll
        for (int z = 0; z < 4; ++z) accU[ni][z] = 0.f;

    int kt_bot = i_bot0 >> 5;
    for (int ks2 = 0; ks2 < W / 32; ++ks2) {
        float a8[8];
#pragma unroll
        for (int j = 0; j < 8; ++j) a8[j] = Cl[fr][ks2 * 32 + kg * 8 + j];
        bf16x8 ah2, al2;
        split8(a8, ah2, al2);
#pragma unroll
        for (int ni = 0; ni < 4; ++ni) {
            int ct = wv * 4 + ni;
            size_t mo = ((size_t)((kt_bot + ks2) * 32 + ct)) * 512 + (size_t)lane * 8;
            bf16x8 bh = *(const bf16x8*)(Mfh_g + mo);
            bf16x8 bl = *(const bf16x8*)(Mfl_g + mo);
            accU[ni] = MFMA(ah2, bh, accU[ni]);
            accU[ni] = MFMA(ah2, bl, accU[ni]);
            accU[ni] = MFMA(al2, bh, accU[ni]);
        }
    }
#pragma unroll
    for (int ni = 0; ni < 4; ++ni) {
        int c = (wv * 4 + ni) * 16 + fr;
#pragma unroll
        for (int jj = 0; jj < 4; ++jj) {
            int il = kg * 4 + jj;
            float ma = bf2f(MAh[il][c]) + bf2f(MAl[il][c]);
            float m2 = ma - accU[ni][jj];
            u16 hu = f2bf(m2);
            MAh[il][c] = hu;
            MAl[il][c] = f2bf(m2 - bf2f(hu));
        }
    }
    __syncthreads();

    for (int idx = t; idx < 1024; idx += 512) {
        int c = idx >> 1, sub = idx & 1;
        bf16x8 hv, lv;
#pragma unroll
        for (int j = 0; j < 8; ++j) {
            hv[j] = (short)MAh[sub * 8 + j][c];
            lv[j] = (short)MAl[sub * 8 + j][c];
        }
        size_t off = ((size_t)(kt_top * 32 + (c >> 4))) * 512
                   + (size_t)((hh + sub) * 16 + (c & 15)) * 8;
        *(bf16x8*)(Mfh_g + off) = hv;
        *(bf16x8*)(Mfl_g + off) = lv;
    }
}

// ---------------------------------------------------------------------------
// Kernel 3: Qt[g][d][c] = [I - w*M]^T. 512 blocks x 256 thr, XCD-swizzled.
// A from Af (coalesced frags, no split VALU), B from Mf. Bit-identical math.
// ---------------------------------------------------------------------------
__global__ __launch_bounds__(256) void k_qbuild2(const u16* __restrict__ Afh,
                                                 const u16* __restrict__ Afl,
                                                 const u16* __restrict__ Mfh,
                                                 const u16* __restrict__ Mfl,
                                                 u16* __restrict__ Qt) {
    int bid = blockIdx.x;
    int qb  = (bid & 7) * 64 + (bid >> 3);    // XCD-chunked
    int t = threadIdx.x, lane = t & 63, wv = t >> 6;
    int fr = lane & 15, kg = lane >> 4;
    int g  = qb >> 6;
    int tm = (qb >> 2) & 15, tn = qb & 3;
    int c0 = tm * 32;
    int d0 = tn * 128 + wv * 32;

    const u16* Afh_g = Afh + (size_t)g * CH * CH;
    const u16* Afl_g = Afl + (size_t)g * CH * CH;
    const u16* Mfh_g = Mfh + (size_t)g * CH * CH;
    const u16* Mfl_g = Mfl + (size_t)g * CH * CH;
    u16* Qt_g = Qt + (size_t)g * CH * CH;

    f32x4 acc[2][2];
#pragma unroll
    for (int mi = 0; mi < 2; ++mi)
#pragma unroll
        for (int ni = 0; ni < 2; ++ni)
#pragma unroll
            for (int z = 0; z < 4; ++z) acc[mi][ni][z] = 0.f;

    int mt0 = c0 >> 4;
    for (int ks = 0; ks < 16; ++ks) {
        bf16x8 ah[2], al[2], bh[2], bl[2];
#pragma unroll
        for (int mi = 0; mi < 2; ++mi) {
            size_t ao = ((size_t)(ks * 32 + mt0 + mi)) * 512 + (size_t)lane * 8;
            ah[mi] = *(const bf16x8*)(Afh_g + ao);
            al[mi] = *(const bf16x8*)(Afl_g + ao);
        }
#pragma unroll
        for (int ni = 0; ni < 2; ++ni) {
            int ct = (d0 >> 4) + ni;
            size_t mo = ((size_t)(ks * 32 + ct)) * 512 + (size_t)lane * 8;
            bh[ni] = *(const bf16x8*)(Mfh_g + mo);
            bl[ni] = *(const bf16x8*)(Mfl_g + mo);
        }
#pragma unroll
        for (int mi = 0; mi < 2; ++mi)
#pragma unroll
            for (int ni = 0; ni < 2; ++ni) {
                acc[mi][ni] = MFMA(ah[mi], bh[ni], acc[mi][ni]);
                acc[mi][ni] = MFMA(ah[mi], bl[ni], acc[mi][ni]);
                acc[mi][ni] = MFMA(al[mi], bh[ni], acc[mi][ni]);
            }
    }
#pragma unroll
    for (int mi = 0; mi < 2; ++mi)
#pragma unroll
        for (int ni = 0; ni < 2; ++ni) {
            int cb2 = c0 + mi * 16 + kg * 4;
            int d   = d0 + ni * 16 + fr;
            ushort4 h4;
            h4.x = f2bf(((cb2 + 0 == d) ? 1.0f : 0.0f) - acc[mi][ni][0]);
            h4.y = f2bf(((cb2 + 1 == d) ? 1.0f : 0.0f) - acc[mi][ni][1]);
            h4.z = f2bf(((cb2 + 2 == d) ? 1.0f : 0.0f) - acc[mi][ni][2]);
            h4.w = f2bf(((cb2 + 3 == d) ? 1.0f : 0.0f) - acc[mi][ni][3]);
            *(ushort4*)(Qt_g + (size_t)d * CH + cb2) = h4;
        }
}

// ---------------------------------------------------------------------------
// Kernel 4: dbuf GEMM with COUNTED vmcnt (T4) — loads never drain to 0 in the
// main loop. BK=32, 32KB LDS (4-5 blocks/CU). Each thread issues exactly 4
// global_load_lds per STAGE -> wait vmcnt(4) keeps next tile in flight.
// ---------------------------------------------------------------------------
__global__ __launch_bounds__(256) void k_gemm2(const u16* __restrict__ xb,
                                               const u16* __restrict__ Qt,
                                               float* __restrict__ out) {
    __shared__ u16 Ab[2][128 * 32];
    __shared__ u16 Bb[2][128 * 32];

    int bid0 = blockIdx.x;
    int wg = (bid0 & 7) * 128 + (bid0 >> 3);  // bijective XCD chunk
    int g  = wg >> 7;
    int r  = wg & 127;
    int tm = r >> 2;
    int tn = r & 3;

    int t    = threadIdx.x;
    int lane = t & 63;
    int wv   = t >> 6;
    int wr   = wv >> 1, wc = wv & 1;
    int fr   = lane & 15, kg = lane >> 4;

    const u16* xg  = xb + (size_t)g * BS * CH + (size_t)tm * 128 * CH;
    const u16* Qtg = Qt + (size_t)g * CH * CH + (size_t)tn * 128 * CH;
    float* og = out + (size_t)g * BS * CH + (size_t)tm * 128 * CH + (size_t)tn * 128;

    f32x4 acc[4][4];
#pragma unroll
    for (int mi = 0; mi < 4; ++mi)
#pragma unroll
        for (int ni = 0; ni < 4; ++ni)
#pragma unroll
            for (int z = 0; z < 4; ++z) acc[mi][ni][z] = 0.f;

    int srow = lane >> 2;
    int scol = (lane & 3) * 8;

    auto STAGE = [&](int p, int ks) {   // exactly 4 gload16 per thread
        int k0 = ks * 32;
#pragma unroll
        for (int si = 0; si < 2; ++si) {
            int seg = wv * 2 + si;
            int row = seg * 16 + srow;
            gload16(xg  + (size_t)row * CH + k0 + scol, &Ab[p][seg * 512]);
            gload16(Qtg + (size_t)row * CH + k0 + scol, &Bb[p][seg * 512]);
        }
    };

    STAGE(0, 0);
    asm volatile("s_waitcnt vmcnt(0)" ::: "memory");
    __builtin_amdgcn_s_barrier();

    for (int ks = 0; ks < 16; ++ks) {
        int cur = ks & 1;
        if (ks < 15) {
            STAGE(cur ^ 1, ks + 1);                       // 4 new loads in flight
            asm volatile("s_waitcnt vmcnt(4)" ::: "memory");  // tile-ks done
        } else {
            asm volatile("s_waitcnt vmcnt(0)" ::: "memory");
        }
        __builtin_amdgcn_s_barrier();                     // tile-ks visible to all

        bf16x8 af[4], bfr[4];
#pragma unroll
        for (int mi = 0; mi < 4; ++mi)
            af[mi] = *(const bf16x8*)&Ab[cur][(wr * 64 + mi * 16 + fr) * 32 + kg * 8];
#pragma unroll
        for (int ni = 0; ni < 4; ++ni)
            bfr[ni] = *(const bf16x8*)&Bb[cur][(wc * 64 + ni * 16 + fr) * 32 + kg * 8];
#pragma unroll
        for (int mi = 0; mi < 4; ++mi)
#pragma unroll
            for (int ni = 0; ni < 4; ++ni)
                acc[mi][ni] = MFMA(af[mi], bfr[ni], acc[mi][ni]);

        asm volatile("" ::: "memory");                    // pin LDS reads above
        __builtin_amdgcn_s_barrier();                     // reads done before overwrite
    }

    int rg = lane >> 4;
#pragma unroll
    for (int mi = 0; mi < 4; ++mi)
#pragma unroll
        for (int ni = 0; ni < 4; ++ni)
#pragma unroll
            for (int rj = 0; rj < 4; ++rj) {
                int grow = wr * 64 + mi * 16 + rg * 4 + rj;
                int gcol = wc * 64 + ni * 16 + fr;
                og[(size_t)grow * CH + gcol] = acc[mi][ni][rj];
            }
}

// ---------------------------------------------------------------------------
// Fallback GEMM (fp32 A, in-staging convert) — round-5 verified.
// ---------------------------------------------------------------------------
#define LDP 40
__global__ __launch_bounds__(256) void k_gemm_f32(const float* __restrict__ x,
                                                  const u16* __restrict__ Qt,
                                                  float* __restrict__ out) {
    __shared__ u16 Al[128 * LDP];
    __shared__ u16 Bl[128 * LDP];

    int bid = blockIdx.x;
    int g  = bid >> 7;
    int tn = (bid >> 5) & 3;
    int tm = bid & 31;

    int t    = threadIdx.x;
    int lane = t & 63;
    int w    = t >> 6;
    int wr   = w >> 1, wc = w & 1;

    const float* xg = x + (size_t)g * BS * CH + (size_t)tm * 128 * CH;
    const u16* Qtg = Qt + (size_t)g * CH * CH + (size_t)tn * 128 * CH;
    float* og = out + (size_t)g * BS * CH + (size_t)tm * 128 * CH + (size_t)tn * 128;

    f32x4 acc[4][4];
#pragma unroll
    for (int mi = 0; mi < 4; ++mi)
#pragma unroll
        for (int ni = 0; ni < 4; ++ni)
#pragma unroll
            for (int z = 0; z < 4; ++z) acc[mi][ni][z] = 0.f;

    int a_k4 = t & 7;
    int a_r  = t >> 3;
    int b_n  = t & 127;
    int b_kh = t >> 7;
    int fr = lane & 15, kg = lane >> 4;

    for (int ks = 0; ks < 16; ++ks) {
        int k0 = ks * 32;
        __syncthreads();
#pragma unroll
        for (int rr = 0; rr < 4; ++rr) {
            int r = a_r + 32 * rr;
            float4 v = *(const float4*)(xg + (size_t)r * CH + k0 + a_k4 * 4);
            ushort4 h;
            h.x = f2bf(v.x); h.y = f2bf(v.y); h.z = f2bf(v.z); h.w = f2bf(v.w);
            *(ushort4*)(&Al[r * LDP + a_k4 * 4]) = h;
        }
        {
            const u16* src = Qtg + (size_t)b_n * CH + k0 + b_kh * 16;
            u16x8 lo = *(const u16x8*)src;
            u16x8 hi = *(const u16x8*)(src + 8);
            *(u16x8*)(&Bl[b_n * LDP + b_kh * 16]) = lo;
            *(u16x8*)(&Bl[b_n * LDP + b_kh * 16 + 8]) = hi;
        }
        __syncthreads();
        bf16x8 af[4], bfr[4];
#pragma unroll
        for (int mi = 0; mi < 4; ++mi)
            af[mi] = *(const bf16x8*)(&Al[(wr * 64 + mi * 16 + fr) * LDP + kg * 8]);
#pragma unroll
        for (int ni = 0; ni < 4; ++ni)
            bfr[ni] = *(const bf16x8*)(&Bl[(wc * 64 + ni * 16 + fr) * LDP + kg * 8]);
#pragma unroll
        for (int mi = 0; mi < 4; ++mi)
#pragma unroll
            for (int ni = 0; ni < 4; ++ni)
                acc[mi][ni] = MFMA(af[mi], bfr[ni], acc[mi][ni]);
    }

    int rg = lane >> 4;
#pragma unroll
    for (int mi = 0; mi < 4; ++mi)
#pragma unroll
        for (int ni = 0; ni < 4; ++ni)
#pragma unroll
            for (int rj = 0; rj < 4; ++rj) {
                int grow = wr * 64 + mi * 16 + rg * 4 + rj;
                int gcol = wc * 64 + ni * 16 + fr;
                og[(size_t)grow * CH + gcol] = acc[mi][ni][rj];
            }
}

// ---------------------------------------------------------------------------
extern "C" void kernel_launch(void* const* d_in, const int* in_sizes, int n_in,
                              void* d_out, int out_size, void* d_ws, size_t ws_size,
                              hipStream_t stream) {
    const float* x = (const float*)d_in[0];   // (8, 4096, 512)
    const float* w = (const float*)d_in[1];   // (8, 512, 512)
    float* out = (float*)d_out;

    char* ob = (char*)d_out;                  // 64 MiB scratch, dead before GEMM
    u16* Yfh = (u16*)ob;                      // [0, 4MB)
    u16* Yfl = (u16*)(ob + (4u  << 20));      // [4, 8)
    u16* Mfh = (u16*)(ob + (8u  << 20));      // [8, 12)
    u16* Mfl = (u16*)(ob + (12u << 20));      // [12, 16)
    u16* Afh = (u16*)(ob + (16u << 20));      // [16, 20)
    u16* Afl = (u16*)(ob + (20u << 20));      // [20, 24)

    int fat = (ws_size >= ((32u << 20) + (4u << 20))) ? 1 : 0;
    u16* xbp = (u16*)d_ws;
    u16* Qt  = fat ? (u16*)((char*)d_ws + (32u << 20)) : (u16*)d_ws;

    k_panelprep<<<dim3(fat ? 1152 : 128), dim3(1024), 0, stream>>>(w, x, Yfh, Yfl, Mfh, Mfl, Afh, Afl, xbp);
    k_combine<32><<<dim3(128), dim3(512), 0, stream>>>(Yfh, Yfl, Mfh, Mfl);
    k_combine<64><<<dim3(128), dim3(512), 0, stream>>>(Yfh, Yfl, Mfh, Mfl);
    k_combine<128><<<dim3(128), dim3(512), 0, stream>>>(Yfh, Yfl, Mfh, Mfl);
    k_combine<256><<<dim3(128), dim3(512), 0, stream>>>(Yfh, Yfl, Mfh, Mfl);
    k_qbuild2<<<dim3(512), dim3(256), 0, stream>>>(Afh, Afl, Mfh, Mfl, Qt);
    if (fat)
        k_gemm2<<<dim3(1024), dim3(256), 0, stream>>>(xbp, Qt, out);
    else
        k_gemm_f32<<<dim3(1024), dim3(256), 0, stream>>>(x, Qt, out);
}

// Round 16
// 102.049 us; speedup vs baseline: 2.1164x; 1.0387x over previous
//
#include <hip/hip_runtime.h>

#define GROUP 8
#define BS 4096
#define CH 512
#define PW 32
#define NPANEL 16

typedef __attribute__((ext_vector_type(4))) float f32x4;
typedef __attribute__((ext_vector_type(8))) short bf16x8;
typedef __attribute__((ext_vector_type(8))) unsigned short u16x8;
typedef unsigned short u16;

static __device__ __forceinline__ u16 f2bf(float f) {
    unsigned int u = __builtin_bit_cast(unsigned int, f);
    u += 0x7FFFu + ((u >> 16) & 1u);   // RNE
    return (u16)(u >> 16);
}
static __device__ __forceinline__ float bf2f(u16 h) {
    return __builtin_bit_cast(float, (unsigned int)h << 16);
}
static __device__ __forceinline__ void split8(const float* v, bf16x8& h, bf16x8& l) {
#pragma unroll
    for (int j = 0; j < 8; ++j) {
        u16 hu = f2bf(v[j]);
        h[j] = (short)hu;
        l[j] = (short)f2bf(v[j] - bf2f(hu));
    }
}
#define MFMA(a, b, c) __builtin_amdgcn_mfma_f32_16x16x32_bf16(a, b, c, 0, 0, 0)

typedef const __attribute__((address_space(1))) void* gas_t;
typedef __attribute__((address_space(3))) void* las_t;
static __device__ __forceinline__ void gload16(const void* g, void* l) {
    __builtin_amdgcn_global_load_lds((gas_t)g, (las_t)l, 16, 0, 0);
}

// Yf: B-frag tiles over k=c. tile (it<32, ct<16); off = (it*16+ct)*512 + lane*8.
// Mf: B-frag tiles over k=i. tile (kt<16, ct<32);
//   off(i,c) = (kt*32+ct)*512 + ((i>>3)&3)*128 + (c&15)*8 + (i&7).
// Af: A-frag tiles (m=c, k=i). tile (kt<16, mt<32); off = (kt*32+mt)*512 + lane*8.
// XCD swizzle convention: group g owns XCD g across prep chain, xcast, gemm.

// ---------------------------------------------------------------------------
// Kernel 1: per-32-panel prep, 1024 thr. Blocks 0..127: prep (XCD-swizzled).
// Blocks 128..1151 (fat only): x fp32->bf16 cast, group g on XCD g so xb is
// L2-warm for k_gemm2's matching g->XCD mapping.
// ---------------------------------------------------------------------------
__global__ __launch_bounds__(1024) void k_panelprep(const float* __restrict__ w,
                                                    const float* __restrict__ x,
                                                    u16* __restrict__ Yfh,
                                                    u16* __restrict__ Yfl,
                                                    u16* __restrict__ Mfh,
                                                    u16* __restrict__ Mfl,
                                                    u16* __restrict__ Afh,
                                                    u16* __restrict__ Afl,
                                                    u16* __restrict__ xb) {
    __shared__ float Ylds[PW][516];
    __shared__ float Sp[16][PW][36];     // reused as M staging after S-reduce
    __shared__ float S_ls[PW][36];
    __shared__ float T_ls[PW][36];

    int bid = blockIdx.x;
    int t   = threadIdx.x;

    if (bid >= 128) {
        // xcast: block bx covers slice j of group (bx&7); (128+bx)%8 == bx%8,
        // so this block runs on XCD == its group under bid%8 dispatch.
        int bx  = bid - 128;                       // 0..1023
        int xcd = bx & 7;
        int j   = bx >> 3;                         // 0..127
        const int UPG = (BS * CH) / 8;             // 262144 units per group
        int base = xcd * UPG + j * (UPG / 128);    // 2048 units per block
        for (int u = t; u < 2048; u += 1024) {
            int i = base + u;
            const float4* s = (const float4*)(x + (size_t)i * 8);
            float4 a = s[0], b = s[1];
            u16x8 o;
            o[0] = f2bf(a.x); o[1] = f2bf(a.y); o[2] = f2bf(a.z); o[3] = f2bf(a.w);
            o[4] = f2bf(b.x); o[5] = f2bf(b.y); o[6] = f2bf(b.z); o[7] = f2bf(b.w);
            *(u16x8*)(xb + (size_t)i * 8) = o;
        }
        return;
    }

    int pb   = (bid & 7) * 16 + (bid >> 3);   // XCD-chunked (128%8==0)
    int lane = t & 63;
    int wv   = t >> 6;
    int fr   = lane & 15;
    int kg   = lane >> 4;
    int g    = pb >> 4;
    int p    = pb & 15;
    int i0   = p * PW;

    const float* wg = w + (size_t)g * CH * CH;
    for (int idx4 = t; idx4 < 4096; idx4 += 1024) {
        int c = idx4 >> 3, f4 = idx4 & 7;
        float4 v = *(const float4*)(wg + (size_t)c * CH + i0 + f4 * 4);
        Ylds[f4 * 4 + 0][c] = v.x;
        Ylds[f4 * 4 + 1][c] = v.y;
        Ylds[f4 * 4 + 2][c] = v.z;
        Ylds[f4 * 4 + 3][c] = v.w;
    }
    __syncthreads();

    {
        f32x4 sacc[2][2];
#pragma unroll
        for (int a = 0; a < 2; ++a)
#pragma unroll
            for (int b = 0; b < 2; ++b)
#pragma unroll
                for (int z = 0; z < 4; ++z) sacc[a][b][z] = 0.f;
        {
            int kk = wv;
            bf16x8 fh[2], fl[2];
#pragma unroll
            for (int h = 0; h < 2; ++h) {
                float a8[8];
                const float* src = &Ylds[h * 16 + fr][kk * 32 + kg * 8];
#pragma unroll
                for (int j = 0; j < 8; ++j) a8[j] = src[j];
                split8(a8, fh[h], fl[h]);
            }
#pragma unroll
            for (int a = 0; a < 2; ++a)
#pragma unroll
                for (int b = 0; b < 2; ++b) {
                    sacc[a][b] = MFMA(fh[a], fh[b], sacc[a][b]);
                    sacc[a][b] = MFMA(fh[a], fl[b], sacc[a][b]);
                    sacc[a][b] = MFMA(fl[a], fh[b], sacc[a][b]);
                }
        }
#pragma unroll
        for (int a = 0; a < 2; ++a)
#pragma unroll
            for (int b = 0; b < 2; ++b)
#pragma unroll
                for (int j = 0; j < 4; ++j)
                    Sp[wv][a * 16 + kg * 4 + j][b * 16 + fr] = sacc[a][b][j];
    }
    __syncthreads();
    for (int idx = t; idx < PW * PW; idx += 1024) {
        int r = idx >> 5, c = idx & 31;
        float s = 0.f;
#pragma unroll
        for (int q = 0; q < 16; ++q) s += Sp[q][r][c];
        S_ls[r][c] = s;
    }
    __syncthreads();

    if (wv == 0) {
        float Trow[PW];
#pragma unroll
        for (int j = 0; j < PW; ++j) Trow[j] = 0.f;
        if (lane < PW) Trow[lane] = 2.0f / S_ls[lane][lane];
#pragma unroll
        for (int k = 1; k < PW; ++k) {
            float acc = 0.f;
#pragma unroll
            for (int j = 0; j < PW; ++j)
                if (j < k) acc += Trow[j] * S_ls[j][k];
            float bk = 2.0f / S_ls[k][k];
            if (lane < k) Trow[k] = -bk * acc;
        }
        if (lane < PW)
#pragma unroll
            for (int j = 0; j < PW; ++j) T_ls[lane][j] = Trow[j];
    }
    __syncthreads();

    // ---- M^T = Y^T * T^T; staged in LDS in exact Mf byte layout ----
    u16* Msth = (u16*)Sp;
    u16* Mstl = Msth + 16384;
    {
        bf16x8 tbh[2], tbl[2];
#pragma unroll
        for (int cf = 0; cf < 2; ++cf) {
            float t8[8];
            const float* src = &T_ls[cf * 16 + fr][kg * 8];
#pragma unroll
            for (int j = 0; j < 8; ++j) t8[j] = src[j];
            split8(t8, tbh[cf], tbl[cf]);
        }
#pragma unroll
        for (int rfi = 0; rfi < 2; ++rfi) {
            int rf = 2 * wv + rfi;
            float a8[8];
#pragma unroll
            for (int j = 0; j < 8; ++j) a8[j] = Ylds[kg * 8 + j][rf * 16 + fr];
            bf16x8 ah, al;
            split8(a8, ah, al);
#pragma unroll
            for (int cf = 0; cf < 2; ++cf) {
                f32x4 m;
#pragma unroll
                for (int z = 0; z < 4; ++z) m[z] = 0.f;
                m = MFMA(ah, tbh[cf], m);
                m = MFMA(ah, tbl[cf], m);
                m = MFMA(al, tbh[cf], m);
#pragma unroll
                for (int j = 0; j < 4; ++j) {
                    int c  = rf * 16 + kg * 4 + j;
                    int ii = cf * 16 + fr;
                    int off = ((c >> 4)) * 512 + ((ii >> 3) * 16 + (c & 15)) * 8 + (ii & 7);
                    u16 hu = f2bf(m[j]);
                    Msth[off] = hu;
                    Mstl[off] = f2bf(m[j] - bf2f(hu));
                }
            }
        }
    }
    __syncthreads();
    {
        u16* Mfh_g = Mfh + (size_t)g * CH * CH + (size_t)p * 16384;
        u16* Mfl_g = Mfl + (size_t)g * CH * CH + (size_t)p * 16384;
        for (int idx = t; idx < 2048; idx += 1024) {
            *(bf16x8*)(Mfh_g + (size_t)idx * 8) = *(const bf16x8*)(Msth + idx * 8);
            *(bf16x8*)(Mfl_g + (size_t)idx * 8) = *(const bf16x8*)(Mstl + idx * 8);
        }
    }

    // ---- export Y panel (Yf) ----
    {
        u16* Yfh_g = Yfh + (size_t)g * CH * CH;
        u16* Yfl_g = Yfl + (size_t)g * CH * CH;
        for (int idx = t; idx < 32 * 64; idx += 1024) {
            int tile = idx >> 6, l2 = idx & 63;
            int itl = tile >> 4, ct = tile & 15;
            int row = l2 & 15, kgg = l2 >> 4;
            float a8[8];
            const float* src = &Ylds[itl * 16 + row][ct * 32 + kgg * 8];
#pragma unroll
            for (int j = 0; j < 8; ++j) a8[j] = src[j];
            bf16x8 h, l;
            split8(a8, h, l);
            size_t off = ((size_t)((2 * p + itl) * 16 + ct)) * 512 + (size_t)l2 * 8;
            *(bf16x8*)(Yfh_g + off) = h;
            *(bf16x8*)(Yfl_g + off) = l;
        }
    }

    // ---- export Af ----
    {
        u16* Afh_g = Afh + (size_t)g * CH * CH;
        u16* Afl_g = Afl + (size_t)g * CH * CH;
        for (int idx = t; idx < 32 * 64; idx += 1024) {
            int mt = idx >> 6, l2 = idx & 63;
            int row = l2 & 15, kg2 = l2 >> 4;
            float a8[8];
#pragma unroll
            for (int j = 0; j < 8; ++j) a8[j] = Ylds[kg2 * 8 + j][mt * 16 + row];
            bf16x8 h, l;
            split8(a8, h, l);
            size_t off = ((size_t)(p * 32 + mt)) * 512 + (size_t)l2 * 8;
            *(bf16x8*)(Afh_g + off) = h;
            *(bf16x8*)(Afl_g + off) = l;
        }
    }
}

// ---------------------------------------------------------------------------
// Kernel 2 (x4 levels): WY merge, 128 blocks x 512 thr, 16-row strips,
// XCD-swizzled. Software-pipelined global B-loads (depth-1 prefetch) in both
// the C-phase and U-phase; fully-unrolled loops, static register sets.
// ---------------------------------------------------------------------------
template<int W>
__global__ __launch_bounds__(512) void k_combine(const u16* __restrict__ Yfh,
                                                 const u16* __restrict__ Yfl,
                                                 u16* __restrict__ Mfh,
                                                 u16* __restrict__ Mfl) {
    constexpr int NF   = W / 16;
    constexpr int KSPL = (NF >= 8) ? 1 : 8 / NF;
    constexpr int CPW  = (NF + 7) / 8;

    __shared__ u16 MAh[16][520];
    __shared__ u16 MAl[16][520];
    __shared__ float Cl[16][W + 4];
    __shared__ float Cpart[(KSPL > 1) ? (KSPL - 1) : 1][16][W + 4];

    int bid = blockIdx.x;
    int cb  = (bid & 7) * 16 + (bid >> 3);    // XCD-chunked
    int t = threadIdx.x, lane = t & 63, wv = t >> 6;
    int fr = lane & 15, kg = lane >> 4;
    int g  = cb >> 4;
    int sg = cb & 15;
    constexpr int SP = W / 16;
    int q  = sg / SP, rs = sg % SP;
    int i_top0 = 2 * q * W + rs * 16;
    int i_bot0 = 2 * q * W + W;

    const u16* Yfh_g = Yfh + (size_t)g * CH * CH;
    const u16* Yfl_g = Yfl + (size_t)g * CH * CH;
    u16* Mfh_g = Mfh + (size_t)g * CH * CH;
    u16* Mfl_g = Mfl + (size_t)g * CH * CH;

    int kt_top = i_top0 >> 5;
    int hh     = (i_top0 & 31) >> 3;

    for (int idx = t; idx < 1024; idx += 512) {
        int c = idx >> 1, sub = idx & 1;
        size_t off = ((size_t)(kt_top * 32 + (c >> 4))) * 512
                   + (size_t)((hh + sub) * 16 + (c & 15)) * 8;
        bf16x8 hv = *(const bf16x8*)(Mfh_g + off);
        bf16x8 lv = *(const bf16x8*)(Mfl_g + off);
#pragma unroll
        for (int j = 0; j < 8; ++j) {
            MAh[sub * 8 + j][c] = (u16)hv[j];
            MAl[sub * 8 + j][c] = (u16)lv[j];
        }
    }
    __syncthreads();

    int ibt = i_bot0 >> 4;

    if constexpr (KSPL == 1) {
        f32x4 accC[CPW];
#pragma unroll
        for (int nfi = 0; nfi < CPW; ++nfi)
#pragma unroll
            for (int z = 0; z < 4; ++z) accC[nfi][z] = 0.f;

        auto LOADY = [&](int ks, bf16x8* dh, bf16x8* dl) {
#pragma unroll
            for (int nfi = 0; nfi < CPW; ++nfi) {
                int nf = wv + 8 * nfi;
                size_t yo = ((size_t)((ibt + nf) * 16 + ks)) * 512 + (size_t)lane * 8;
                dh[nfi] = *(const bf16x8*)(Yfh_g + yo);
                dl[nfi] = *(const bf16x8*)(Yfl_g + yo);
            }
        };

        bf16x8 pbh[CPW], pbl[CPW];
        LOADY(0, pbh, pbl);
#pragma unroll
        for (int ks = 0; ks < 16; ++ks) {
            bf16x8 qbh[CPW], qbl[CPW];
            if (ks + 1 < 16) LOADY(ks + 1, qbh, qbl);   // prefetch next step
            bf16x8 ah = *(const bf16x8*)&MAh[fr][ks * 32 + kg * 8];
            bf16x8 al = *(const bf16x8*)&MAl[fr][ks * 32 + kg * 8];
#pragma unroll
            for (int nfi = 0; nfi < CPW; ++nfi) {
                accC[nfi] = MFMA(ah, pbh[nfi], accC[nfi]);
                accC[nfi] = MFMA(ah, pbl[nfi], accC[nfi]);
                accC[nfi] = MFMA(al, pbh[nfi], accC[nfi]);
            }
#pragma unroll
            for (int nfi = 0; nfi < CPW; ++nfi) { pbh[nfi] = qbh[nfi]; pbl[nfi] = qbl[nfi]; }
        }
#pragma unroll
        for (int nfi = 0; nfi < CPW; ++nfi) {
            int nf = wv + 8 * nfi;
#pragma unroll
            for (int jj = 0; jj < 4; ++jj)
                Cl[kg * 4 + jj][nf * 16 + fr] = accC[nfi][jj];
        }
        __syncthreads();
    } else {
        int nf  = wv % NF;
        int ksl = wv / NF;
        constexpr int KCH = 16 / KSPL;
        f32x4 accC;
#pragma unroll
        for (int z = 0; z < 4; ++z) accC[z] = 0.f;

        auto LOADY1 = [&](int ks, bf16x8& dh, bf16x8& dl) {
            size_t yo = ((size_t)((ibt + nf) * 16 + ks)) * 512 + (size_t)lane * 8;
            dh = *(const bf16x8*)(Yfh_g + yo);
            dl = *(const bf16x8*)(Yfl_g + yo);
        };

        bf16x8 pbh, pbl;
        LOADY1(ksl * KCH, pbh, pbl);
#pragma unroll
        for (int ki = 0; ki < KCH; ++ki) {
            int ks = ksl * KCH + ki;
            bf16x8 qbh, qbl;
            if (ki + 1 < KCH) LOADY1(ks + 1, qbh, qbl);
            bf16x8 ah = *(const bf16x8*)&MAh[fr][ks * 32 + kg * 8];
            bf16x8 al = *(const bf16x8*)&MAl[fr][ks * 32 + kg * 8];
            accC = MFMA(ah, pbh, accC);
            accC = MFMA(ah, pbl, accC);
            accC = MFMA(al, pbh, accC);
            pbh = qbh; pbl = qbl;
        }
        if (ksl == 0) {
#pragma unroll
            for (int jj = 0; jj < 4; ++jj)
                Cl[kg * 4 + jj][nf * 16 + fr] = accC[jj];
        } else {
#pragma unroll
            for (int jj = 0; jj < 4; ++jj)
                Cpart[ksl - 1][kg * 4 + jj][nf * 16 + fr] = accC[jj];
        }
        __syncthreads();
        for (int idx = t; idx < 16 * W; idx += 512) {
            int r = idx / W, c = idx - r * W;
            float s = Cl[r][c];
#pragma unroll
            for (int u = 0; u < KSPL - 1; ++u) s += Cpart[u][r][c];
            Cl[r][c] = s;
        }
        __syncthreads();
    }

    // ---- U-phase with depth-1 prefetch of M_bot frags ----
    f32x4 accU[4];
#pragma unroll
    for (int ni = 0; ni < 4; ++ni)
#pragma unroll
        for (int z = 0; z < 4; ++z) accU[ni][z] = 0.f;

    int kt_bot = i_bot0 >> 5;
    constexpr int NKS2 = W / 32;

    auto LOADM = [&](int ks2, bf16x8* dh, bf16x8* dl) {
#pragma unroll
        for (int ni = 0; ni < 4; ++ni) {
            int ct = wv * 4 + ni;
            size_t mo = ((size_t)((kt_bot + ks2) * 32 + ct)) * 512 + (size_t)lane * 8;
            dh[ni] = *(const bf16x8*)(Mfh_g + mo);
            dl[ni] = *(const bf16x8*)(Mfl_g + mo);
        }
    };

    {
        bf16x8 mph[4], mpl[4];
        LOADM(0, mph, mpl);
#pragma unroll
        for (int ks2 = 0; ks2 < NKS2; ++ks2) {
            bf16x8 mqh[4], mql[4];
            if (ks2 + 1 < NKS2) LOADM(ks2 + 1, mqh, mql);
            float a8[8];
#pragma unroll
            for (int j = 0; j < 8; ++j) a8[j] = Cl[fr][ks2 * 32 + kg * 8 + j];
            bf16x8 ah2, al2;
            split8(a8, ah2, al2);
#pragma unroll
            for (int ni = 0; ni < 4; ++ni) {
                accU[ni] = MFMA(ah2, mph[ni], accU[ni]);
                accU[ni] = MFMA(ah2, mpl[ni], accU[ni]);
                accU[ni] = MFMA(al2, mph[ni], accU[ni]);
            }
#pragma unroll
            for (int ni = 0; ni < 4; ++ni) { mph[ni] = mqh[ni]; mpl[ni] = mql[ni]; }
        }
    }
#pragma unroll
    for (int ni = 0; ni < 4; ++ni) {
        int c = (wv * 4 + ni) * 16 + fr;
#pragma unroll
        for (int jj = 0; jj < 4; ++jj) {
            int il = kg * 4 + jj;
            float ma = bf2f(MAh[il][c]) + bf2f(MAl[il][c]);
            float m2 = ma - accU[ni][jj];
            u16 hu = f2bf(m2);
            MAh[il][c] = hu;
            MAl[il][c] = f2bf(m2 - bf2f(hu));
        }
    }
    __syncthreads();

    for (int idx = t; idx < 1024; idx += 512) {
        int c = idx >> 1, sub = idx & 1;
        bf16x8 hv, lv;
#pragma unroll
        for (int j = 0; j < 8; ++j) {
            hv[j] = (short)MAh[sub * 8 + j][c];
            lv[j] = (short)MAl[sub * 8 + j][c];
        }
        size_t off = ((size_t)(kt_top * 32 + (c >> 4))) * 512
                   + (size_t)((hh + sub) * 16 + (c & 15)) * 8;
        *(bf16x8*)(Mfh_g + off) = hv;
        *(bf16x8*)(Mfl_g + off) = lv;
    }
}

// ---------------------------------------------------------------------------
// Kernel 3: Qt[g][d][c] = [I - w*M]^T. 512 blocks x 256 thr, XCD-swizzled.
// A from Af, B from Mf (both coalesced frags). (round-15 verified)
// ---------------------------------------------------------------------------
__global__ __launch_bounds__(256) void k_qbuild2(const u16* __restrict__ Afh,
                                                 const u16* __restrict__ Afl,
                                                 const u16* __restrict__ Mfh,
                                                 const u16* __restrict__ Mfl,
                                                 u16* __restrict__ Qt) {
    int bid = blockIdx.x;
    int qb  = (bid & 7) * 64 + (bid >> 3);    // XCD-chunked
    int t = threadIdx.x, lane = t & 63, wv = t >> 6;
    int fr = lane & 15, kg = lane >> 4;
    int g  = qb >> 6;
    int tm = (qb >> 2) & 15, tn = qb & 3;
    int c0 = tm * 32;
    int d0 = tn * 128 + wv * 32;

    const u16* Afh_g = Afh + (size_t)g * CH * CH;
    const u16* Afl_g = Afl + (size_t)g * CH * CH;
    const u16* Mfh_g = Mfh + (size_t)g * CH * CH;
    const u16* Mfl_g = Mfl + (size_t)g * CH * CH;
    u16* Qt_g = Qt + (size_t)g * CH * CH;

    f32x4 acc[2][2];
#pragma unroll
    for (int mi = 0; mi < 2; ++mi)
#pragma unroll
        for (int ni = 0; ni < 2; ++ni)
#pragma unroll
            for (int z = 0; z < 4; ++z) acc[mi][ni][z] = 0.f;

    int mt0 = c0 >> 4;
    for (int ks = 0; ks < 16; ++ks) {
        bf16x8 ah[2], al[2], bh[2], bl[2];
#pragma unroll
        for (int mi = 0; mi < 2; ++mi) {
            size_t ao = ((size_t)(ks * 32 + mt0 + mi)) * 512 + (size_t)lane * 8;
            ah[mi] = *(const bf16x8*)(Afh_g + ao);
            al[mi] = *(const bf16x8*)(Afl_g + ao);
        }
#pragma unroll
        for (int ni = 0; ni < 2; ++ni) {
            int ct = (d0 >> 4) + ni;
            size_t mo = ((size_t)(ks * 32 + ct)) * 512 + (size_t)lane * 8;
            bh[ni] = *(const bf16x8*)(Mfh_g + mo);
            bl[ni] = *(const bf16x8*)(Mfl_g + mo);
        }
#pragma unroll
        for (int mi = 0; mi < 2; ++mi)
#pragma unroll
            for (int ni = 0; ni < 2; ++ni) {
                acc[mi][ni] = MFMA(ah[mi], bh[ni], acc[mi][ni]);
                acc[mi][ni] = MFMA(ah[mi], bl[ni], acc[mi][ni]);
                acc[mi][ni] = MFMA(al[mi], bh[ni], acc[mi][ni]);
            }
    }
#pragma unroll
    for (int mi = 0; mi < 2; ++mi)
#pragma unroll
        for (int ni = 0; ni < 2; ++ni) {
            int cb2 = c0 + mi * 16 + kg * 4;
            int d   = d0 + ni * 16 + fr;
            ushort4 h4;
            h4.x = f2bf(((cb2 + 0 == d) ? 1.0f : 0.0f) - acc[mi][ni][0]);
            h4.y = f2bf(((cb2 + 1 == d) ? 1.0f : 0.0f) - acc[mi][ni][1]);
            h4.z = f2bf(((cb2 + 2 == d) ? 1.0f : 0.0f) - acc[mi][ni][2]);
            h4.w = f2bf(((cb2 + 3 == d) ? 1.0f : 0.0f) - acc[mi][ni][3]);
            *(ushort4*)(Qt_g + (size_t)d * CH + cb2) = h4;
        }
}

// ---------------------------------------------------------------------------
// Kernel 4: dbuf GEMM, counted vmcnt (T4) + setprio around MFMA cluster (T5).
// BK=32, 32KB LDS. (round-15 verified structure)
// ---------------------------------------------------------------------------
__global__ __launch_bounds__(256) void k_gemm2(const u16* __restrict__ xb,
                                               const u16* __restrict__ Qt,
                                               float* __restrict__ out) {
    __shared__ u16 Ab[2][128 * 32];
    __shared__ u16 Bb[2][128 * 32];

    int bid0 = blockIdx.x;
    int wg = (bid0 & 7) * 128 + (bid0 >> 3);  // bijective XCD chunk; g == bid0&7
    int g  = wg >> 7;
    int r  = wg & 127;
    int tm = r >> 2;
    int tn = r & 3;

    int t    = threadIdx.x;
    int lane = t & 63;
    int wv   = t >> 6;
    int wr   = wv >> 1, wc = wv & 1;
    int fr   = lane & 15, kg = lane >> 4;

    const u16* xg  = xb + (size_t)g * BS * CH + (size_t)tm * 128 * CH;
    const u16* Qtg = Qt + (size_t)g * CH * CH + (size_t)tn * 128 * CH;
    float* og = out + (size_t)g * BS * CH + (size_t)tm * 128 * CH + (size_t)tn * 128;

    f32x4 acc[4][4];
#pragma unroll
    for (int mi = 0; mi < 4; ++mi)
#pragma unroll
        for (int ni = 0; ni < 4; ++ni)
#pragma unroll
            for (int z = 0; z < 4; ++z) acc[mi][ni][z] = 0.f;

    int srow = lane >> 2;
    int scol = (lane & 3) * 8;

    auto STAGE = [&](int p, int ks) {   // exactly 4 gload16 per thread
        int k0 = ks * 32;
#pragma unroll
        for (int si = 0; si < 2; ++si) {
            int seg = wv * 2 + si;
            int row = seg * 16 + srow;
            gload16(xg  + (size_t)row * CH + k0 + scol, &Ab[p][seg * 512]);
            gload16(Qtg + (size_t)row * CH + k0 + scol, &Bb[p][seg * 512]);
        }
    };

    STAGE(0, 0);
    asm volatile("s_waitcnt vmcnt(0)" ::: "memory");
    __builtin_amdgcn_s_barrier();

    for (int ks = 0; ks < 16; ++ks) {
        int cur = ks & 1;
        if (ks < 15) {
            STAGE(cur ^ 1, ks + 1);
            asm volatile("s_waitcnt vmcnt(4)" ::: "memory");
        } else {
            asm volatile("s_waitcnt vmcnt(0)" ::: "memory");
        }
        __builtin_amdgcn_s_barrier();

        bf16x8 af[4], bfr[4];
#pragma unroll
        for (int mi = 0; mi < 4; ++mi)
            af[mi] = *(const bf16x8*)&Ab[cur][(wr * 64 + mi * 16 + fr) * 32 + kg * 8];
#pragma unroll
        for (int ni = 0; ni < 4; ++ni)
            bfr[ni] = *(const bf16x8*)&Bb[cur][(wc * 64 + ni * 16 + fr) * 32 + kg * 8];
        __builtin_amdgcn_s_setprio(1);
#pragma unroll
        for (int mi = 0; mi < 4; ++mi)
#pragma unroll
            for (int ni = 0; ni < 4; ++ni)
                acc[mi][ni] = MFMA(af[mi], bfr[ni], acc[mi][ni]);
        __builtin_amdgcn_s_setprio(0);

        asm volatile("" ::: "memory");
        __builtin_amdgcn_s_barrier();
    }

    int rg = lane >> 4;
#pragma unroll
    for (int mi = 0; mi < 4; ++mi)
#pragma unroll
        for (int ni = 0; ni < 4; ++ni)
#pragma unroll
            for (int rj = 0; rj < 4; ++rj) {
                int grow = wr * 64 + mi * 16 + rg * 4 + rj;
                int gcol = wc * 64 + ni * 16 + fr;
                og[(size_t)grow * CH + gcol] = acc[mi][ni][rj];
            }
}

// ---------------------------------------------------------------------------
// Fallback GEMM (fp32 A, in-staging convert) — round-5 verified.
// ---------------------------------------------------------------------------
#define LDP 40
__global__ __launch_bounds__(256) void k_gemm_f32(const float* __restrict__ x,
                                                  const u16* __restrict__ Qt,
                                                  float* __restrict__ out) {
    __shared__ u16 Al[128 * LDP];
    __shared__ u16 Bl[128 * LDP];

    int bid = blockIdx.x;
    int g  = bid >> 7;
    int tn = (bid >> 5) & 3;
    int tm = bid & 31;

    int t    = threadIdx.x;
    int lane = t & 63;
    int w    = t >> 6;
    int wr   = w >> 1, wc = w & 1;

    const float* xg = x + (size_t)g * BS * CH + (size_t)tm * 128 * CH;
    const u16* Qtg = Qt + (size_t)g * CH * CH + (size_t)tn * 128 * CH;
    float* og = out + (size_t)g * BS * CH + (size_t)tm * 128 * CH + (size_t)tn * 128;

    f32x4 acc[4][4];
#pragma unroll
    for (int mi = 0; mi < 4; ++mi)
#pragma unroll
        for (int ni = 0; ni < 4; ++ni)
#pragma unroll
            for (int z = 0; z < 4; ++z) acc[mi][ni][z] = 0.f;

    int a_k4 = t & 7;
    int a_r  = t >> 3;
    int b_n  = t & 127;
    int b_kh = t >> 7;
    int fr = lane & 15, kg = lane >> 4;

    for (int ks = 0; ks < 16; ++ks) {
        int k0 = ks * 32;
        __syncthreads();
#pragma unroll
        for (int rr = 0; rr < 4; ++rr) {
            int r = a_r + 32 * rr;
            float4 v = *(const float4*)(xg + (size_t)r * CH + k0 + a_k4 * 4);
            ushort4 h;
            h.x = f2bf(v.x); h.y = f2bf(v.y); h.z = f2bf(v.z); h.w = f2bf(v.w);
            *(ushort4*)(&Al[r * LDP + a_k4 * 4]) = h;
        }
        {
            const u16* src = Qtg + (size_t)b_n * CH + k0 + b_kh * 16;
            u16x8 lo = *(const u16x8*)src;
            u16x8 hi = *(const u16x8*)(src + 8);
            *(u16x8*)(&Bl[b_n * LDP + b_kh * 16]) = lo;
            *(u16x8*)(&Bl[b_n * LDP + b_kh * 16 + 8]) = hi;
        }
        __syncthreads();
        bf16x8 af[4], bfr[4];
#pragma unroll
        for (int mi = 0; mi < 4; ++mi)
            af[mi] = *(const bf16x8*)(&Al[(wr * 64 + mi * 16 + fr) * LDP + kg * 8]);
#pragma unroll
        for (int ni = 0; ni < 4; ++ni)
            bfr[ni] = *(const bf16x8*)(&Bl[(wc * 64 + ni * 16 + fr) * LDP + kg * 8]);
#pragma unroll
        for (int mi = 0; mi < 4; ++mi)
#pragma unroll
            for (int ni = 0; ni < 4; ++ni)
                acc[mi][ni] = MFMA(af[mi], bfr[ni], acc[mi][ni]);
    }

    int rg = lane >> 4;
#pragma unroll
    for (int mi = 0; mi < 4; ++mi)
#pragma unroll
        for (int ni = 0; ni < 4; ++ni)
#pragma unroll
            for (int rj = 0; rj < 4; ++rj) {
                int grow = wr * 64 + mi * 16 + rg * 4 + rj;
                int gcol = wc * 64 + ni * 16 + fr;
                og[(size_t)grow * CH + gcol] = acc[mi][ni][rj];
            }
}

// ---------------------------------------------------------------------------
extern "C" void kernel_launch(void* const* d_in, const int* in_sizes, int n_in,
                              void* d_out, int out_size, void* d_ws, size_t ws_size,
                              hipStream_t stream) {
    const float* x = (const float*)d_in[0];   // (8, 4096, 512)
    const float* w = (const float*)d_in[1];   // (8, 512, 512)
    float* out = (float*)d_out;

    char* ob = (char*)d_out;                  // 64 MiB scratch, dead before GEMM
    u16* Yfh = (u16*)ob;                      // [0, 4MB)
    u16* Yfl = (u16*)(ob + (4u  << 20));      // [4, 8)
    u16* Mfh = (u16*)(ob + (8u  << 20));      // [8, 12)
    u16* Mfl = (u16*)(ob + (12u << 20));      // [12, 16)
    u16* Afh = (u16*)(ob + (16u << 20));      // [16, 20)
    u16* Afl = (u16*)(ob + (20u << 20));      // [20, 24)

    int fat = (ws_size >= ((32u << 20) + (4u << 20))) ? 1 : 0;
    u16* xbp = (u16*)d_ws;
    u16* Qt  = fat ? (u16*)((char*)d_ws + (32u << 20)) : (u16*)d_ws;

    k_panelprep<<<dim3(fat ? 1152 : 128), dim3(1024), 0, stream>>>(w, x, Yfh, Yfl, Mfh, Mfl, Afh, Afl, xbp);
    k_combine<32><<<dim3(128), dim3(512), 0, stream>>>(Yfh, Yfl, Mfh, Mfl);
    k_combine<64><<<dim3(128), dim3(512), 0, stream>>>(Yfh, Yfl, Mfh, Mfl);
    k_combine<128><<<dim3(128), dim3(512), 0, stream>>>(Yfh, Yfl, Mfh, Mfl);
    k_combine<256><<<dim3(128), dim3(512), 0, stream>>>(Yfh, Yfl, Mfh, Mfl);
    k_qbuild2<<<dim3(512), dim3(256), 0, stream>>>(Afh, Afl, Mfh, Mfl, Qt);
    if (fat)
        k_gemm2<<<dim3(1024), dim3(256), 0, stream>>>(xbp, Qt, out);
    else
        k_gemm_f32<<<dim3(1024), dim3(256), 0, stream>>>(x, Qt, out);
}